// Round 3
// baseline (1051.100 us; speedup 1.0000x reference)
//
#include <hip/hip_runtime.h>

#define N_NODES_C 40000
#define N_EDGES_C 640000
#define DIM 128
#define NB 50
#define NBP 52        // padded basis (multiple of 4)
#define LDA 132       // padded A-tile leading dim (row stride 528B: 16B-aligned, 2-way banks = free)
#define BLK 256
#define TROWS 64
#define LOG2_C 0.6931471805599453f
#define PI_OVER_CUT 0.6283185307179586f  // pi/5
#define NSCAN_BLK 157  // ceil(40000/256)

__device__ __forceinline__ float ssp_f(float t) {
    return fmaxf(t, 0.0f) + log1pf(expf(-fabsf(t))) - LOG2_C;
}

// ---- async global->LDS, 16B per lane ----
__device__ __forceinline__ void gll16(const float* g, float* l) {
    __builtin_amdgcn_global_load_lds(
        (const __attribute__((address_space(1))) void*)g,
        (__attribute__((address_space(3))) void*)l, 16, 0, 0);
}

// Stage W_f1 (50 rows x 128) into BcW rows 0..49 via LDS-direct loads; zero rows 50,51.
__device__ __forceinline__ void stage_w1_lds(const float* __restrict__ W1,
                                             float* __restrict__ BcW, int tid) {
#pragma unroll
    for (int r = 0; r < 6; ++r) {
        int i = r * BLK + tid;           // float4 slot, 0..1535
        gll16(W1 + (size_t)i * 4, BcW + (size_t)i * 4);
    }
    if (tid < 64) {                      // slots 1536..1599 (one full wave)
        int i = 1536 + tid;
        gll16(W1 + (size_t)i * 4, BcW + (size_t)i * 4);
    }
    if (tid >= 64 && tid < 128) {        // zero rows 50,51: slots 1600..1663
        int i = 1536 + tid;
        *(float4*)&BcW[(size_t)i * 4] = make_float4(0.f, 0.f, 0.f, 0.f);
    }
}

// Prefetch a 64x128 chunk of W (rows k0..k0+63) into 8 float4 regs per thread.
__device__ __forceinline__ void prefetch_w64(const float* __restrict__ W, int k0,
                                             float4 (&p)[8], int tid) {
#pragma unroll
    for (int r = 0; r < 8; ++r)
        p[r] = *(const float4*)(W + (size_t)k0 * DIM + ((size_t)(r * BLK + tid)) * 4);
}

__device__ __forceinline__ void write_w64(const float4 (&p)[8], float* __restrict__ BcW, int tid) {
#pragma unroll
    for (int r = 0; r < 8; ++r)
        *(float4*)&BcW[(size_t)(r * BLK + tid) * 4] = p[r];
}

// acc[4][8] += A_lds[64 rows][lda] (cols kbase..kbase+4*NK4) @ BcW[4*NK4 rows][128]
template <int NK4>
__device__ __forceinline__ void gemm_chunk(const float* __restrict__ A_lds, int lda, int kbase,
                                           const float* __restrict__ Bc,
                                           float acc[4][8], int rt, int ct) {
#pragma unroll 2
    for (int k4 = 0; k4 < NK4; ++k4) {
        float4 av[4];
#pragma unroll
        for (int i = 0; i < 4; ++i)
            av[i] = *(const float4*)&A_lds[(rt * 4 + i) * lda + kbase + k4 * 4];
#pragma unroll
        for (int kk = 0; kk < 4; ++kk) {
            const float* bp = &Bc[(k4 * 4 + kk) * DIM + ct * 8];
            float4 b0 = *(const float4*)bp;
            float4 b1 = *(const float4*)(bp + 4);
#pragma unroll
            for (int i = 0; i < 4; ++i) {
                float a = ((const float*)&av[i])[kk];
                acc[i][0] = fmaf(a, b0.x, acc[i][0]);
                acc[i][1] = fmaf(a, b0.y, acc[i][1]);
                acc[i][2] = fmaf(a, b0.z, acc[i][2]);
                acc[i][3] = fmaf(a, b0.w, acc[i][3]);
                acc[i][4] = fmaf(a, b1.x, acc[i][4]);
                acc[i][5] = fmaf(a, b1.y, acc[i][5]);
                acc[i][6] = fmaf(a, b1.z, acc[i][6]);
                acc[i][7] = fmaf(a, b1.w, acc[i][7]);
            }
        }
    }
}

__device__ __forceinline__ void init_acc_bias(float acc[4][8], const float* __restrict__ b, int ct) {
    float4 bb0 = *(const float4*)&b[ct * 8];
    float4 bb1 = *(const float4*)&b[ct * 8 + 4];
#pragma unroll
    for (int i = 0; i < 4; ++i) {
        acc[i][0] = bb0.x; acc[i][1] = bb0.y; acc[i][2] = bb0.z; acc[i][3] = bb0.w;
        acc[i][4] = bb1.x; acc[i][5] = bb1.y; acc[i][6] = bb1.z; acc[i][7] = bb1.w;
    }
}

// ---------------- Kernel: h = x @ W_in2f ----------------
__global__ __launch_bounds__(BLK) void node_in2f_kernel(const float* __restrict__ x,
                                                        const float* __restrict__ W,
                                                        float* __restrict__ h) {
    __shared__ float At[TROWS * LDA];   // 33.8 KB
    __shared__ float BcW[64 * DIM];     // 32 KB
    const int tid = threadIdx.x;
    const int rt = tid >> 4, ct = tid & 15;
    const int n0 = blockIdx.x * TROWS;

    for (int i = tid; i < TROWS * (DIM / 4); i += BLK) {
        int row = i >> 5, c4 = i & 31;
        *(float4*)&At[row * LDA + c4 * 4] = *(const float4*)&x[(size_t)(n0 + row) * DIM + c4 * 4];
    }
    float4 pw0[8], pw1[8];
    prefetch_w64(W, 0, pw0, tid);
    prefetch_w64(W, 64, pw1, tid);
    write_w64(pw0, BcW, tid);           // BcW fresh; compiler inserts counted vmcnt for pw0
    __syncthreads();                    // B1: At + c0 visible

    float acc[4][8];
#pragma unroll
    for (int i = 0; i < 4; ++i)
#pragma unroll
        for (int j = 0; j < 8; ++j) acc[i][j] = 0.f;

    gemm_chunk<16>(At, LDA, 0, BcW, acc, rt, ct);
    __syncthreads();                    // B2: chunk0 reads done
    write_w64(pw1, BcW, tid);
    __syncthreads();                    // B3: c1 visible
    gemm_chunk<16>(At, LDA, 64, BcW, acc, rt, ct);

#pragma unroll
    for (int i = 0; i < 4; ++i) {
        float* hp = &h[(size_t)(n0 + rt * 4 + i) * DIM + ct * 8];
        *(float4*)hp = make_float4(acc[i][0], acc[i][1], acc[i][2], acc[i][3]);
        *(float4*)(hp + 4) = make_float4(acc[i][4], acc[i][5], acc[i][6], acc[i][7]);
    }
}

// ---------------- CSR build ----------------
__global__ __launch_bounds__(BLK) void hist_kernel(const int* __restrict__ ind_i,
                                                   int* __restrict__ cnt) {
    int e = blockIdx.x * BLK + threadIdx.x;
    if (e < N_EDGES_C) atomicAdd(&cnt[ind_i[e]], 1);
}

__global__ __launch_bounds__(BLK) void scan1_kernel(const int* __restrict__ cnt,
                                                    int* __restrict__ excl,
                                                    int* __restrict__ bsum) {
    __shared__ int s[BLK];
    const int tid = threadIdx.x;
    const int idx = blockIdx.x * BLK + tid;
    int v = (idx < N_NODES_C) ? cnt[idx] : 0;
    s[tid] = v;
    __syncthreads();
    for (int off = 1; off < BLK; off <<= 1) {
        int t = (tid >= off) ? s[tid - off] : 0;
        __syncthreads();
        s[tid] += t;
        __syncthreads();
    }
    if (idx < N_NODES_C) excl[idx] = s[tid] - v;
    if (tid == BLK - 1) bsum[blockIdx.x] = s[tid];
}

__global__ __launch_bounds__(BLK) void scan2_kernel(int* __restrict__ bsum) {
    __shared__ int s[BLK];
    const int tid = threadIdx.x;
    int v = (tid < NSCAN_BLK) ? bsum[tid] : 0;
    s[tid] = v;
    __syncthreads();
    for (int off = 1; off < BLK; off <<= 1) {
        int t = (tid >= off) ? s[tid - off] : 0;
        __syncthreads();
        s[tid] += t;
        __syncthreads();
    }
    if (tid < NSCAN_BLK) bsum[tid] = s[tid] - v;  // exclusive
}

__global__ __launch_bounds__(BLK) void scan3_kernel(int* __restrict__ start,
                                                    int* __restrict__ cursor,
                                                    const int* __restrict__ bsum) {
    const int idx = blockIdx.x * BLK + threadIdx.x;
    if (idx < N_NODES_C) {
        int v = start[idx] + bsum[blockIdx.x];
        start[idx] = v;
        cursor[idx] = v;
    }
}

__global__ __launch_bounds__(BLK) void place_kernel(const int* __restrict__ ind_i,
                                                    int* __restrict__ cursor,
                                                    int* __restrict__ eids) {
    int e = blockIdx.x * BLK + threadIdx.x;
    if (e < N_EDGES_C) {
        int slot = atomicAdd(&cursor[ind_i[e]], 1);
        eids[slot] = e;
    }
}

// ---------------- Edge kernel: msg = (ssp(f@W1+b1)@W2+b2) * C * h[ind_j] ----------------
__global__ __launch_bounds__(BLK) void edge_kernel_msg(const float* __restrict__ f_ij,
                                                       const float* __restrict__ r_ij,
                                                       const int* __restrict__ ind_j,
                                                       const float* __restrict__ W_f1,
                                                       const float* __restrict__ b_f1,
                                                       const float* __restrict__ W_f2,
                                                       const float* __restrict__ b_f2,
                                                       const float* __restrict__ h,
                                                       float* __restrict__ msg) {
    __shared__ float fA[TROWS * NBP];   // 13.3 KB
    __shared__ float t1[TROWS * LDA];   // 33.8 KB
    __shared__ float BcW[64 * DIM];     // 32 KB  (W1 full, then W2 in 2 chunks)
    const int tid = threadIdx.x;
    const int rt = tid >> 4, ct = tid & 15;
    const int e0 = blockIdx.x * TROWS;  // 640000 % 64 == 0: all blocks full

    stage_w1_lds(W_f1, BcW, tid);
    for (int i = tid; i < TROWS * NBP; i += BLK) {
        int row = i / NBP, c = i - row * NBP;
        float v = 0.f;
        if (c < NB) v = f_ij[(size_t)(e0 + row) * NB + c];
        fA[row * NBP + c] = v;
    }
    float4 pw0[8], pw1[8];
    prefetch_w64(W_f2, 0, pw0, tid);
    prefetch_w64(W_f2, 64, pw1, tid);

    __syncthreads();                    // B1: W1, fA visible; prefetches landed

    float acc[4][8];
    init_acc_bias(acc, b_f1, ct);
    gemm_chunk<13>(fA, NBP, 0, BcW, acc, rt, ct);   // K=52 (cols 50,51 zero)

    // t1 = ssp(acc)
#pragma unroll
    for (int i = 0; i < 4; ++i) {
        float* tp = &t1[(rt * 4 + i) * LDA + ct * 8];
        *(float4*)tp = make_float4(ssp_f(acc[i][0]), ssp_f(acc[i][1]),
                                   ssp_f(acc[i][2]), ssp_f(acc[i][3]));
        *(float4*)(tp + 4) = make_float4(ssp_f(acc[i][4]), ssp_f(acc[i][5]),
                                         ssp_f(acc[i][6]), ssp_f(acc[i][7]));
    }
    __syncthreads();                    // B2: t1 visible; GEMM1's BcW reads done
    write_w64(pw0, BcW, tid);           // deposit W2 chunk0
    __syncthreads();                    // B3

    init_acc_bias(acc, b_f2, ct);
    gemm_chunk<16>(t1, LDA, 0, BcW, acc, rt, ct);
    __syncthreads();                    // B4
    write_w64(pw1, BcW, tid);           // deposit W2 chunk1
    __syncthreads();                    // B5
    gemm_chunk<16>(t1, LDA, 64, BcW, acc, rt, ct);

    // epilogue: cutoff, gather h[ind_j], write msg row
#pragma unroll
    for (int i = 0; i < 4; ++i) {
        int e = e0 + rt * 4 + i;
        float r = r_ij[e];
        float C = (r < 5.0f) ? 0.5f * (cosf(r * PI_OVER_CUT) + 1.0f) : 0.0f;
        int nj = ind_j[e];
        const float* hp = &h[(size_t)nj * DIM + ct * 8];
        float4 h0 = *(const float4*)hp;
        float4 h1 = *(const float4*)(hp + 4);
        float* mp = &msg[(size_t)e * DIM + ct * 8];
        *(float4*)mp = make_float4(h0.x * acc[i][0] * C, h0.y * acc[i][1] * C,
                                   h0.z * acc[i][2] * C, h0.w * acc[i][3] * C);
        *(float4*)(mp + 4) = make_float4(h1.x * acc[i][4] * C, h1.y * acc[i][5] * C,
                                         h1.z * acc[i][6] * C, h1.w * acc[i][7] * C);
    }
}

// ---------------- Gather: agg[n] = sum over CSR edges of msg ----------------
__global__ __launch_bounds__(BLK) void gather_kernel(const float* __restrict__ msg,
                                                     const int* __restrict__ eids,
                                                     const int* __restrict__ start,
                                                     const int* __restrict__ cnt,
                                                     float* __restrict__ agg) {
    const int wave = threadIdx.x >> 6;
    const int lane = threadIdx.x & 63;
    const int node = blockIdx.x * 4 + wave;
    if (node >= N_NODES_C) return;
    const int s = start[node];
    const int d = cnt[node];
    float ax = 0.f, ay = 0.f;
    int k = 0;
    for (; k + 1 < d; k += 2) {
        int ea = eids[s + k], eb = eids[s + k + 1];
        float2 va = *(const float2*)&msg[(size_t)ea * DIM + lane * 2];
        float2 vb = *(const float2*)&msg[(size_t)eb * DIM + lane * 2];
        ax += va.x + vb.x;
        ay += va.y + vb.y;
    }
    if (k < d) {
        int ea = eids[s + k];
        float2 va = *(const float2*)&msg[(size_t)ea * DIM + lane * 2];
        ax += va.x;
        ay += va.y;
    }
    *(float2*)&agg[(size_t)node * DIM + lane * 2] = make_float2(ax, ay);
}

// ---------------- Output: out = ssp(agg@W_out + b_out) @ W_lin + b_lin ----------------
__global__ __launch_bounds__(BLK) void node_out_kernel(const float* __restrict__ agg,
                                                       const float* __restrict__ W_out,
                                                       const float* __restrict__ b_out,
                                                       const float* __restrict__ W_lin,
                                                       const float* __restrict__ b_lin,
                                                       float* __restrict__ out) {
    __shared__ float At[TROWS * LDA];
    __shared__ float BcW[64 * DIM];
    const int tid = threadIdx.x;
    const int rt = tid >> 4, ct = tid & 15;
    const int n0 = blockIdx.x * TROWS;

    for (int i = tid; i < TROWS * (DIM / 4); i += BLK) {
        int row = i >> 5, c4 = i & 31;
        *(float4*)&At[row * LDA + c4 * 4] = *(const float4*)&agg[(size_t)(n0 + row) * DIM + c4 * 4];
    }
    float4 pw0[8], pw1[8];
    prefetch_w64(W_out, 0, pw0, tid);
    prefetch_w64(W_out, 64, pw1, tid);
    write_w64(pw0, BcW, tid);
    __syncthreads();                    // B1

    float acc[4][8];
    init_acc_bias(acc, b_out, ct);
    gemm_chunk<16>(At, LDA, 0, BcW, acc, rt, ct);
    __syncthreads();                    // B2
    write_w64(pw1, BcW, tid);
    prefetch_w64(W_lin, 0, pw0, tid);   // issue early (one exposed L2 latency at B3; small kernel)
    __syncthreads();                    // B3
    gemm_chunk<16>(At, LDA, 64, BcW, acc, rt, ct);
    __syncthreads();                    // B4: all At/BcW reads done

    // v = ssp(acc) -> At; deposit W_lin chunk0
#pragma unroll
    for (int i = 0; i < 4; ++i) {
        float* tp = &At[(rt * 4 + i) * LDA + ct * 8];
        *(float4*)tp = make_float4(ssp_f(acc[i][0]), ssp_f(acc[i][1]),
                                   ssp_f(acc[i][2]), ssp_f(acc[i][3]));
        *(float4*)(tp + 4) = make_float4(ssp_f(acc[i][4]), ssp_f(acc[i][5]),
                                         ssp_f(acc[i][6]), ssp_f(acc[i][7]));
    }
    write_w64(pw0, BcW, tid);
    prefetch_w64(W_lin, 64, pw1, tid);  // hidden under next GEMM chunk
    __syncthreads();                    // B5

    init_acc_bias(acc, b_lin, ct);
    gemm_chunk<16>(At, LDA, 0, BcW, acc, rt, ct);
    __syncthreads();                    // B6
    write_w64(pw1, BcW, tid);
    __syncthreads();                    // B7
    gemm_chunk<16>(At, LDA, 64, BcW, acc, rt, ct);

#pragma unroll
    for (int i = 0; i < 4; ++i) {
        float* op = &out[(size_t)(n0 + rt * 4 + i) * DIM + ct * 8];
        *(float4*)op = make_float4(acc[i][0], acc[i][1], acc[i][2], acc[i][3]);
        *(float4*)(op + 4) = make_float4(acc[i][4], acc[i][5], acc[i][6], acc[i][7]);
    }
}

// ---------------- Atomic fallback (only if workspace too small) ----------------
__global__ __launch_bounds__(BLK) void edge_kernel_atomic(const float* __restrict__ f_ij,
                                                          const float* __restrict__ r_ij,
                                                          const int* __restrict__ ind_i,
                                                          const int* __restrict__ ind_j,
                                                          const float* __restrict__ W_f1,
                                                          const float* __restrict__ b_f1,
                                                          const float* __restrict__ W_f2,
                                                          const float* __restrict__ b_f2,
                                                          const float* __restrict__ h,
                                                          float* __restrict__ agg) {
    __shared__ float fA[TROWS * NBP];
    __shared__ float t1[TROWS * LDA];
    __shared__ float BcW[64 * DIM];
    const int tid = threadIdx.x;
    const int rt = tid >> 4, ct = tid & 15;
    const int e0 = blockIdx.x * TROWS;

    stage_w1_lds(W_f1, BcW, tid);
    for (int i = tid; i < TROWS * NBP; i += BLK) {
        int row = i / NBP, c = i - row * NBP;
        float v = 0.f;
        if (c < NB) v = f_ij[(size_t)(e0 + row) * NB + c];
        fA[row * NBP + c] = v;
    }
    float4 pw0[8], pw1[8];
    prefetch_w64(W_f2, 0, pw0, tid);
    prefetch_w64(W_f2, 64, pw1, tid);
    __syncthreads();

    float acc[4][8];
    init_acc_bias(acc, b_f1, ct);
    gemm_chunk<13>(fA, NBP, 0, BcW, acc, rt, ct);
#pragma unroll
    for (int i = 0; i < 4; ++i) {
        float* tp = &t1[(rt * 4 + i) * LDA + ct * 8];
        *(float4*)tp = make_float4(ssp_f(acc[i][0]), ssp_f(acc[i][1]),
                                   ssp_f(acc[i][2]), ssp_f(acc[i][3]));
        *(float4*)(tp + 4) = make_float4(ssp_f(acc[i][4]), ssp_f(acc[i][5]),
                                         ssp_f(acc[i][6]), ssp_f(acc[i][7]));
    }
    __syncthreads();
    write_w64(pw0, BcW, tid);
    __syncthreads();
    init_acc_bias(acc, b_f2, ct);
    gemm_chunk<16>(t1, LDA, 0, BcW, acc, rt, ct);
    __syncthreads();
    write_w64(pw1, BcW, tid);
    __syncthreads();
    gemm_chunk<16>(t1, LDA, 64, BcW, acc, rt, ct);

#pragma unroll
    for (int i = 0; i < 4; ++i) {
        int e = e0 + rt * 4 + i;
        float r = r_ij[e];
        float C = (r < 5.0f) ? 0.5f * (cosf(r * PI_OVER_CUT) + 1.0f) : 0.0f;
        int nj = ind_j[e];
        int ni = ind_i[e];
        const float* hp = &h[(size_t)nj * DIM + ct * 8];
        float4 h0 = *(const float4*)hp;
        float4 h1 = *(const float4*)(hp + 4);
        float* ap = &agg[(size_t)ni * DIM + ct * 8];
        atomicAdd(ap + 0, h0.x * acc[i][0] * C);
        atomicAdd(ap + 1, h0.y * acc[i][1] * C);
        atomicAdd(ap + 2, h0.z * acc[i][2] * C);
        atomicAdd(ap + 3, h0.w * acc[i][3] * C);
        atomicAdd(ap + 4, h1.x * acc[i][4] * C);
        atomicAdd(ap + 5, h1.y * acc[i][5] * C);
        atomicAdd(ap + 6, h1.z * acc[i][6] * C);
        atomicAdd(ap + 7, h1.w * acc[i][7] * C);
    }
}

extern "C" void kernel_launch(void* const* d_in, const int* in_sizes, int n_in,
                              void* d_out, int out_size, void* d_ws, size_t ws_size,
                              hipStream_t stream) {
    const float* x      = (const float*)d_in[0];
    const float* r_ij   = (const float*)d_in[1];
    const float* f_ij   = (const float*)d_in[2];
    const int*   ind_i  = (const int*)d_in[3];
    const int*   ind_j  = (const int*)d_in[4];
    const float* W_in2f = (const float*)d_in[5];
    const float* W_f1   = (const float*)d_in[6];
    const float* b_f1   = (const float*)d_in[7];
    const float* W_f2   = (const float*)d_in[8];
    const float* b_f2   = (const float*)d_in[9];
    const float* W_out  = (const float*)d_in[10];
    const float* b_out  = (const float*)d_in[11];
    const float* W_lin  = (const float*)d_in[12];
    const float* b_lin  = (const float*)d_in[13];
    float* out = (float*)d_out;

    char* ws = (char*)d_ws;
    size_t off = 0;
    auto alloc = [&](size_t bytes) {
        char* p = ws + off;
        off = (off + bytes + 511) & ~(size_t)511;
        return p;
    };
    float* h      = (float*)alloc((size_t)N_NODES_C * DIM * sizeof(float));
    float* agg    = (float*)alloc((size_t)N_NODES_C * DIM * sizeof(float));
    float* msg    = (float*)alloc((size_t)N_EDGES_C * DIM * sizeof(float));
    int*   eids   = (int*)alloc((size_t)N_EDGES_C * sizeof(int));
    int*   cnt    = (int*)alloc((size_t)N_NODES_C * sizeof(int));
    int*   startA = (int*)alloc((size_t)N_NODES_C * sizeof(int));
    int*   cursor = (int*)alloc((size_t)N_NODES_C * sizeof(int));
    int*   bsum   = (int*)alloc((size_t)NSCAN_BLK * sizeof(int));
    const bool have_ws = (off <= ws_size);

    node_in2f_kernel<<<N_NODES_C / TROWS, BLK, 0, stream>>>(x, W_in2f, h);

    if (have_ws) {
        hipMemsetAsync(cnt, 0, (size_t)N_NODES_C * sizeof(int), stream);
        hist_kernel<<<(N_EDGES_C + BLK - 1) / BLK, BLK, 0, stream>>>(ind_i, cnt);
        scan1_kernel<<<NSCAN_BLK, BLK, 0, stream>>>(cnt, startA, bsum);
        scan2_kernel<<<1, BLK, 0, stream>>>(bsum);
        scan3_kernel<<<NSCAN_BLK, BLK, 0, stream>>>(startA, cursor, bsum);
        place_kernel<<<(N_EDGES_C + BLK - 1) / BLK, BLK, 0, stream>>>(ind_i, cursor, eids);

        edge_kernel_msg<<<N_EDGES_C / TROWS, BLK, 0, stream>>>(
            f_ij, r_ij, ind_j, W_f1, b_f1, W_f2, b_f2, h, msg);
        gather_kernel<<<(N_NODES_C + 3) / 4, BLK, 0, stream>>>(msg, eids, startA, cnt, agg);
    } else {
        hipMemsetAsync(agg, 0, (size_t)N_NODES_C * DIM * sizeof(float), stream);
        edge_kernel_atomic<<<N_EDGES_C / TROWS, BLK, 0, stream>>>(
            f_ij, r_ij, ind_i, ind_j, W_f1, b_f1, W_f2, b_f2, h, agg);
    }

    node_out_kernel<<<N_NODES_C / TROWS, BLK, 0, stream>>>(agg, W_out, b_out, W_lin, b_lin, out);
}

// Round 4
// 1048.450 us; speedup vs baseline: 1.0025x; 1.0025x over previous
//
#include <hip/hip_runtime.h>

#define N_NODES_C 40000
#define N_EDGES_C 640000
#define DIM 128
#define NB 50
#define NBP 52        // padded basis (multiple of 4)
#define LDA 132       // padded A-tile leading dim (row stride 528B: 16B-aligned, 2-way banks = free)
#define BLK 256
#define TROWS 64
#define LOG2_C 0.6931471805599453f
#define PI_OVER_CUT 0.6283185307179586f  // pi/5
#define NSCAN_BLK 157  // ceil(40000/256)

__device__ __forceinline__ float ssp_f(float t) {
    return fmaxf(t, 0.0f) + log1pf(expf(-fabsf(t))) - LOG2_C;
}

// ---- async global->LDS, 16B per lane ----
__device__ __forceinline__ void gll16(const float* g, float* l) {
    __builtin_amdgcn_global_load_lds(
        (const __attribute__((address_space(1))) void*)g,
        (__attribute__((address_space(3))) void*)l, 16, 0, 0);
}

// Stage W_f1 (50 rows x 128) into BcW rows 0..49 via LDS-direct loads; zero rows 50,51.
__device__ __forceinline__ void stage_w1_lds(const float* __restrict__ W1,
                                             float* __restrict__ BcW, int tid) {
#pragma unroll
    for (int r = 0; r < 6; ++r) {
        int i = r * BLK + tid;           // float4 slot, 0..1535
        gll16(W1 + (size_t)i * 4, BcW + (size_t)i * 4);
    }
    if (tid < 64) {                      // slots 1536..1599 (one full wave)
        int i = 1536 + tid;
        gll16(W1 + (size_t)i * 4, BcW + (size_t)i * 4);
    }
    if (tid >= 64 && tid < 128) {        // zero rows 50,51: slots 1600..1663
        int i = 1536 + tid;
        *(float4*)&BcW[(size_t)i * 4] = make_float4(0.f, 0.f, 0.f, 0.f);
    }
}

// Prefetch a 64x128 chunk of W (rows k0..k0+63) into 8 float4 regs per thread.
__device__ __forceinline__ void prefetch_w64(const float* __restrict__ W, int k0,
                                             float4 (&p)[8], int tid) {
#pragma unroll
    for (int r = 0; r < 8; ++r)
        p[r] = *(const float4*)(W + (size_t)k0 * DIM + ((size_t)(r * BLK + tid)) * 4);
}

__device__ __forceinline__ void write_w64(const float4 (&p)[8], float* __restrict__ BcW, int tid) {
#pragma unroll
    for (int r = 0; r < 8; ++r)
        *(float4*)&BcW[(size_t)(r * BLK + tid) * 4] = p[r];
}

// acc[4][8] += A_lds[64 rows][lda] (cols kbase..kbase+4*NK4) @ BcW[4*NK4 rows][128]
template <int NK4>
__device__ __forceinline__ void gemm_chunk(const float* __restrict__ A_lds, int lda, int kbase,
                                           const float* __restrict__ Bc,
                                           float acc[4][8], int rt, int ct) {
#pragma unroll 2
    for (int k4 = 0; k4 < NK4; ++k4) {
        float4 av[4];
#pragma unroll
        for (int i = 0; i < 4; ++i)
            av[i] = *(const float4*)&A_lds[(rt * 4 + i) * lda + kbase + k4 * 4];
#pragma unroll
        for (int kk = 0; kk < 4; ++kk) {
            const float* bp = &Bc[(k4 * 4 + kk) * DIM + ct * 8];
            float4 b0 = *(const float4*)bp;
            float4 b1 = *(const float4*)(bp + 4);
#pragma unroll
            for (int i = 0; i < 4; ++i) {
                float a = ((const float*)&av[i])[kk];
                acc[i][0] = fmaf(a, b0.x, acc[i][0]);
                acc[i][1] = fmaf(a, b0.y, acc[i][1]);
                acc[i][2] = fmaf(a, b0.z, acc[i][2]);
                acc[i][3] = fmaf(a, b0.w, acc[i][3]);
                acc[i][4] = fmaf(a, b1.x, acc[i][4]);
                acc[i][5] = fmaf(a, b1.y, acc[i][5]);
                acc[i][6] = fmaf(a, b1.z, acc[i][6]);
                acc[i][7] = fmaf(a, b1.w, acc[i][7]);
            }
        }
    }
}

__device__ __forceinline__ void init_acc_bias(float acc[4][8], const float* __restrict__ b, int ct) {
    float4 bb0 = *(const float4*)&b[ct * 8];
    float4 bb1 = *(const float4*)&b[ct * 8 + 4];
#pragma unroll
    for (int i = 0; i < 4; ++i) {
        acc[i][0] = bb0.x; acc[i][1] = bb0.y; acc[i][2] = bb0.z; acc[i][3] = bb0.w;
        acc[i][4] = bb1.x; acc[i][5] = bb1.y; acc[i][6] = bb1.z; acc[i][7] = bb1.w;
    }
}

// ---------------- Kernel: h = x @ W_in2f ----------------
// __launch_bounds__(BLK, 2): LDS caps us at 2 blocks/CU anyway; min-2-waves/EU
// raises the VGPR budget to 256 so the W-prefetch regs don't spill to scratch
// (round-3 spill: VGPR stuck at 88, +640MB WRITE_SIZE of scratch traffic).
__global__ __launch_bounds__(BLK, 2) void node_in2f_kernel(const float* __restrict__ x,
                                                           const float* __restrict__ W,
                                                           float* __restrict__ h) {
    __shared__ float At[TROWS * LDA];   // 33.8 KB
    __shared__ float BcW[64 * DIM];     // 32 KB
    const int tid = threadIdx.x;
    const int rt = tid >> 4, ct = tid & 15;
    const int n0 = blockIdx.x * TROWS;

    for (int i = tid; i < TROWS * (DIM / 4); i += BLK) {
        int row = i >> 5, c4 = i & 31;
        *(float4*)&At[row * LDA + c4 * 4] = *(const float4*)&x[(size_t)(n0 + row) * DIM + c4 * 4];
    }
    float4 pw0[8], pw1[8];
    prefetch_w64(W, 0, pw0, tid);
    prefetch_w64(W, 64, pw1, tid);
    write_w64(pw0, BcW, tid);
    __syncthreads();                    // B1: At + c0 visible

    float acc[4][8];
#pragma unroll
    for (int i = 0; i < 4; ++i)
#pragma unroll
        for (int j = 0; j < 8; ++j) acc[i][j] = 0.f;

    gemm_chunk<16>(At, LDA, 0, BcW, acc, rt, ct);
    __syncthreads();                    // B2: chunk0 reads done
    write_w64(pw1, BcW, tid);
    __syncthreads();                    // B3: c1 visible
    gemm_chunk<16>(At, LDA, 64, BcW, acc, rt, ct);

#pragma unroll
    for (int i = 0; i < 4; ++i) {
        float* hp = &h[(size_t)(n0 + rt * 4 + i) * DIM + ct * 8];
        *(float4*)hp = make_float4(acc[i][0], acc[i][1], acc[i][2], acc[i][3]);
        *(float4*)(hp + 4) = make_float4(acc[i][4], acc[i][5], acc[i][6], acc[i][7]);
    }
}

// ---------------- CSR build ----------------
__global__ __launch_bounds__(BLK) void hist_kernel(const int* __restrict__ ind_i,
                                                   int* __restrict__ cnt) {
    int e = blockIdx.x * BLK + threadIdx.x;
    if (e < N_EDGES_C) atomicAdd(&cnt[ind_i[e]], 1);
}

__global__ __launch_bounds__(BLK) void scan1_kernel(const int* __restrict__ cnt,
                                                    int* __restrict__ excl,
                                                    int* __restrict__ bsum) {
    __shared__ int s[BLK];
    const int tid = threadIdx.x;
    const int idx = blockIdx.x * BLK + tid;
    int v = (idx < N_NODES_C) ? cnt[idx] : 0;
    s[tid] = v;
    __syncthreads();
    for (int off = 1; off < BLK; off <<= 1) {
        int t = (tid >= off) ? s[tid - off] : 0;
        __syncthreads();
        s[tid] += t;
        __syncthreads();
    }
    if (idx < N_NODES_C) excl[idx] = s[tid] - v;
    if (tid == BLK - 1) bsum[blockIdx.x] = s[tid];
}

__global__ __launch_bounds__(BLK) void scan2_kernel(int* __restrict__ bsum) {
    __shared__ int s[BLK];
    const int tid = threadIdx.x;
    int v = (tid < NSCAN_BLK) ? bsum[tid] : 0;
    s[tid] = v;
    __syncthreads();
    for (int off = 1; off < BLK; off <<= 1) {
        int t = (tid >= off) ? s[tid - off] : 0;
        __syncthreads();
        s[tid] += t;
        __syncthreads();
    }
    if (tid < NSCAN_BLK) bsum[tid] = s[tid] - v;  // exclusive
}

__global__ __launch_bounds__(BLK) void scan3_kernel(int* __restrict__ start,
                                                    int* __restrict__ cursor,
                                                    const int* __restrict__ bsum) {
    const int idx = blockIdx.x * BLK + threadIdx.x;
    if (idx < N_NODES_C) {
        int v = start[idx] + bsum[blockIdx.x];
        start[idx] = v;
        cursor[idx] = v;
    }
}

__global__ __launch_bounds__(BLK) void place_kernel(const int* __restrict__ ind_i,
                                                    int* __restrict__ cursor,
                                                    int* __restrict__ eids) {
    int e = blockIdx.x * BLK + threadIdx.x;
    if (e < N_EDGES_C) {
        int slot = atomicAdd(&cursor[ind_i[e]], 1);
        eids[slot] = e;
    }
}

// ---------------- Edge kernel: msg = (ssp(f@W1+b1)@W2+b2) * C * h[ind_j] ----------------
__global__ __launch_bounds__(BLK, 2) void edge_kernel_msg(const float* __restrict__ f_ij,
                                                          const float* __restrict__ r_ij,
                                                          const int* __restrict__ ind_j,
                                                          const float* __restrict__ W_f1,
                                                          const float* __restrict__ b_f1,
                                                          const float* __restrict__ W_f2,
                                                          const float* __restrict__ b_f2,
                                                          const float* __restrict__ h,
                                                          float* __restrict__ msg) {
    __shared__ float fA[TROWS * NBP];   // 13.3 KB
    __shared__ float t1[TROWS * LDA];   // 33.8 KB
    __shared__ float BcW[64 * DIM];     // 32 KB  (W1 full, then W2 in 2 chunks)
    const int tid = threadIdx.x;
    const int rt = tid >> 4, ct = tid & 15;
    const int e0 = blockIdx.x * TROWS;  // 640000 % 64 == 0: all blocks full

    stage_w1_lds(W_f1, BcW, tid);
    for (int i = tid; i < TROWS * NBP; i += BLK) {
        int row = i / NBP, c = i - row * NBP;
        float v = 0.f;
        if (c < NB) v = f_ij[(size_t)(e0 + row) * NB + c];
        fA[row * NBP + c] = v;
    }
    float4 pw0[8], pw1[8];
    prefetch_w64(W_f2, 0, pw0, tid);
    prefetch_w64(W_f2, 64, pw1, tid);

    __syncthreads();                    // B1: W1, fA visible; prefetches landed

    float acc[4][8];
    init_acc_bias(acc, b_f1, ct);
    gemm_chunk<13>(fA, NBP, 0, BcW, acc, rt, ct);   // K=52 (cols 50,51 zero)

    // t1 = ssp(acc)
#pragma unroll
    for (int i = 0; i < 4; ++i) {
        float* tp = &t1[(rt * 4 + i) * LDA + ct * 8];
        *(float4*)tp = make_float4(ssp_f(acc[i][0]), ssp_f(acc[i][1]),
                                   ssp_f(acc[i][2]), ssp_f(acc[i][3]));
        *(float4*)(tp + 4) = make_float4(ssp_f(acc[i][4]), ssp_f(acc[i][5]),
                                         ssp_f(acc[i][6]), ssp_f(acc[i][7]));
    }
    __syncthreads();                    // B2: t1 visible; GEMM1's BcW reads done
    write_w64(pw0, BcW, tid);           // deposit W2 chunk0
    __syncthreads();                    // B3

    init_acc_bias(acc, b_f2, ct);
    gemm_chunk<16>(t1, LDA, 0, BcW, acc, rt, ct);
    __syncthreads();                    // B4
    write_w64(pw1, BcW, tid);           // deposit W2 chunk1
    __syncthreads();                    // B5
    gemm_chunk<16>(t1, LDA, 64, BcW, acc, rt, ct);

    // epilogue: cutoff, gather h[ind_j], write msg row
#pragma unroll
    for (int i = 0; i < 4; ++i) {
        int e = e0 + rt * 4 + i;
        float r = r_ij[e];
        float C = (r < 5.0f) ? 0.5f * (cosf(r * PI_OVER_CUT) + 1.0f) : 0.0f;
        int nj = ind_j[e];
        const float* hp = &h[(size_t)nj * DIM + ct * 8];
        float4 h0 = *(const float4*)hp;
        float4 h1 = *(const float4*)(hp + 4);
        float* mp = &msg[(size_t)e * DIM + ct * 8];
        *(float4*)mp = make_float4(h0.x * acc[i][0] * C, h0.y * acc[i][1] * C,
                                   h0.z * acc[i][2] * C, h0.w * acc[i][3] * C);
        *(float4*)(mp + 4) = make_float4(h1.x * acc[i][4] * C, h1.y * acc[i][5] * C,
                                         h1.z * acc[i][6] * C, h1.w * acc[i][7] * C);
    }
}

// ---------------- Gather: agg[n] = sum over CSR edges of msg ----------------
__global__ __launch_bounds__(BLK) void gather_kernel(const float* __restrict__ msg,
                                                     const int* __restrict__ eids,
                                                     const int* __restrict__ start,
                                                     const int* __restrict__ cnt,
                                                     float* __restrict__ agg) {
    const int wave = threadIdx.x >> 6;
    const int lane = threadIdx.x & 63;
    const int node = blockIdx.x * 4 + wave;
    if (node >= N_NODES_C) return;
    const int s = start[node];
    const int d = cnt[node];
    float ax = 0.f, ay = 0.f;
    int k = 0;
    for (; k + 1 < d; k += 2) {
        int ea = eids[s + k], eb = eids[s + k + 1];
        float2 va = *(const float2*)&msg[(size_t)ea * DIM + lane * 2];
        float2 vb = *(const float2*)&msg[(size_t)eb * DIM + lane * 2];
        ax += va.x + vb.x;
        ay += va.y + vb.y;
    }
    if (k < d) {
        int ea = eids[s + k];
        float2 va = *(const float2*)&msg[(size_t)ea * DIM + lane * 2];
        ax += va.x;
        ay += va.y;
    }
    *(float2*)&agg[(size_t)node * DIM + lane * 2] = make_float2(ax, ay);
}

// ---------------- Output: out = ssp(agg@W_out + b_out) @ W_lin + b_lin ----------------
__global__ __launch_bounds__(BLK, 2) void node_out_kernel(const float* __restrict__ agg,
                                                          const float* __restrict__ W_out,
                                                          const float* __restrict__ b_out,
                                                          const float* __restrict__ W_lin,
                                                          const float* __restrict__ b_lin,
                                                          float* __restrict__ out) {
    __shared__ float At[TROWS * LDA];
    __shared__ float BcW[64 * DIM];
    const int tid = threadIdx.x;
    const int rt = tid >> 4, ct = tid & 15;
    const int n0 = blockIdx.x * TROWS;

    for (int i = tid; i < TROWS * (DIM / 4); i += BLK) {
        int row = i >> 5, c4 = i & 31;
        *(float4*)&At[row * LDA + c4 * 4] = *(const float4*)&agg[(size_t)(n0 + row) * DIM + c4 * 4];
    }
    float4 pw0[8], pw1[8];
    prefetch_w64(W_out, 0, pw0, tid);
    prefetch_w64(W_out, 64, pw1, tid);
    write_w64(pw0, BcW, tid);
    __syncthreads();                    // B1

    float acc[4][8];
    init_acc_bias(acc, b_out, ct);
    gemm_chunk<16>(At, LDA, 0, BcW, acc, rt, ct);
    __syncthreads();                    // B2
    write_w64(pw1, BcW, tid);
    prefetch_w64(W_lin, 0, pw0, tid);
    __syncthreads();                    // B3
    gemm_chunk<16>(At, LDA, 64, BcW, acc, rt, ct);
    __syncthreads();                    // B4: all At/BcW reads done

    // v = ssp(acc) -> At; deposit W_lin chunk0
#pragma unroll
    for (int i = 0; i < 4; ++i) {
        float* tp = &At[(rt * 4 + i) * LDA + ct * 8];
        *(float4*)tp = make_float4(ssp_f(acc[i][0]), ssp_f(acc[i][1]),
                                   ssp_f(acc[i][2]), ssp_f(acc[i][3]));
        *(float4*)(tp + 4) = make_float4(ssp_f(acc[i][4]), ssp_f(acc[i][5]),
                                         ssp_f(acc[i][6]), ssp_f(acc[i][7]));
    }
    write_w64(pw0, BcW, tid);
    prefetch_w64(W_lin, 64, pw1, tid);
    __syncthreads();                    // B5

    init_acc_bias(acc, b_lin, ct);
    gemm_chunk<16>(At, LDA, 0, BcW, acc, rt, ct);
    __syncthreads();                    // B6
    write_w64(pw1, BcW, tid);
    __syncthreads();                    // B7
    gemm_chunk<16>(At, LDA, 64, BcW, acc, rt, ct);

#pragma unroll
    for (int i = 0; i < 4; ++i) {
        float* op = &out[(size_t)(n0 + rt * 4 + i) * DIM + ct * 8];
        *(float4*)op = make_float4(acc[i][0], acc[i][1], acc[i][2], acc[i][3]);
        *(float4*)(op + 4) = make_float4(acc[i][4], acc[i][5], acc[i][6], acc[i][7]);
    }
}

// ---------------- Atomic fallback (only if workspace too small) ----------------
__global__ __launch_bounds__(BLK, 2) void edge_kernel_atomic(const float* __restrict__ f_ij,
                                                             const float* __restrict__ r_ij,
                                                             const int* __restrict__ ind_i,
                                                             const int* __restrict__ ind_j,
                                                             const float* __restrict__ W_f1,
                                                             const float* __restrict__ b_f1,
                                                             const float* __restrict__ W_f2,
                                                             const float* __restrict__ b_f2,
                                                             const float* __restrict__ h,
                                                             float* __restrict__ agg) {
    __shared__ float fA[TROWS * NBP];
    __shared__ float t1[TROWS * LDA];
    __shared__ float BcW[64 * DIM];
    const int tid = threadIdx.x;
    const int rt = tid >> 4, ct = tid & 15;
    const int e0 = blockIdx.x * TROWS;

    stage_w1_lds(W_f1, BcW, tid);
    for (int i = tid; i < TROWS * NBP; i += BLK) {
        int row = i / NBP, c = i - row * NBP;
        float v = 0.f;
        if (c < NB) v = f_ij[(size_t)(e0 + row) * NB + c];
        fA[row * NBP + c] = v;
    }
    float4 pw0[8], pw1[8];
    prefetch_w64(W_f2, 0, pw0, tid);
    prefetch_w64(W_f2, 64, pw1, tid);
    __syncthreads();

    float acc[4][8];
    init_acc_bias(acc, b_f1, ct);
    gemm_chunk<13>(fA, NBP, 0, BcW, acc, rt, ct);
#pragma unroll
    for (int i = 0; i < 4; ++i) {
        float* tp = &t1[(rt * 4 + i) * LDA + ct * 8];
        *(float4*)tp = make_float4(ssp_f(acc[i][0]), ssp_f(acc[i][1]),
                                   ssp_f(acc[i][2]), ssp_f(acc[i][3]));
        *(float4*)(tp + 4) = make_float4(ssp_f(acc[i][4]), ssp_f(acc[i][5]),
                                         ssp_f(acc[i][6]), ssp_f(acc[i][7]));
    }
    __syncthreads();
    write_w64(pw0, BcW, tid);
    __syncthreads();
    init_acc_bias(acc, b_f2, ct);
    gemm_chunk<16>(t1, LDA, 0, BcW, acc, rt, ct);
    __syncthreads();
    write_w64(pw1, BcW, tid);
    __syncthreads();
    gemm_chunk<16>(t1, LDA, 64, BcW, acc, rt, ct);

#pragma unroll
    for (int i = 0; i < 4; ++i) {
        int e = e0 + rt * 4 + i;
        float r = r_ij[e];
        float C = (r < 5.0f) ? 0.5f * (cosf(r * PI_OVER_CUT) + 1.0f) : 0.0f;
        int nj = ind_j[e];
        int ni = ind_i[e];
        const float* hp = &h[(size_t)nj * DIM + ct * 8];
        float4 h0 = *(const float4*)hp;
        float4 h1 = *(const float4*)(hp + 4);
        float* ap = &agg[(size_t)ni * DIM + ct * 8];
        atomicAdd(ap + 0, h0.x * acc[i][0] * C);
        atomicAdd(ap + 1, h0.y * acc[i][1] * C);
        atomicAdd(ap + 2, h0.z * acc[i][2] * C);
        atomicAdd(ap + 3, h0.w * acc[i][3] * C);
        atomicAdd(ap + 4, h1.x * acc[i][4] * C);
        atomicAdd(ap + 5, h1.y * acc[i][5] * C);
        atomicAdd(ap + 6, h1.z * acc[i][6] * C);
        atomicAdd(ap + 7, h1.w * acc[i][7] * C);
    }
}

extern "C" void kernel_launch(void* const* d_in, const int* in_sizes, int n_in,
                              void* d_out, int out_size, void* d_ws, size_t ws_size,
                              hipStream_t stream) {
    const float* x      = (const float*)d_in[0];
    const float* r_ij   = (const float*)d_in[1];
    const float* f_ij   = (const float*)d_in[2];
    const int*   ind_i  = (const int*)d_in[3];
    const int*   ind_j  = (const int*)d_in[4];
    const float* W_in2f = (const float*)d_in[5];
    const float* W_f1   = (const float*)d_in[6];
    const float* b_f1   = (const float*)d_in[7];
    const float* W_f2   = (const float*)d_in[8];
    const float* b_f2   = (const float*)d_in[9];
    const float* W_out  = (const float*)d_in[10];
    const float* b_out  = (const float*)d_in[11];
    const float* W_lin  = (const float*)d_in[12];
    const float* b_lin  = (const float*)d_in[13];
    float* out = (float*)d_out;

    char* ws = (char*)d_ws;
    size_t off = 0;
    auto alloc = [&](size_t bytes) {
        char* p = ws + off;
        off = (off + bytes + 511) & ~(size_t)511;
        return p;
    };
    float* h      = (float*)alloc((size_t)N_NODES_C * DIM * sizeof(float));
    float* agg    = (float*)alloc((size_t)N_NODES_C * DIM * sizeof(float));
    float* msg    = (float*)alloc((size_t)N_EDGES_C * DIM * sizeof(float));
    int*   eids   = (int*)alloc((size_t)N_EDGES_C * sizeof(int));
    int*   cnt    = (int*)alloc((size_t)N_NODES_C * sizeof(int));
    int*   startA = (int*)alloc((size_t)N_NODES_C * sizeof(int));
    int*   cursor = (int*)alloc((size_t)N_NODES_C * sizeof(int));
    int*   bsum   = (int*)alloc((size_t)NSCAN_BLK * sizeof(int));
    const bool have_ws = (off <= ws_size);

    node_in2f_kernel<<<N_NODES_C / TROWS, BLK, 0, stream>>>(x, W_in2f, h);

    if (have_ws) {
        hipMemsetAsync(cnt, 0, (size_t)N_NODES_C * sizeof(int), stream);
        hist_kernel<<<(N_EDGES_C + BLK - 1) / BLK, BLK, 0, stream>>>(ind_i, cnt);
        scan1_kernel<<<NSCAN_BLK, BLK, 0, stream>>>(cnt, startA, bsum);
        scan2_kernel<<<1, BLK, 0, stream>>>(bsum);
        scan3_kernel<<<NSCAN_BLK, BLK, 0, stream>>>(startA, cursor, bsum);
        place_kernel<<<(N_EDGES_C + BLK - 1) / BLK, BLK, 0, stream>>>(ind_i, cursor, eids);

        edge_kernel_msg<<<N_EDGES_C / TROWS, BLK, 0, stream>>>(
            f_ij, r_ij, ind_j, W_f1, b_f1, W_f2, b_f2, h, msg);
        gather_kernel<<<(N_NODES_C + 3) / 4, BLK, 0, stream>>>(msg, eids, startA, cnt, agg);
    } else {
        hipMemsetAsync(agg, 0, (size_t)N_NODES_C * DIM * sizeof(float), stream);
        edge_kernel_atomic<<<N_EDGES_C / TROWS, BLK, 0, stream>>>(
            f_ij, r_ij, ind_i, ind_j, W_f1, b_f1, W_f2, b_f2, h, agg);
    }

    node_out_kernel<<<N_NODES_C / TROWS, BLK, 0, stream>>>(agg, W_out, b_out, W_lin, b_lin, out);
}

// Round 5
// 908.256 us; speedup vs baseline: 1.1573x; 1.1544x over previous
//
#include <hip/hip_runtime.h>

#define N_NODES_C 40000
#define N_EDGES_C 640000
#define DIM 128
#define NB 50
#define LDA 132       // padded A-tile leading dim (row stride 528B: 16B-aligned; 2-way banks = free)
#define BLK 256
#define TROWS 64
#define LOG2_C 0.6931471805599453f
#define PI_OVER_CUT 0.6283185307179586f  // pi/5
#define NSCAN_BLK 157  // ceil(40000/256)

__device__ __forceinline__ float ssp_f(float t) {
    return fmaxf(t, 0.0f) + log1pf(expf(-fabsf(t))) - LOG2_C;
}

// Stage a chunk of B[K][128] (row-major, rows k0..k0+rows) into LDS chunk buffer.
__device__ __forceinline__ void stage_chunk(const float* __restrict__ B, int k0, int rows,
                                            float* __restrict__ Bc, int tid) {
    const int n4 = rows * (DIM / 4);
    const float4* Bg = (const float4*)B + (size_t)k0 * (DIM / 4);
    float4* Bc4 = (float4*)Bc;
    for (int i = tid; i < n4; i += BLK) Bc4[i] = Bg[i];
}

// acc[4][8] += A_lds[64 rows][lda] @ Bglob[K=KPAD][128], staged via Bc in 32-row chunks.
template <int KPAD>
__device__ __forceinline__ void gemm_tile(const float* __restrict__ A_lds, int lda,
                                          const float* __restrict__ Bglob,
                                          float* __restrict__ Bc,
                                          float acc[4][8], int rt, int ct, int tid) {
    for (int k0 = 0; k0 < KPAD; k0 += 32) {
        __syncthreads();                       // previous chunk reads (and prior LDS writes) done
        stage_chunk(Bglob, k0, 32, Bc, tid);
        __syncthreads();                       // chunk visible
#pragma unroll 2
        for (int k4 = 0; k4 < 8; ++k4) {
            float4 av[4];
#pragma unroll
            for (int i = 0; i < 4; ++i)
                av[i] = *(const float4*)&A_lds[(rt * 4 + i) * lda + k0 + k4 * 4];
#pragma unroll
            for (int kk = 0; kk < 4; ++kk) {
                const float* bp = &Bc[(k4 * 4 + kk) * DIM + ct * 8];
                float4 b0 = *(const float4*)bp;
                float4 b1 = *(const float4*)(bp + 4);
#pragma unroll
                for (int i = 0; i < 4; ++i) {
                    float a = ((const float*)&av[i])[kk];
                    acc[i][0] = fmaf(a, b0.x, acc[i][0]);
                    acc[i][1] = fmaf(a, b0.y, acc[i][1]);
                    acc[i][2] = fmaf(a, b0.z, acc[i][2]);
                    acc[i][3] = fmaf(a, b0.w, acc[i][3]);
                    acc[i][4] = fmaf(a, b1.x, acc[i][4]);
                    acc[i][5] = fmaf(a, b1.y, acc[i][5]);
                    acc[i][6] = fmaf(a, b1.z, acc[i][6]);
                    acc[i][7] = fmaf(a, b1.w, acc[i][7]);
                }
            }
        }
    }
}

// GEMM1 with A read directly from global as float2 (8B-aligned: row*50*4B + k2*8B).
// B chunk (rows k2base*2 .. +NK2*2) already staged in Bc (chunk-local row = k2*2+kk).
template <int NK2>
__device__ __forceinline__ void gemm1_direct(const float* const (&frow)[4], int k2base,
                                             const float* __restrict__ Bc,
                                             float acc[4][8], int ct) {
#pragma unroll 4
    for (int k2 = 0; k2 < NK2; ++k2) {
        float2 a2[4];
#pragma unroll
        for (int i = 0; i < 4; ++i)
            a2[i] = *(const float2*)(frow[i] + (k2base + k2) * 2);
#pragma unroll
        for (int kk = 0; kk < 2; ++kk) {
            const float* bp = &Bc[(k2 * 2 + kk) * DIM + ct * 8];
            float4 b0 = *(const float4*)bp;
            float4 b1 = *(const float4*)(bp + 4);
#pragma unroll
            for (int i = 0; i < 4; ++i) {
                float a = kk ? a2[i].y : a2[i].x;
                acc[i][0] = fmaf(a, b0.x, acc[i][0]);
                acc[i][1] = fmaf(a, b0.y, acc[i][1]);
                acc[i][2] = fmaf(a, b0.z, acc[i][2]);
                acc[i][3] = fmaf(a, b0.w, acc[i][3]);
                acc[i][4] = fmaf(a, b1.x, acc[i][4]);
                acc[i][5] = fmaf(a, b1.y, acc[i][5]);
                acc[i][6] = fmaf(a, b1.z, acc[i][6]);
                acc[i][7] = fmaf(a, b1.w, acc[i][7]);
            }
        }
    }
}

__device__ __forceinline__ void init_acc_bias(float acc[4][8], const float* __restrict__ b, int ct) {
    float4 bb0 = *(const float4*)&b[ct * 8];
    float4 bb1 = *(const float4*)&b[ct * 8 + 4];
#pragma unroll
    for (int i = 0; i < 4; ++i) {
        acc[i][0] = bb0.x; acc[i][1] = bb0.y; acc[i][2] = bb0.z; acc[i][3] = bb0.w;
        acc[i][4] = bb1.x; acc[i][5] = bb1.y; acc[i][6] = bb1.z; acc[i][7] = bb1.w;
    }
}

// ---------------- Kernel: h = x @ W_in2f ----------------
__global__ __launch_bounds__(BLK) void node_in2f_kernel(const float* __restrict__ x,
                                                        const float* __restrict__ W,
                                                        float* __restrict__ h) {
    __shared__ float At[TROWS * LDA];   // 33.8 KB
    __shared__ float Bc[32 * DIM];      // 16 KB   -> 49 KB total: 3 blocks/CU
    const int tid = threadIdx.x;
    const int rt = tid >> 4, ct = tid & 15;
    const int n0 = blockIdx.x * TROWS;

    for (int i = tid; i < TROWS * (DIM / 4); i += BLK) {
        int row = i >> 5, c4 = i & 31;
        *(float4*)&At[row * LDA + c4 * 4] = *(const float4*)&x[(size_t)(n0 + row) * DIM + c4 * 4];
    }

    float acc[4][8];
#pragma unroll
    for (int i = 0; i < 4; ++i)
#pragma unroll
        for (int j = 0; j < 8; ++j) acc[i][j] = 0.f;

    gemm_tile<DIM>(At, LDA, W, Bc, acc, rt, ct, tid);

#pragma unroll
    for (int i = 0; i < 4; ++i) {
        float* hp = &h[(size_t)(n0 + rt * 4 + i) * DIM + ct * 8];
        *(float4*)hp = make_float4(acc[i][0], acc[i][1], acc[i][2], acc[i][3]);
        *(float4*)(hp + 4) = make_float4(acc[i][4], acc[i][5], acc[i][6], acc[i][7]);
    }
}

// ---------------- CSR build ----------------
__global__ __launch_bounds__(BLK) void hist_kernel(const int* __restrict__ ind_i,
                                                   int* __restrict__ cnt) {
    int e = blockIdx.x * BLK + threadIdx.x;
    if (e < N_EDGES_C) atomicAdd(&cnt[ind_i[e]], 1);
}

__global__ __launch_bounds__(BLK) void scan1_kernel(const int* __restrict__ cnt,
                                                    int* __restrict__ excl,
                                                    int* __restrict__ bsum) {
    __shared__ int s[BLK];
    const int tid = threadIdx.x;
    const int idx = blockIdx.x * BLK + tid;
    int v = (idx < N_NODES_C) ? cnt[idx] : 0;
    s[tid] = v;
    __syncthreads();
    for (int off = 1; off < BLK; off <<= 1) {
        int t = (tid >= off) ? s[tid - off] : 0;
        __syncthreads();
        s[tid] += t;
        __syncthreads();
    }
    if (idx < N_NODES_C) excl[idx] = s[tid] - v;
    if (tid == BLK - 1) bsum[blockIdx.x] = s[tid];
}

__global__ __launch_bounds__(BLK) void scan2_kernel(int* __restrict__ bsum) {
    __shared__ int s[BLK];
    const int tid = threadIdx.x;
    int v = (tid < NSCAN_BLK) ? bsum[tid] : 0;
    s[tid] = v;
    __syncthreads();
    for (int off = 1; off < BLK; off <<= 1) {
        int t = (tid >= off) ? s[tid - off] : 0;
        __syncthreads();
        s[tid] += t;
        __syncthreads();
    }
    if (tid < NSCAN_BLK) bsum[tid] = s[tid] - v;  // exclusive
}

__global__ __launch_bounds__(BLK) void scan3_kernel(int* __restrict__ start,
                                                    int* __restrict__ cursor,
                                                    const int* __restrict__ bsum) {
    const int idx = blockIdx.x * BLK + threadIdx.x;
    if (idx < N_NODES_C) {
        int v = start[idx] + bsum[blockIdx.x];
        start[idx] = v;
        cursor[idx] = v;
    }
}

__global__ __launch_bounds__(BLK) void place_kernel(const int* __restrict__ ind_i,
                                                    int* __restrict__ cursor,
                                                    int* __restrict__ eids) {
    int e = blockIdx.x * BLK + threadIdx.x;
    if (e < N_EDGES_C) {
        int slot = atomicAdd(&cursor[ind_i[e]], 1);
        eids[slot] = e;
    }
}

// ---------------- Edge kernel: msg = (ssp(f@W1+b1)@W2+b2) * C * h[ind_j] ----------------
__global__ __launch_bounds__(BLK) void edge_kernel_msg(const float* __restrict__ f_ij,
                                                       const float* __restrict__ r_ij,
                                                       const int* __restrict__ ind_j,
                                                       const float* __restrict__ W_f1,
                                                       const float* __restrict__ b_f1,
                                                       const float* __restrict__ W_f2,
                                                       const float* __restrict__ b_f2,
                                                       const float* __restrict__ h,
                                                       float* __restrict__ msg) {
    __shared__ float t1[TROWS * LDA];   // 33.8 KB
    __shared__ float Bc[32 * DIM];      // 16 KB   -> 49 KB total: 3 blocks/CU
    const int tid = threadIdx.x;
    const int rt = tid >> 4, ct = tid & 15;
    const int e0 = blockIdx.x * TROWS;  // 640000 % 64 == 0: all blocks full

    // A-operand row pointers (direct global; float2 loads are always 8B-aligned)
    const float* frow[4];
#pragma unroll
    for (int i = 0; i < 4; ++i) frow[i] = f_ij + (size_t)(e0 + rt * 4 + i) * NB;

    float acc[4][8];
    init_acc_bias(acc, b_f1, ct);

    // GEMM1 chunk 0: W1 rows 0..31
    stage_chunk(W_f1, 0, 32, Bc, tid);
    __syncthreads();
    gemm1_direct<16>(frow, 0, Bc, acc, ct);
    // GEMM1 chunk 1: W1 rows 32..49
    __syncthreads();
    stage_chunk(W_f1, 32, 18, Bc, tid);
    __syncthreads();
    gemm1_direct<9>(frow, 16, Bc, acc, ct);

    // t1 = ssp(acc)
#pragma unroll
    for (int i = 0; i < 4; ++i) {
        float* tp = &t1[(rt * 4 + i) * LDA + ct * 8];
        *(float4*)tp = make_float4(ssp_f(acc[i][0]), ssp_f(acc[i][1]),
                                   ssp_f(acc[i][2]), ssp_f(acc[i][3]));
        *(float4*)(tp + 4) = make_float4(ssp_f(acc[i][4]), ssp_f(acc[i][5]),
                                         ssp_f(acc[i][6]), ssp_f(acc[i][7]));
    }
    // gemm_tile's leading __syncthreads() covers: GEMM1 Bc reads done + t1 visible

    init_acc_bias(acc, b_f2, ct);
    gemm_tile<DIM>(t1, LDA, W_f2, Bc, acc, rt, ct, tid);

    // epilogue: cutoff, gather h[ind_j], write msg row
#pragma unroll
    for (int i = 0; i < 4; ++i) {
        int e = e0 + rt * 4 + i;
        float r = r_ij[e];
        float C = (r < 5.0f) ? 0.5f * (cosf(r * PI_OVER_CUT) + 1.0f) : 0.0f;
        int nj = ind_j[e];
        const float* hp = &h[(size_t)nj * DIM + ct * 8];
        float4 h0 = *(const float4*)hp;
        float4 h1 = *(const float4*)(hp + 4);
        float* mp = &msg[(size_t)e * DIM + ct * 8];
        *(float4*)mp = make_float4(h0.x * acc[i][0] * C, h0.y * acc[i][1] * C,
                                   h0.z * acc[i][2] * C, h0.w * acc[i][3] * C);
        *(float4*)(mp + 4) = make_float4(h1.x * acc[i][4] * C, h1.y * acc[i][5] * C,
                                         h1.z * acc[i][6] * C, h1.w * acc[i][7] * C);
    }
}

// ---------------- Gather: agg[n] = sum over CSR edges of msg ----------------
__global__ __launch_bounds__(BLK) void gather_kernel(const float* __restrict__ msg,
                                                     const int* __restrict__ eids,
                                                     const int* __restrict__ start,
                                                     const int* __restrict__ cnt,
                                                     float* __restrict__ agg) {
    const int wave = threadIdx.x >> 6;
    const int lane = threadIdx.x & 63;
    const int node = blockIdx.x * 4 + wave;
    if (node >= N_NODES_C) return;
    const int s = start[node];
    const int d = cnt[node];
    float ax = 0.f, ay = 0.f;
    int k = 0;
    for (; k + 1 < d; k += 2) {
        int ea = eids[s + k], eb = eids[s + k + 1];
        float2 va = *(const float2*)&msg[(size_t)ea * DIM + lane * 2];
        float2 vb = *(const float2*)&msg[(size_t)eb * DIM + lane * 2];
        ax += va.x + vb.x;
        ay += va.y + vb.y;
    }
    if (k < d) {
        int ea = eids[s + k];
        float2 va = *(const float2*)&msg[(size_t)ea * DIM + lane * 2];
        ax += va.x;
        ay += va.y;
    }
    *(float2*)&agg[(size_t)node * DIM + lane * 2] = make_float2(ax, ay);
}

// ---------------- Output: out = ssp(agg@W_out + b_out) @ W_lin + b_lin ----------------
__global__ __launch_bounds__(BLK) void node_out_kernel(const float* __restrict__ agg,
                                                       const float* __restrict__ W_out,
                                                       const float* __restrict__ b_out,
                                                       const float* __restrict__ W_lin,
                                                       const float* __restrict__ b_lin,
                                                       float* __restrict__ out) {
    __shared__ float At[TROWS * LDA];
    __shared__ float Bc[32 * DIM];
    const int tid = threadIdx.x;
    const int rt = tid >> 4, ct = tid & 15;
    const int n0 = blockIdx.x * TROWS;

    for (int i = tid; i < TROWS * (DIM / 4); i += BLK) {
        int row = i >> 5, c4 = i & 31;
        *(float4*)&At[row * LDA + c4 * 4] = *(const float4*)&agg[(size_t)(n0 + row) * DIM + c4 * 4];
    }

    float acc[4][8];
    init_acc_bias(acc, b_out, ct);
    gemm_tile<DIM>(At, LDA, W_out, Bc, acc, rt, ct, tid);

    __syncthreads();  // all At reads done before overwrite
#pragma unroll
    for (int i = 0; i < 4; ++i) {
        float* tp = &At[(rt * 4 + i) * LDA + ct * 8];
        *(float4*)tp = make_float4(ssp_f(acc[i][0]), ssp_f(acc[i][1]),
                                   ssp_f(acc[i][2]), ssp_f(acc[i][3]));
        *(float4*)(tp + 4) = make_float4(ssp_f(acc[i][4]), ssp_f(acc[i][5]),
                                         ssp_f(acc[i][6]), ssp_f(acc[i][7]));
    }

    init_acc_bias(acc, b_lin, ct);
    gemm_tile<DIM>(At, LDA, W_lin, Bc, acc, rt, ct, tid);

#pragma unroll
    for (int i = 0; i < 4; ++i) {
        float* op = &out[(size_t)(n0 + rt * 4 + i) * DIM + ct * 8];
        *(float4*)op = make_float4(acc[i][0], acc[i][1], acc[i][2], acc[i][3]);
        *(float4*)(op + 4) = make_float4(acc[i][4], acc[i][5], acc[i][6], acc[i][7]);
    }
}

// ---------------- Atomic fallback (only if workspace too small) ----------------
__global__ __launch_bounds__(BLK) void edge_kernel_atomic(const float* __restrict__ f_ij,
                                                          const float* __restrict__ r_ij,
                                                          const int* __restrict__ ind_i,
                                                          const int* __restrict__ ind_j,
                                                          const float* __restrict__ W_f1,
                                                          const float* __restrict__ b_f1,
                                                          const float* __restrict__ W_f2,
                                                          const float* __restrict__ b_f2,
                                                          const float* __restrict__ h,
                                                          float* __restrict__ agg) {
    __shared__ float t1[TROWS * LDA];
    __shared__ float Bc[32 * DIM];
    const int tid = threadIdx.x;
    const int rt = tid >> 4, ct = tid & 15;
    const int e0 = blockIdx.x * TROWS;

    const float* frow[4];
#pragma unroll
    for (int i = 0; i < 4; ++i) frow[i] = f_ij + (size_t)(e0 + rt * 4 + i) * NB;

    float acc[4][8];
    init_acc_bias(acc, b_f1, ct);
    stage_chunk(W_f1, 0, 32, Bc, tid);
    __syncthreads();
    gemm1_direct<16>(frow, 0, Bc, acc, ct);
    __syncthreads();
    stage_chunk(W_f1, 32, 18, Bc, tid);
    __syncthreads();
    gemm1_direct<9>(frow, 16, Bc, acc, ct);

#pragma unroll
    for (int i = 0; i < 4; ++i) {
        float* tp = &t1[(rt * 4 + i) * LDA + ct * 8];
        *(float4*)tp = make_float4(ssp_f(acc[i][0]), ssp_f(acc[i][1]),
                                   ssp_f(acc[i][2]), ssp_f(acc[i][3]));
        *(float4*)(tp + 4) = make_float4(ssp_f(acc[i][4]), ssp_f(acc[i][5]),
                                         ssp_f(acc[i][6]), ssp_f(acc[i][7]));
    }

    init_acc_bias(acc, b_f2, ct);
    gemm_tile<DIM>(t1, LDA, W_f2, Bc, acc, rt, ct, tid);

#pragma unroll
    for (int i = 0; i < 4; ++i) {
        int e = e0 + rt * 4 + i;
        float r = r_ij[e];
        float C = (r < 5.0f) ? 0.5f * (cosf(r * PI_OVER_CUT) + 1.0f) : 0.0f;
        int nj = ind_j[e];
        int ni = ind_i[e];
        const float* hp = &h[(size_t)nj * DIM + ct * 8];
        float4 h0 = *(const float4*)hp;
        float4 h1 = *(const float4*)(hp + 4);
        float* ap = &agg[(size_t)ni * DIM + ct * 8];
        atomicAdd(ap + 0, h0.x * acc[i][0] * C);
        atomicAdd(ap + 1, h0.y * acc[i][1] * C);
        atomicAdd(ap + 2, h0.z * acc[i][2] * C);
        atomicAdd(ap + 3, h0.w * acc[i][3] * C);
        atomicAdd(ap + 4, h1.x * acc[i][4] * C);
        atomicAdd(ap + 5, h1.y * acc[i][5] * C);
        atomicAdd(ap + 6, h1.z * acc[i][6] * C);
        atomicAdd(ap + 7, h1.w * acc[i][7] * C);
    }
}

extern "C" void kernel_launch(void* const* d_in, const int* in_sizes, int n_in,
                              void* d_out, int out_size, void* d_ws, size_t ws_size,
                              hipStream_t stream) {
    const float* x      = (const float*)d_in[0];
    const float* r_ij   = (const float*)d_in[1];
    const float* f_ij   = (const float*)d_in[2];
    const int*   ind_i  = (const int*)d_in[3];
    const int*   ind_j  = (const int*)d_in[4];
    const float* W_in2f = (const float*)d_in[5];
    const float* W_f1   = (const float*)d_in[6];
    const float* b_f1   = (const float*)d_in[7];
    const float* W_f2   = (const float*)d_in[8];
    const float* b_f2   = (const float*)d_in[9];
    const float* W_out  = (const float*)d_in[10];
    const float* b_out  = (const float*)d_in[11];
    const float* W_lin  = (const float*)d_in[12];
    const float* b_lin  = (const float*)d_in[13];
    float* out = (float*)d_out;

    char* ws = (char*)d_ws;
    size_t off = 0;
    auto alloc = [&](size_t bytes) {
        char* p = ws + off;
        off = (off + bytes + 511) & ~(size_t)511;
        return p;
    };
    float* h      = (float*)alloc((size_t)N_NODES_C * DIM * sizeof(float));
    float* agg    = (float*)alloc((size_t)N_NODES_C * DIM * sizeof(float));
    float* msg    = (float*)alloc((size_t)N_EDGES_C * DIM * sizeof(float));
    int*   eids   = (int*)alloc((size_t)N_EDGES_C * sizeof(int));
    int*   cnt    = (int*)alloc((size_t)N_NODES_C * sizeof(int));
    int*   startA = (int*)alloc((size_t)N_NODES_C * sizeof(int));
    int*   cursor = (int*)alloc((size_t)N_NODES_C * sizeof(int));
    int*   bsum   = (int*)alloc((size_t)NSCAN_BLK * sizeof(int));
    const bool have_ws = (off <= ws_size);

    node_in2f_kernel<<<N_NODES_C / TROWS, BLK, 0, stream>>>(x, W_in2f, h);

    if (have_ws) {
        hipMemsetAsync(cnt, 0, (size_t)N_NODES_C * sizeof(int), stream);
        hist_kernel<<<(N_EDGES_C + BLK - 1) / BLK, BLK, 0, stream>>>(ind_i, cnt);
        scan1_kernel<<<NSCAN_BLK, BLK, 0, stream>>>(cnt, startA, bsum);
        scan2_kernel<<<1, BLK, 0, stream>>>(bsum);
        scan3_kernel<<<NSCAN_BLK, BLK, 0, stream>>>(startA, cursor, bsum);
        place_kernel<<<(N_EDGES_C + BLK - 1) / BLK, BLK, 0, stream>>>(ind_i, cursor, eids);

        edge_kernel_msg<<<N_EDGES_C / TROWS, BLK, 0, stream>>>(
            f_ij, r_ij, ind_j, W_f1, b_f1, W_f2, b_f2, h, msg);
        gather_kernel<<<(N_NODES_C + 3) / 4, BLK, 0, stream>>>(msg, eids, startA, cnt, agg);
    } else {
        hipMemsetAsync(agg, 0, (size_t)N_NODES_C * DIM * sizeof(float), stream);
        edge_kernel_atomic<<<N_EDGES_C / TROWS, BLK, 0, stream>>>(
            f_ij, r_ij, ind_i, ind_j, W_f1, b_f1, W_f2, b_f2, h, agg);
    }

    node_out_kernel<<<N_NODES_C / TROWS, BLK, 0, stream>>>(agg, W_out, b_out, W_lin, b_lin, out);
}

// Round 6
// 785.334 us; speedup vs baseline: 1.3384x; 1.1565x over previous
//
#include <hip/hip_runtime.h>

#define N_NODES_C 40000
#define N_EDGES_C 640000
#define DIM 128
#define NB 50
#define LDA 132       // padded A-tile leading dim for f32 vector-GEMM tiles
#define BLK 256
#define TROWS 64
#define LOG2_C 0.6931471805599453f
#define PI_OVER_CUT 0.6283185307179586f  // pi/5
#define NSCAN_BLK 157  // ceil(40000/256)

// ---- MFMA fragment types (per guide: short-based ext vectors, compile-verified on gfx950)
typedef __attribute__((ext_vector_type(8))) short s8v;   // 8 bf16 = A/B frag of 16x16x32
typedef __attribute__((ext_vector_type(4))) short s4v;   // 4 bf16 (8B LDS write)
typedef __attribute__((ext_vector_type(4))) float f4v;   // C/D frag

// fp32 -> bf16 (RNE) bit-twiddle; inputs here are always finite
__device__ __forceinline__ unsigned short f2bf(float x) {
    unsigned int u = __float_as_uint(x);
    u += 0x7fffu + ((u >> 16) & 1u);
    return (unsigned short)(u >> 16);
}
__device__ __forceinline__ float bf2f(unsigned short h) {
    return __uint_as_float(((unsigned int)h) << 16);
}

__device__ __forceinline__ float ssp_f(float t) {
    return fmaxf(t, 0.0f) + log1pf(expf(-fabsf(t))) - LOG2_C;
}

// ---------------- old (vector) helpers: used by node kernels + atomic fallback ----------------
__device__ __forceinline__ void stage_chunk(const float* __restrict__ B, int k0, int rows,
                                            float* __restrict__ Bc, int tid) {
    const int n4 = rows * (DIM / 4);
    const float4* Bg = (const float4*)B + (size_t)k0 * (DIM / 4);
    float4* Bc4 = (float4*)Bc;
    for (int i = tid; i < n4; i += BLK) Bc4[i] = Bg[i];
}

template <int KPAD>
__device__ __forceinline__ void gemm_tile(const float* __restrict__ A_lds, int lda,
                                          const float* __restrict__ Bglob,
                                          float* __restrict__ Bc,
                                          float acc[4][8], int rt, int ct, int tid) {
    for (int k0 = 0; k0 < KPAD; k0 += 32) {
        __syncthreads();
        stage_chunk(Bglob, k0, 32, Bc, tid);
        __syncthreads();
#pragma unroll 2
        for (int k4 = 0; k4 < 8; ++k4) {
            float4 av[4];
#pragma unroll
            for (int i = 0; i < 4; ++i)
                av[i] = *(const float4*)&A_lds[(rt * 4 + i) * lda + k0 + k4 * 4];
#pragma unroll
            for (int kk = 0; kk < 4; ++kk) {
                const float* bp = &Bc[(k4 * 4 + kk) * DIM + ct * 8];
                float4 b0 = *(const float4*)bp;
                float4 b1 = *(const float4*)(bp + 4);
#pragma unroll
                for (int i = 0; i < 4; ++i) {
                    float a = ((const float*)&av[i])[kk];
                    acc[i][0] = fmaf(a, b0.x, acc[i][0]);
                    acc[i][1] = fmaf(a, b0.y, acc[i][1]);
                    acc[i][2] = fmaf(a, b0.z, acc[i][2]);
                    acc[i][3] = fmaf(a, b0.w, acc[i][3]);
                    acc[i][4] = fmaf(a, b1.x, acc[i][4]);
                    acc[i][5] = fmaf(a, b1.y, acc[i][5]);
                    acc[i][6] = fmaf(a, b1.z, acc[i][6]);
                    acc[i][7] = fmaf(a, b1.w, acc[i][7]);
                }
            }
        }
    }
}

// old row-major GEMM1 (atomic fallback only)
template <int NK2>
__device__ __forceinline__ void gemm1_direct(const float* const (&frow)[4], int k2base,
                                             const float* __restrict__ Bc,
                                             float acc[4][8], int ct) {
#pragma unroll 4
    for (int k2 = 0; k2 < NK2; ++k2) {
        float2 a2[4];
#pragma unroll
        for (int i = 0; i < 4; ++i)
            a2[i] = *(const float2*)(frow[i] + (k2base + k2) * 2);
#pragma unroll
        for (int kk = 0; kk < 2; ++kk) {
            const float* bp = &Bc[(k2 * 2 + kk) * DIM + ct * 8];
            float4 b0 = *(const float4*)bp;
            float4 b1 = *(const float4*)(bp + 4);
#pragma unroll
            for (int i = 0; i < 4; ++i) {
                float a = kk ? a2[i].y : a2[i].x;
                acc[i][0] = fmaf(a, b0.x, acc[i][0]);
                acc[i][1] = fmaf(a, b0.y, acc[i][1]);
                acc[i][2] = fmaf(a, b0.z, acc[i][2]);
                acc[i][3] = fmaf(a, b0.w, acc[i][3]);
                acc[i][4] = fmaf(a, b1.x, acc[i][4]);
                acc[i][5] = fmaf(a, b1.y, acc[i][5]);
                acc[i][6] = fmaf(a, b1.z, acc[i][6]);
                acc[i][7] = fmaf(a, b1.w, acc[i][7]);
            }
        }
    }
}

// ---------------- new helpers for MFMA edge kernel ----------------
// grouped B stage: W rows k0..k0+R-1 of [*,128] -> Bc[16 grp][<=32 k][8] (grp stride 260 words)
// banks: read addr word = ct*260 -> ct*4 mod 32: ct,ct+8 alias = 2-way (free, m136)
__device__ __forceinline__ void stage_wg(const float* __restrict__ W, int k0, int R,
                                         float* __restrict__ Bc, int tid) {
    for (int i = tid; i < R * 32; i += BLK) {
        int k = i >> 5, c4 = i & 31;
        float4 v = *(const float4*)&W[(size_t)(k0 + k) * DIM + c4 * 4];
        *(float4*)&Bc[(c4 >> 1) * 260 + k * 8 + (c4 & 1) * 4] = v;
    }
}

// GEMM1 A from global (float2, 8B-aligned since rows are 50 floats), grouped-B from LDS
template <int NK2>
__device__ __forceinline__ void gemm1g(const float* const (&frow)[4], int k2base,
                                       const float* __restrict__ Bc,
                                       float acc[4][8], int ct) {
#pragma unroll 4
    for (int k2 = 0; k2 < NK2; ++k2) {
        float2 a2[4];
#pragma unroll
        for (int i = 0; i < 4; ++i)
            a2[i] = *(const float2*)(frow[i] + (k2base + k2) * 2);
#pragma unroll
        for (int kk = 0; kk < 2; ++kk) {
            const float* bp = &Bc[ct * 260 + (k2 * 2 + kk) * 8];
            float4 b0 = *(const float4*)bp;
            float4 b1 = *(const float4*)(bp + 4);
#pragma unroll
            for (int i = 0; i < 4; ++i) {
                float a = kk ? a2[i].y : a2[i].x;
                acc[i][0] = fmaf(a, b0.x, acc[i][0]);
                acc[i][1] = fmaf(a, b0.y, acc[i][1]);
                acc[i][2] = fmaf(a, b0.z, acc[i][2]);
                acc[i][3] = fmaf(a, b0.w, acc[i][3]);
                acc[i][4] = fmaf(a, b1.x, acc[i][4]);
                acc[i][5] = fmaf(a, b1.y, acc[i][5]);
                acc[i][6] = fmaf(a, b1.z, acc[i][6]);
                acc[i][7] = fmaf(a, b1.w, acc[i][7]);
            }
        }
    }
}

__device__ __forceinline__ void init_acc_bias(float acc[4][8], const float* __restrict__ b, int ct) {
    float4 bb0 = *(const float4*)&b[ct * 8];
    float4 bb1 = *(const float4*)&b[ct * 8 + 4];
#pragma unroll
    for (int i = 0; i < 4; ++i) {
        acc[i][0] = bb0.x; acc[i][1] = bb0.y; acc[i][2] = bb0.z; acc[i][3] = bb0.w;
        acc[i][4] = bb1.x; acc[i][5] = bb1.y; acc[i][6] = bb1.z; acc[i][7] = bb1.w;
    }
}

// ---------------- Kernel: h = x @ W_in2f (unchanged, vector) ----------------
__global__ __launch_bounds__(BLK) void node_in2f_kernel(const float* __restrict__ x,
                                                        const float* __restrict__ W,
                                                        float* __restrict__ h) {
    __shared__ float At[TROWS * LDA];
    __shared__ float Bc[32 * DIM];
    const int tid = threadIdx.x;
    const int rt = tid >> 4, ct = tid & 15;
    const int n0 = blockIdx.x * TROWS;

    for (int i = tid; i < TROWS * (DIM / 4); i += BLK) {
        int row = i >> 5, c4 = i & 31;
        *(float4*)&At[row * LDA + c4 * 4] = *(const float4*)&x[(size_t)(n0 + row) * DIM + c4 * 4];
    }

    float acc[4][8];
#pragma unroll
    for (int i = 0; i < 4; ++i)
#pragma unroll
        for (int j = 0; j < 8; ++j) acc[i][j] = 0.f;

    gemm_tile<DIM>(At, LDA, W, Bc, acc, rt, ct, tid);

#pragma unroll
    for (int i = 0; i < 4; ++i) {
        float* hp = &h[(size_t)(n0 + rt * 4 + i) * DIM + ct * 8];
        *(float4*)hp = make_float4(acc[i][0], acc[i][1], acc[i][2], acc[i][3]);
        *(float4*)(hp + 4) = make_float4(acc[i][4], acc[i][5], acc[i][6], acc[i][7]);
    }
}

// ---------------- CSR build ----------------
__global__ __launch_bounds__(BLK) void hist_kernel(const int* __restrict__ ind_i,
                                                   int* __restrict__ cnt) {
    int e = blockIdx.x * BLK + threadIdx.x;
    if (e < N_EDGES_C) atomicAdd(&cnt[ind_i[e]], 1);
}

__global__ __launch_bounds__(BLK) void scan1_kernel(const int* __restrict__ cnt,
                                                    int* __restrict__ excl,
                                                    int* __restrict__ bsum) {
    __shared__ int s[BLK];
    const int tid = threadIdx.x;
    const int idx = blockIdx.x * BLK + tid;
    int v = (idx < N_NODES_C) ? cnt[idx] : 0;
    s[tid] = v;
    __syncthreads();
    for (int off = 1; off < BLK; off <<= 1) {
        int t = (tid >= off) ? s[tid - off] : 0;
        __syncthreads();
        s[tid] += t;
        __syncthreads();
    }
    if (idx < N_NODES_C) excl[idx] = s[tid] - v;
    if (tid == BLK - 1) bsum[blockIdx.x] = s[tid];
}

__global__ __launch_bounds__(BLK) void scan2_kernel(int* __restrict__ bsum) {
    __shared__ int s[BLK];
    const int tid = threadIdx.x;
    int v = (tid < NSCAN_BLK) ? bsum[tid] : 0;
    s[tid] = v;
    __syncthreads();
    for (int off = 1; off < BLK; off <<= 1) {
        int t = (tid >= off) ? s[tid - off] : 0;
        __syncthreads();
        s[tid] += t;
        __syncthreads();
    }
    if (tid < NSCAN_BLK) bsum[tid] = s[tid] - v;  // exclusive
}

__global__ __launch_bounds__(BLK) void scan3_kernel(int* __restrict__ start,
                                                    int* __restrict__ cursor,
                                                    const int* __restrict__ bsum) {
    const int idx = blockIdx.x * BLK + threadIdx.x;
    if (idx < N_NODES_C) {
        int v = start[idx] + bsum[blockIdx.x];
        start[idx] = v;
        cursor[idx] = v;
    }
}

__global__ __launch_bounds__(BLK) void place_kernel(const int* __restrict__ ind_i,
                                                    int* __restrict__ cursor,
                                                    int* __restrict__ eids) {
    int e = blockIdx.x * BLK + threadIdx.x;
    if (e < N_EDGES_C) {
        int slot = atomicAdd(&cursor[ind_i[e]], 1);
        eids[slot] = e;
    }
}

// ---------------- Edge kernel: GEMM1 vector + GEMM2 MFMA(split-bf16) ----------------
// LDS map:
//   region0 (34816B): t1_hi[64][136] ushort + t1_lo[64][136]  (stride 136: 16B-aligned rows,
//                     bank = row*4 mod 32 -> 2-way free)   ALIAS: epi f32[64][132] (33792B)
//   region1 (20480B): Wt_hi[128][40] ushort + Wt_lo[128][40] (transposed W2 chunk, col stride 40:
//                     16B-aligned, bank = col*20 mod 32 -> 2-way free)
//                     ALIAS: Bc f32[16*260] grouped W1 (16640B), GEMM1 phase only
__global__ __launch_bounds__(BLK) void edge_kernel_msg(const float* __restrict__ f_ij,
                                                       const float* __restrict__ r_ij,
                                                       const int* __restrict__ ind_j,
                                                       const float* __restrict__ W_f1,
                                                       const float* __restrict__ b_f1,
                                                       const float* __restrict__ W_f2,
                                                       const float* __restrict__ b_f2,
                                                       const float* __restrict__ h,
                                                       float* __restrict__ msg) {
    __shared__ __align__(16) char smem[34816 + 20480];
    unsigned short* t1_hi = (unsigned short*)smem;            // [64][136]
    unsigned short* t1_lo = t1_hi + 64 * 136;
    float*          epi   = (float*)smem;                     // [64][132] (alias, post-GEMM2)
    float*          Bc    = (float*)(smem + 34816);           // [16*260] (alias, GEMM1)
    unsigned short* Wt_hi = (unsigned short*)(smem + 34816);  // [128][40]
    unsigned short* Wt_lo = Wt_hi + 128 * 40;

    const int tid = threadIdx.x;
    const int rt = tid >> 4, ct = tid & 15;
    const int e0 = blockIdx.x * TROWS;  // 640000 % 64 == 0

    // ---- GEMM1 (vector): t_pre = f @ W1 + b1, K = 50 = 32 + 18
    const float* frow[4];
#pragma unroll
    for (int i = 0; i < 4; ++i) frow[i] = f_ij + (size_t)(e0 + rt * 4 + i) * NB;

    float acc[4][8];
    init_acc_bias(acc, b_f1, ct);

    stage_wg(W_f1, 0, 32, Bc, tid);
    __syncthreads();
    gemm1g<16>(frow, 0, Bc, acc, ct);
    __syncthreads();
    stage_wg(W_f1, 32, 18, Bc, tid);
    __syncthreads();
    gemm1g<9>(frow, 16, Bc, acc, ct);

    // ---- t1 = ssp(acc), split to bf16 hi/lo (wave-local rows: wave w owns rows 16w..16w+15)
#pragma unroll
    for (int i = 0; i < 4; ++i) {
        s8v vh, vl;
#pragma unroll
        for (int j = 0; j < 8; ++j) {
            float s = ssp_f(acc[i][j]);
            unsigned short hb = f2bf(s);
            vh[j] = (short)hb;
            vl[j] = (short)f2bf(s - bf2f(hb));
        }
        int row = rt * 4 + i;
        *(s8v*)&t1_hi[row * 136 + ct * 8] = vh;
        *(s8v*)&t1_lo[row * 136 + ct * 8] = vl;
    }

    // ---- GEMM2 (MFMA 16x16x32 bf16, 3-term split): C = t1 @ W2 + b2
    const int w  = tid >> 6;   // wave 0..3 -> rows 16w..16w+15
    const int l  = tid & 63;
    const int lr = l & 15;     // A-row / B-col / C-col within tile
    const int lk = l >> 4;     // k-block: k = lk*8 + j

    f4v acc2[8];
#pragma unroll
    for (int t = 0; t < 8; ++t) {
        float bv = b_f2[t * 16 + lr];
        acc2[t] = (f4v){bv, bv, bv, bv};
    }
    const int rowA = 16 * w + lr;

    for (int kc = 0; kc < 4; ++kc) {
        __syncthreads();  // prior Bc/Wt reads done before overwrite
        // stage W2 chunk kc: transpose + split. thread = (kb = tid&7, cb = tid>>3)
        {
            int kb = tid & 7, cb = tid >> 3;
            const float* src = W_f2 + (size_t)(kc * 32 + kb * 4) * DIM + cb * 4;
            float4 r0 = *(const float4*)src;
            float4 r1 = *(const float4*)(src + DIM);
            float4 r2 = *(const float4*)(src + 2 * DIM);
            float4 r3 = *(const float4*)(src + 3 * DIM);
#pragma unroll
            for (int j = 0; j < 4; ++j) {
                float v0 = (&r0.x)[j], v1 = (&r1.x)[j], v2 = (&r2.x)[j], v3 = (&r3.x)[j];
                unsigned short h0 = f2bf(v0), h1 = f2bf(v1), h2 = f2bf(v2), h3 = f2bf(v3);
                s4v vh = {(short)h0, (short)h1, (short)h2, (short)h3};
                s4v vl = {(short)f2bf(v0 - bf2f(h0)), (short)f2bf(v1 - bf2f(h1)),
                          (short)f2bf(v2 - bf2f(h2)), (short)f2bf(v3 - bf2f(h3))};
                int col = cb * 4 + j;
                *(s4v*)&Wt_hi[col * 40 + kb * 4] = vh;
                *(s4v*)&Wt_lo[col * 40 + kb * 4] = vl;
            }
        }
        __syncthreads();  // chunk visible

        s8v Ah = *(const s8v*)&t1_hi[rowA * 136 + kc * 32 + lk * 8];
        s8v Al = *(const s8v*)&t1_lo[rowA * 136 + kc * 32 + lk * 8];
#pragma unroll
        for (int t = 0; t < 8; ++t) {
            s8v Bh = *(const s8v*)&Wt_hi[(t * 16 + lr) * 40 + lk * 8];
            s8v Bl = *(const s8v*)&Wt_lo[(t * 16 + lr) * 40 + lk * 8];
            acc2[t] = __builtin_amdgcn_mfma_f32_16x16x32_bf16(Ah, Bl, acc2[t], 0, 0, 0);
            acc2[t] = __builtin_amdgcn_mfma_f32_16x16x32_bf16(Al, Bh, acc2[t], 0, 0, 0);
            acc2[t] = __builtin_amdgcn_mfma_f32_16x16x32_bf16(Ah, Bh, acc2[t], 0, 0, 0);
        }
    }

    // ---- transpose C-frags through LDS (C layout: col = lr, row = lk*4 + r; m89-verified)
    __syncthreads();  // all t1/Wt reads done before epi overwrites region0
#pragma unroll
    for (int t = 0; t < 8; ++t)
#pragma unroll
        for (int r = 0; r < 4; ++r)
            epi[(16 * w + lk * 4 + r) * 132 + t * 16 + lr] = acc2[t][r];
    __syncthreads();

    // ---- epilogue (vectorized, old layout): cutoff, gather h[ind_j], write msg row
#pragma unroll
    for (int i = 0; i < 4; ++i) {
        int e = e0 + rt * 4 + i;
        float r = r_ij[e];
        float C = (r < 5.0f) ? 0.5f * (cosf(r * PI_OVER_CUT) + 1.0f) : 0.0f;
        int nj = ind_j[e];
        const float* hp = &h[(size_t)nj * DIM + ct * 8];
        float4 h0 = *(const float4*)hp;
        float4 h1 = *(const float4*)(hp + 4);
        const float* ep = &epi[(rt * 4 + i) * 132 + ct * 8];
        float4 a0 = *(const float4*)ep;
        float4 a1 = *(const float4*)(ep + 4);
        float* mp = &msg[(size_t)e * DIM + ct * 8];
        *(float4*)mp = make_float4(h0.x * a0.x * C, h0.y * a0.y * C,
                                   h0.z * a0.z * C, h0.w * a0.w * C);
        *(float4*)(mp + 4) = make_float4(h1.x * a1.x * C, h1.y * a1.y * C,
                                         h1.z * a1.z * C, h1.w * a1.w * C);
    }
}

// ---------------- Gather: agg[n] = sum over CSR edges of msg ----------------
__global__ __launch_bounds__(BLK) void gather_kernel(const float* __restrict__ msg,
                                                     const int* __restrict__ eids,
                                                     const int* __restrict__ start,
                                                     const int* __restrict__ cnt,
                                                     float* __restrict__ agg) {
    const int wave = threadIdx.x >> 6;
    const int lane = threadIdx.x & 63;
    const int node = blockIdx.x * 4 + wave;
    if (node >= N_NODES_C) return;
    const int s = start[node];
    const int d = cnt[node];
    float ax = 0.f, ay = 0.f;
    int k = 0;
    for (; k + 1 < d; k += 2) {
        int ea = eids[s + k], eb = eids[s + k + 1];
        float2 va = *(const float2*)&msg[(size_t)ea * DIM + lane * 2];
        float2 vb = *(const float2*)&msg[(size_t)eb * DIM + lane * 2];
        ax += va.x + vb.x;
        ay += va.y + vb.y;
    }
    if (k < d) {
        int ea = eids[s + k];
        float2 va = *(const float2*)&msg[(size_t)ea * DIM + lane * 2];
        ax += va.x;
        ay += va.y;
    }
    *(float2*)&agg[(size_t)node * DIM + lane * 2] = make_float2(ax, ay);
}

// ---------------- Output: out = ssp(agg@W_out + b_out) @ W_lin + b_lin (unchanged) ----------------
__global__ __launch_bounds__(BLK) void node_out_kernel(const float* __restrict__ agg,
                                                       const float* __restrict__ W_out,
                                                       const float* __restrict__ b_out,
                                                       const float* __restrict__ W_lin,
                                                       const float* __restrict__ b_lin,
                                                       float* __restrict__ out) {
    __shared__ float At[TROWS * LDA];
    __shared__ float Bc[32 * DIM];
    const int tid = threadIdx.x;
    const int rt = tid >> 4, ct = tid & 15;
    const int n0 = blockIdx.x * TROWS;

    for (int i = tid; i < TROWS * (DIM / 4); i += BLK) {
        int row = i >> 5, c4 = i & 31;
        *(float4*)&At[row * LDA + c4 * 4] = *(const float4*)&agg[(size_t)(n0 + row) * DIM + c4 * 4];
    }

    float acc[4][8];
    init_acc_bias(acc, b_out, ct);
    gemm_tile<DIM>(At, LDA, W_out, Bc, acc, rt, ct, tid);

    __syncthreads();
#pragma unroll
    for (int i = 0; i < 4; ++i) {
        float* tp = &At[(rt * 4 + i) * LDA + ct * 8];
        *(float4*)tp = make_float4(ssp_f(acc[i][0]), ssp_f(acc[i][1]),
                                   ssp_f(acc[i][2]), ssp_f(acc[i][3]));
        *(float4*)(tp + 4) = make_float4(ssp_f(acc[i][4]), ssp_f(acc[i][5]),
                                         ssp_f(acc[i][6]), ssp_f(acc[i][7]));
    }

    init_acc_bias(acc, b_lin, ct);
    gemm_tile<DIM>(At, LDA, W_lin, Bc, acc, rt, ct, tid);

#pragma unroll
    for (int i = 0; i < 4; ++i) {
        float* op = &out[(size_t)(n0 + rt * 4 + i) * DIM + ct * 8];
        *(float4*)op = make_float4(acc[i][0], acc[i][1], acc[i][2], acc[i][3]);
        *(float4*)(op + 4) = make_float4(acc[i][4], acc[i][5], acc[i][6], acc[i][7]);
    }
}

// ---------------- Atomic fallback (only if workspace too small; vector path) ----------------
__global__ __launch_bounds__(BLK) void edge_kernel_atomic(const float* __restrict__ f_ij,
                                                          const float* __restrict__ r_ij,
                                                          const int* __restrict__ ind_i,
                                                          const int* __restrict__ ind_j,
                                                          const float* __restrict__ W_f1,
                                                          const float* __restrict__ b_f1,
                                                          const float* __restrict__ W_f2,
                                                          const float* __restrict__ b_f2,
                                                          const float* __restrict__ h,
                                                          float* __restrict__ agg) {
    __shared__ float t1[TROWS * LDA];
    __shared__ float Bc[32 * DIM];
    const int tid = threadIdx.x;
    const int rt = tid >> 4, ct = tid & 15;
    const int e0 = blockIdx.x * TROWS;

    const float* frow[4];
#pragma unroll
    for (int i = 0; i < 4; ++i) frow[i] = f_ij + (size_t)(e0 + rt * 4 + i) * NB;

    float acc[4][8];
    init_acc_bias(acc, b_f1, ct);
    stage_chunk(W_f1, 0, 32, Bc, tid);
    __syncthreads();
    gemm1_direct<16>(frow, 0, Bc, acc, ct);
    __syncthreads();
    stage_chunk(W_f1, 32, 18, Bc, tid);
    __syncthreads();
    gemm1_direct<9>(frow, 16, Bc, acc, ct);

#pragma unroll
    for (int i = 0; i < 4; ++i) {
        float* tp = &t1[(rt * 4 + i) * LDA + ct * 8];
        *(float4*)tp = make_float4(ssp_f(acc[i][0]), ssp_f(acc[i][1]),
                                   ssp_f(acc[i][2]), ssp_f(acc[i][3]));
        *(float4*)(tp + 4) = make_float4(ssp_f(acc[i][4]), ssp_f(acc[i][5]),
                                         ssp_f(acc[i][6]), ssp_f(acc[i][7]));
    }

    init_acc_bias(acc, b_f2, ct);
    gemm_tile<DIM>(t1, LDA, W_f2, Bc, acc, rt, ct, tid);

#pragma unroll
    for (int i = 0; i < 4; ++i) {
        int e = e0 + rt * 4 + i;
        float r = r_ij[e];
        float C = (r < 5.0f) ? 0.5f * (cosf(r * PI_OVER_CUT) + 1.0f) : 0.0f;
        int nj = ind_j[e];
        int ni = ind_i[e];
        const float* hp = &h[(size_t)nj * DIM + ct * 8];
        float4 h0 = *(const float4*)hp;
        float4 h1 = *(const float4*)(hp + 4);
        float* ap = &agg[(size_t)ni * DIM + ct * 8];
        atomicAdd(ap + 0, h0.x * acc[i][0] * C);
        atomicAdd(ap + 1, h0.y * acc[i][1] * C);
        atomicAdd(ap + 2, h0.z * acc[i][2] * C);
        atomicAdd(ap + 3, h0.w * acc[i][3] * C);
        atomicAdd(ap + 4, h1.x * acc[i][4] * C);
        atomicAdd(ap + 5, h1.y * acc[i][5] * C);
        atomicAdd(ap + 6, h1.z * acc[i][6] * C);
        atomicAdd(ap + 7, h1.w * acc[i][7] * C);
    }
}

extern "C" void kernel_launch(void* const* d_in, const int* in_sizes, int n_in,
                              void* d_out, int out_size, void* d_ws, size_t ws_size,
                              hipStream_t stream) {
    const float* x      = (const float*)d_in[0];
    const float* r_ij   = (const float*)d_in[1];
    const float* f_ij   = (const float*)d_in[2];
    const int*   ind_i  = (const int*)d_in[3];
    const int*   ind_j  = (const int*)d_in[4];
    const float* W_in2f = (const float*)d_in[5];
    const float* W_f1   = (const float*)d_in[6];
    const float* b_f1   = (const float*)d_in[7];
    const float* W_f2   = (const float*)d_in[8];
    const float* b_f2   = (const float*)d_in[9];
    const float* W_out  = (const float*)d_in[10];
    const float* b_out  = (const float*)d_in[11];
    const float* W_lin  = (const float*)d_in[12];
    const float* b_lin  = (const float*)d_in[13];
    float* out = (float*)d_out;

    char* ws = (char*)d_ws;
    size_t off = 0;
    auto alloc = [&](size_t bytes) {
        char* p = ws + off;
        off = (off + bytes + 511) & ~(size_t)511;
        return p;
    };
    float* h      = (float*)alloc((size_t)N_NODES_C * DIM * sizeof(float));
    float* agg    = (float*)alloc((size_t)N_NODES_C * DIM * sizeof(float));
    float* msg    = (float*)alloc((size_t)N_EDGES_C * DIM * sizeof(float));
    int*   eids   = (int*)alloc((size_t)N_EDGES_C * sizeof(int));
    int*   cnt    = (int*)alloc((size_t)N_NODES_C * sizeof(int));
    int*   startA = (int*)alloc((size_t)N_NODES_C * sizeof(int));
    int*   cursor = (int*)alloc((size_t)N_NODES_C * sizeof(int));
    int*   bsum   = (int*)alloc((size_t)NSCAN_BLK * sizeof(int));
    const bool have_ws = (off <= ws_size);

    node_in2f_kernel<<<N_NODES_C / TROWS, BLK, 0, stream>>>(x, W_in2f, h);

    if (have_ws) {
        hipMemsetAsync(cnt, 0, (size_t)N_NODES_C * sizeof(int), stream);
        hist_kernel<<<(N_EDGES_C + BLK - 1) / BLK, BLK, 0, stream>>>(ind_i, cnt);
        scan1_kernel<<<NSCAN_BLK, BLK, 0, stream>>>(cnt, startA, bsum);
        scan2_kernel<<<1, BLK, 0, stream>>>(bsum);
        scan3_kernel<<<NSCAN_BLK, BLK, 0, stream>>>(startA, cursor, bsum);
        place_kernel<<<(N_EDGES_C + BLK - 1) / BLK, BLK, 0, stream>>>(ind_i, cursor, eids);

        edge_kernel_msg<<<N_EDGES_C / TROWS, BLK, 0, stream>>>(
            f_ij, r_ij, ind_j, W_f1, b_f1, W_f2, b_f2, h, msg);
        gather_kernel<<<(N_NODES_C + 3) / 4, BLK, 0, stream>>>(msg, eids, startA, cnt, agg);
    } else {
        hipMemsetAsync(agg, 0, (size_t)N_NODES_C * DIM * sizeof(float), stream);
        edge_kernel_atomic<<<N_EDGES_C / TROWS, BLK, 0, stream>>>(
            f_ij, r_ij, ind_i, ind_j, W_f1, b_f1, W_f2, b_f2, h, agg);
    }

    node_out_kernel<<<N_NODES_C / TROWS, BLK, 0, stream>>>(agg, W_out, b_out, W_lin, b_lin, out);
}

// Round 7
// 531.549 us; speedup vs baseline: 1.9774x; 1.4774x over previous
//
#include <hip/hip_runtime.h>

#define N_NODES_C 40000
#define N_EDGES_C 640000
#define DIM 128
#define NB 50
#define LDA 132       // f32 transpose-buffer leading dim (528B rows: 16B-aligned)
#define BLK 256
#define TROWS 64
#define LOG2_C 0.6931471805599453f
#define PI_OVER_CUT 0.6283185307179586f  // pi/5
#define NSCAN_BLK 157  // ceil(40000/256)

typedef __attribute__((ext_vector_type(8))) short s8v;   // 8 bf16 = A/B frag of 16x16x32
typedef __attribute__((ext_vector_type(4))) float f4v;   // C/D frag

#define MFMA_BF16 __builtin_amdgcn_mfma_f32_16x16x32_bf16

// Wsplit segment offsets (ushort units). Layout per weight: [nc][128 col][40] with
// k in [0,32) at col*40+k (40-stride for bank spread; slots 32..39 unused).
#define SEG_IN2F_H 0
#define SEG_IN2F_L 20480
#define SEG_F1_H   40960
#define SEG_F1_L   51200
#define SEG_F2_H   61440
#define SEG_F2_L   81920
#define SEG_OUT_H  102400
#define SEG_OUT_L  122880
#define SEG_LIN_H  143360
#define SEG_LIN_L  163840
#define WSPLIT_USHORTS 184320

__device__ __forceinline__ unsigned short f2bf(float x) {
    unsigned int u = __float_as_uint(x);
    u += 0x7fffu + ((u >> 16) & 1u);
    return (unsigned short)(u >> 16);
}
__device__ __forceinline__ float bf2f(unsigned short h) {
    return __uint_as_float(((unsigned int)h) << 16);
}
__device__ __forceinline__ float ssp_f(float t) {
    return fmaxf(t, 0.0f) + log1pf(expf(-fabsf(t))) - LOG2_C;
}
__device__ __forceinline__ void split8(const float* av, s8v& Ah, s8v& Al) {
#pragma unroll
    for (int j = 0; j < 8; ++j) {
        unsigned short hb = f2bf(av[j]);
        Ah[j] = (short)hb;
        Al[j] = (short)f2bf(av[j] - bf2f(hb));
    }
}
// 8 output tiles x 3-term split MFMA; B-frags straight from pre-split global (L2).
__device__ __forceinline__ void mfma8(const unsigned short* __restrict__ bh,
                                      const unsigned short* __restrict__ bl,
                                      const s8v& Ah, const s8v& Al, f4v acc[8]) {
#pragma unroll
    for (int t = 0; t < 8; ++t) {
        s8v Bh = *(const s8v*)(bh + t * 640);
        s8v Bl = *(const s8v*)(bl + t * 640);
        acc[t] = MFMA_BF16(Ah, Bl, acc[t], 0, 0, 0);
        acc[t] = MFMA_BF16(Al, Bh, acc[t], 0, 0, 0);
        acc[t] = MFMA_BF16(Ah, Bh, acc[t], 0, 0, 0);
    }
}

// ---------------- weight pre-split (runs once per launch, 288 blocks) ----------------
__global__ __launch_bounds__(BLK) void split5_kernel(const float* __restrict__ Wa,
                                                     const float* __restrict__ Wb,
                                                     const float* __restrict__ Wc,
                                                     const float* __restrict__ Wd,
                                                     const float* __restrict__ We,
                                                     unsigned short* __restrict__ Ws) {
    int i = blockIdx.x * BLK + threadIdx.x;
    if (i >= 18 * 4096) return;
    int chunk = i >> 12, r = i & 4095, k = r & 31, col = r >> 5;
    const float* W; int Kr, ck, hb, lb;
    if (chunk < 4)       { W = Wa; Kr = 128; ck = chunk;      hb = SEG_IN2F_H; lb = SEG_IN2F_L; }
    else if (chunk < 6)  { W = Wb; Kr = 50;  ck = chunk - 4;  hb = SEG_F1_H;   lb = SEG_F1_L; }
    else if (chunk < 10) { W = Wc; Kr = 128; ck = chunk - 6;  hb = SEG_F2_H;   lb = SEG_F2_L; }
    else if (chunk < 14) { W = Wd; Kr = 128; ck = chunk - 10; hb = SEG_OUT_H;  lb = SEG_OUT_L; }
    else                 { W = We; Kr = 128; ck = chunk - 14; hb = SEG_LIN_H;  lb = SEG_LIN_L; }
    int krow = ck * 32 + k;
    float v = (krow < Kr) ? W[(size_t)krow * DIM + col] : 0.f;
    unsigned short h16 = f2bf(v);
    int o = ck * 5120 + col * 40 + k;
    Ws[hb + o] = h16;
    Ws[lb + o] = f2bf(v - bf2f(h16));
}

// ---------------- h = x @ W_in2f  (MFMA, no LDS) ----------------
__global__ __launch_bounds__(BLK, 4) void node_in2f_mfma(const float* __restrict__ x,
                                                         const unsigned short* __restrict__ Ws,
                                                         float* __restrict__ h) {
    const int tid = threadIdx.x;
    const int w = tid >> 6, l = tid & 63, lr = l & 15, lk = l >> 4;
    const int n0 = blockIdx.x * TROWS;
    const int rowA = 16 * w + lr;
    const float* xr = x + (size_t)(n0 + rowA) * DIM;

    f4v acc[8];
#pragma unroll
    for (int t = 0; t < 8; ++t) acc[t] = (f4v){0.f, 0.f, 0.f, 0.f};
#pragma unroll
    for (int kc = 0; kc < 4; ++kc) {
        const float* ap = xr + kc * 32 + lk * 8;
        float4 a0 = *(const float4*)ap, a1 = *(const float4*)(ap + 4);
        float av[8] = {a0.x, a0.y, a0.z, a0.w, a1.x, a1.y, a1.z, a1.w};
        s8v Ah, Al; split8(av, Ah, Al);
        const int bo = kc * 5120 + lr * 40 + lk * 8;
        mfma8(Ws + SEG_IN2F_H + bo, Ws + SEG_IN2F_L + bo, Ah, Al, acc);
    }
    // direct store: lane holds (row 16w+lk*4+r, col t*16+lr) -> quarter-wave 64B coalesced
#pragma unroll
    for (int t = 0; t < 8; ++t)
#pragma unroll
        for (int r = 0; r < 4; ++r)
            h[(size_t)(n0 + 16 * w + lk * 4 + r) * DIM + t * 16 + lr] = acc[t][r];
}

// ---------------- CSR build ----------------
__global__ __launch_bounds__(BLK) void hist_kernel(const int* __restrict__ ind_i,
                                                   int* __restrict__ cnt) {
    int e = blockIdx.x * BLK + threadIdx.x;
    if (e < N_EDGES_C) atomicAdd(&cnt[ind_i[e]], 1);
}

__global__ __launch_bounds__(BLK) void scan1_kernel(const int* __restrict__ cnt,
                                                    int* __restrict__ excl,
                                                    int* __restrict__ bsum) {
    __shared__ int s[BLK];
    const int tid = threadIdx.x;
    const int idx = blockIdx.x * BLK + tid;
    int v = (idx < N_NODES_C) ? cnt[idx] : 0;
    s[tid] = v;
    __syncthreads();
    for (int off = 1; off < BLK; off <<= 1) {
        int t = (tid >= off) ? s[tid - off] : 0;
        __syncthreads();
        s[tid] += t;
        __syncthreads();
    }
    if (idx < N_NODES_C) excl[idx] = s[tid] - v;
    if (tid == BLK - 1) bsum[blockIdx.x] = s[tid];
}

__global__ __launch_bounds__(BLK) void scan2_kernel(int* __restrict__ bsum) {
    __shared__ int s[BLK];
    const int tid = threadIdx.x;
    int v = (tid < NSCAN_BLK) ? bsum[tid] : 0;
    s[tid] = v;
    __syncthreads();
    for (int off = 1; off < BLK; off <<= 1) {
        int t = (tid >= off) ? s[tid - off] : 0;
        __syncthreads();
        s[tid] += t;
        __syncthreads();
    }
    if (tid < NSCAN_BLK) bsum[tid] = s[tid] - v;  // exclusive
}

__global__ __launch_bounds__(BLK) void scan3_kernel(int* __restrict__ start,
                                                    int* __restrict__ cursor,
                                                    const int* __restrict__ bsum) {
    const int idx = blockIdx.x * BLK + threadIdx.x;
    if (idx < N_NODES_C) {
        int v = start[idx] + bsum[blockIdx.x];
        start[idx] = v;
        cursor[idx] = v;
    }
}

__global__ __launch_bounds__(BLK) void place_kernel(const int* __restrict__ ind_i,
                                                    int* __restrict__ cursor,
                                                    int* __restrict__ eids) {
    int e = blockIdx.x * BLK + threadIdx.x;
    if (e < N_EDGES_C) {
        int slot = atomicAdd(&cursor[ind_i[e]], 1);
        eids[slot] = e;
    }
}

// ---------------- Edge kernel: full MFMA (GEMM1 K=50->64 + GEMM2), 3 barriers ----------------
__global__ __launch_bounds__(BLK, 4) void edge_kernel_mfma(const float* __restrict__ f_ij,
                                                           const float* __restrict__ r_ij,
                                                           const int* __restrict__ ind_j,
                                                           const unsigned short* __restrict__ Ws,
                                                           const float* __restrict__ b_f1,
                                                           const float* __restrict__ b_f2,
                                                           const float* __restrict__ h,
                                                           float* __restrict__ msg) {
    __shared__ float tf[TROWS * LDA];   // 33792B: C1 transpose, then C2/epilogue
    const int tid = threadIdx.x;
    const int w = tid >> 6, l = tid & 63, lr = l & 15, lk = l >> 4;
    const int rt = tid >> 4, ct = tid & 15;
    const int e0 = blockIdx.x * TROWS;  // 640000 % 64 == 0
    const int rowA = 16 * w + lr;

    // ---- GEMM1: t_pre = f @ W1 + b1; A built in-reg from global f_ij (float2, 8B-aligned)
    f4v acc[8];
#pragma unroll
    for (int t = 0; t < 8; ++t) { float bv = b_f1[t * 16 + lr]; acc[t] = (f4v){bv, bv, bv, bv}; }
    const float* fr = f_ij + (size_t)(e0 + rowA) * NB;
#pragma unroll
    for (int kc = 0; kc < 2; ++kc) {
        int kb = kc * 32 + lk * 8;
        float av[8];
#pragma unroll
        for (int ii = 0; ii < 4; ++ii) {
            int k = kb + ii * 2;                      // pairs never straddle 50 (even)
            float2 v = (k < NB) ? *(const float2*)(fr + k) : make_float2(0.f, 0.f);
            av[ii * 2] = v.x; av[ii * 2 + 1] = v.y;
        }
        s8v Ah, Al; split8(av, Ah, Al);
        const int bo = kc * 5120 + lr * 40 + lk * 8;
        mfma8(Ws + SEG_F1_H + bo, Ws + SEG_F1_L + bo, Ah, Al, acc);
    }
    // C1 layout: (row 16w+lk*4+r, col t*16+lr); apply ssp while transposing into tf
#pragma unroll
    for (int t = 0; t < 8; ++t)
#pragma unroll
        for (int r = 0; r < 4; ++r)
            tf[(16 * w + lk * 4 + r) * LDA + t * 16 + lr] = ssp_f(acc[t][r]);
    __syncthreads();

    // ---- GEMM2: msg_pre = t1 @ W2 + b2; A re-read row-major from tf + in-reg split
#pragma unroll
    for (int t = 0; t < 8; ++t) { float bv = b_f2[t * 16 + lr]; acc[t] = (f4v){bv, bv, bv, bv}; }
#pragma unroll
    for (int kc = 0; kc < 4; ++kc) {
        const float* ap = &tf[rowA * LDA + kc * 32 + lk * 8];
        float4 a0 = *(const float4*)ap, a1 = *(const float4*)(ap + 4);
        float av[8] = {a0.x, a0.y, a0.z, a0.w, a1.x, a1.y, a1.z, a1.w};
        s8v Ah, Al; split8(av, Ah, Al);
        const int bo = kc * 5120 + lr * 40 + lk * 8;
        mfma8(Ws + SEG_F2_H + bo, Ws + SEG_F2_L + bo, Ah, Al, acc);
    }
    __syncthreads();   // all tf reads done before overwrite
#pragma unroll
    for (int t = 0; t < 8; ++t)
#pragma unroll
        for (int r = 0; r < 4; ++r)
            tf[(16 * w + lk * 4 + r) * LDA + t * 16 + lr] = acc[t][r];
    __syncthreads();

    // ---- epilogue: cutoff, gather h[ind_j], write msg row (vectorized row-major)
#pragma unroll
    for (int i = 0; i < 4; ++i) {
        int e = e0 + rt * 4 + i;
        float rr = r_ij[e];
        float C = (rr < 5.0f) ? 0.5f * (cosf(rr * PI_OVER_CUT) + 1.0f) : 0.0f;
        int nj = ind_j[e];
        const float* hp = &h[(size_t)nj * DIM + ct * 8];
        float4 h0 = *(const float4*)hp, h1 = *(const float4*)(hp + 4);
        const float* ep = &tf[(rt * 4 + i) * LDA + ct * 8];
        float4 a0 = *(const float4*)ep, a1 = *(const float4*)(ep + 4);
        float* mp = &msg[(size_t)e * DIM + ct * 8];
        *(float4*)mp = make_float4(h0.x * a0.x * C, h0.y * a0.y * C,
                                   h0.z * a0.z * C, h0.w * a0.w * C);
        *(float4*)(mp + 4) = make_float4(h1.x * a1.x * C, h1.y * a1.y * C,
                                         h1.z * a1.z * C, h1.w * a1.w * C);
    }
}

// ---------------- Gather: agg[n] = sum over CSR edges of msg ----------------
__global__ __launch_bounds__(BLK) void gather_kernel(const float* __restrict__ msg,
                                                     const int* __restrict__ eids,
                                                     const int* __restrict__ start,
                                                     const int* __restrict__ cnt,
                                                     float* __restrict__ agg) {
    const int wave = threadIdx.x >> 6;
    const int lane = threadIdx.x & 63;
    const int node = blockIdx.x * 4 + wave;
    if (node >= N_NODES_C) return;
    const int s = start[node];
    const int d = cnt[node];
    float ax = 0.f, ay = 0.f;
    int k = 0;
    for (; k + 1 < d; k += 2) {
        int ea = eids[s + k], eb = eids[s + k + 1];
        float2 va = *(const float2*)&msg[(size_t)ea * DIM + lane * 2];
        float2 vb = *(const float2*)&msg[(size_t)eb * DIM + lane * 2];
        ax += va.x + vb.x;
        ay += va.y + vb.y;
    }
    if (k < d) {
        int ea = eids[s + k];
        float2 va = *(const float2*)&msg[(size_t)ea * DIM + lane * 2];
        ax += va.x;
        ay += va.y;
    }
    *(float2*)&agg[(size_t)node * DIM + lane * 2] = make_float2(ax, ay);
}

// ---------------- out = ssp(agg@W_out + b_out) @ W_lin + b_lin  (MFMA) ----------------
__global__ __launch_bounds__(BLK, 4) void node_out_mfma(const float* __restrict__ agg,
                                                        const unsigned short* __restrict__ Ws,
                                                        const float* __restrict__ b_out,
                                                        const float* __restrict__ b_lin,
                                                        float* __restrict__ out) {
    __shared__ float tf[TROWS * LDA];
    const int tid = threadIdx.x;
    const int w = tid >> 6, l = tid & 63, lr = l & 15, lk = l >> 4;
    const int n0 = blockIdx.x * TROWS;
    const int rowA = 16 * w + lr;
    const float* ar = agg + (size_t)(n0 + rowA) * DIM;

    f4v acc[8];
#pragma unroll
    for (int t = 0; t < 8; ++t) { float bv = b_out[t * 16 + lr]; acc[t] = (f4v){bv, bv, bv, bv}; }
#pragma unroll
    for (int kc = 0; kc < 4; ++kc) {
        const float* ap = ar + kc * 32 + lk * 8;
        float4 a0 = *(const float4*)ap, a1 = *(const float4*)(ap + 4);
        float av[8] = {a0.x, a0.y, a0.z, a0.w, a1.x, a1.y, a1.z, a1.w};
        s8v Ah, Al; split8(av, Ah, Al);
        const int bo = kc * 5120 + lr * 40 + lk * 8;
        mfma8(Ws + SEG_OUT_H + bo, Ws + SEG_OUT_L + bo, Ah, Al, acc);
    }
    // v = ssp(C1) -> tf transpose
#pragma unroll
    for (int t = 0; t < 8; ++t)
#pragma unroll
        for (int r = 0; r < 4; ++r)
            tf[(16 * w + lk * 4 + r) * LDA + t * 16 + lr] = ssp_f(acc[t][r]);
    __syncthreads();

#pragma unroll
    for (int t = 0; t < 8; ++t) { float bv = b_lin[t * 16 + lr]; acc[t] = (f4v){bv, bv, bv, bv}; }
#pragma unroll
    for (int kc = 0; kc < 4; ++kc) {
        const float* ap = &tf[rowA * LDA + kc * 32 + lk * 8];
        float4 a0 = *(const float4*)ap, a1 = *(const float4*)(ap + 4);
        float av[8] = {a0.x, a0.y, a0.z, a0.w, a1.x, a1.y, a1.z, a1.w};
        s8v Ah, Al; split8(av, Ah, Al);
        const int bo = kc * 5120 + lr * 40 + lk * 8;
        mfma8(Ws + SEG_LIN_H + bo, Ws + SEG_LIN_L + bo, Ah, Al, acc);
    }
    // direct store of C2
#pragma unroll
    for (int t = 0; t < 8; ++t)
#pragma unroll
        for (int r = 0; r < 4; ++r)
            out[(size_t)(n0 + 16 * w + lk * 4 + r) * DIM + t * 16 + lr] = acc[t][r];
}

// ================= vector fallback path (only if workspace too small) =================
__device__ __forceinline__ void stage_chunk(const float* __restrict__ B, int k0, int rows,
                                            float* __restrict__ Bc, int tid) {
    const int n4 = rows * (DIM / 4);
    const float4* Bg = (const float4*)B + (size_t)k0 * (DIM / 4);
    float4* Bc4 = (float4*)Bc;
    for (int i = tid; i < n4; i += BLK) Bc4[i] = Bg[i];
}

__device__ __forceinline__ void init_acc_bias(float acc[4][8], const float* __restrict__ b, int ct) {
    float4 bb0 = *(const float4*)&b[ct * 8];
    float4 bb1 = *(const float4*)&b[ct * 8 + 4];
#pragma unroll
    for (int i = 0; i < 4; ++i) {
        acc[i][0] = bb0.x; acc[i][1] = bb0.y; acc[i][2] = bb0.z; acc[i][3] = bb0.w;
        acc[i][4] = bb1.x; acc[i][5] = bb1.y; acc[i][6] = bb1.z; acc[i][7] = bb1.w;
    }
}

template <int KPAD>
__device__ __forceinline__ void gemm_tile(const float* __restrict__ A_lds, int lda,
                                          const float* __restrict__ Bglob,
                                          float* __restrict__ Bc,
                                          float acc[4][8], int rt, int ct, int tid) {
    for (int k0 = 0; k0 < KPAD; k0 += 32) {
        __syncthreads();
        stage_chunk(Bglob, k0, 32, Bc, tid);
        __syncthreads();
#pragma unroll 2
        for (int k4 = 0; k4 < 8; ++k4) {
            float4 av[4];
#pragma unroll
            for (int i = 0; i < 4; ++i)
                av[i] = *(const float4*)&A_lds[(rt * 4 + i) * lda + k0 + k4 * 4];
#pragma unroll
            for (int kk = 0; kk < 4; ++kk) {
                const float* bp = &Bc[(k4 * 4 + kk) * DIM + ct * 8];
                float4 b0 = *(const float4*)bp;
                float4 b1 = *(const float4*)(bp + 4);
#pragma unroll
                for (int i = 0; i < 4; ++i) {
                    float a = ((const float*)&av[i])[kk];
                    acc[i][0] = fmaf(a, b0.x, acc[i][0]);
                    acc[i][1] = fmaf(a, b0.y, acc[i][1]);
                    acc[i][2] = fmaf(a, b0.z, acc[i][2]);
                    acc[i][3] = fmaf(a, b0.w, acc[i][3]);
                    acc[i][4] = fmaf(a, b1.x, acc[i][4]);
                    acc[i][5] = fmaf(a, b1.y, acc[i][5]);
                    acc[i][6] = fmaf(a, b1.z, acc[i][6]);
                    acc[i][7] = fmaf(a, b1.w, acc[i][7]);
                }
            }
        }
    }
}

template <int NK2>
__device__ __forceinline__ void gemm1_direct(const float* const (&frow)[4], int k2base,
                                             const float* __restrict__ Bc,
                                             float acc[4][8], int ct) {
#pragma unroll 4
    for (int k2 = 0; k2 < NK2; ++k2) {
        float2 a2[4];
#pragma unroll
        for (int i = 0; i < 4; ++i)
            a2[i] = *(const float2*)(frow[i] + (k2base + k2) * 2);
#pragma unroll
        for (int kk = 0; kk < 2; ++kk) {
            const float* bp = &Bc[(k2 * 2 + kk) * DIM + ct * 8];
            float4 b0 = *(const float4*)bp;
            float4 b1 = *(const float4*)(bp + 4);
#pragma unroll
            for (int i = 0; i < 4; ++i) {
                float a = kk ? a2[i].y : a2[i].x;
                acc[i][0] = fmaf(a, b0.x, acc[i][0]);
                acc[i][1] = fmaf(a, b0.y, acc[i][1]);
                acc[i][2] = fmaf(a, b0.z, acc[i][2]);
                acc[i][3] = fmaf(a, b0.w, acc[i][3]);
                acc[i][4] = fmaf(a, b1.x, acc[i][4]);
                acc[i][5] = fmaf(a, b1.y, acc[i][5]);
                acc[i][6] = fmaf(a, b1.z, acc[i][6]);
                acc[i][7] = fmaf(a, b1.w, acc[i][7]);
            }
        }
    }
}

__global__ __launch_bounds__(BLK) void node_in2f_fb(const float* __restrict__ x,
                                                    const float* __restrict__ W,
                                                    float* __restrict__ h) {
    __shared__ float At[TROWS * LDA];
    __shared__ float Bc[32 * DIM];
    const int tid = threadIdx.x;
    const int rt = tid >> 4, ct = tid & 15;
    const int n0 = blockIdx.x * TROWS;
    for (int i = tid; i < TROWS * (DIM / 4); i += BLK) {
        int row = i >> 5, c4 = i & 31;
        *(float4*)&At[row * LDA + c4 * 4] = *(const float4*)&x[(size_t)(n0 + row) * DIM + c4 * 4];
    }
    float acc[4][8];
#pragma unroll
    for (int i = 0; i < 4; ++i)
#pragma unroll
        for (int j = 0; j < 8; ++j) acc[i][j] = 0.f;
    gemm_tile<DIM>(At, LDA, W, Bc, acc, rt, ct, tid);
#pragma unroll
    for (int i = 0; i < 4; ++i) {
        float* hp = &h[(size_t)(n0 + rt * 4 + i) * DIM + ct * 8];
        *(float4*)hp = make_float4(acc[i][0], acc[i][1], acc[i][2], acc[i][3]);
        *(float4*)(hp + 4) = make_float4(acc[i][4], acc[i][5], acc[i][6], acc[i][7]);
    }
}

__global__ __launch_bounds__(BLK) void node_out_fb(const float* __restrict__ agg,
                                                   const float* __restrict__ W_out,
                                                   const float* __restrict__ b_out,
                                                   const float* __restrict__ W_lin,
                                                   const float* __restrict__ b_lin,
                                                   float* __restrict__ out) {
    __shared__ float At[TROWS * LDA];
    __shared__ float Bc[32 * DIM];
    const int tid = threadIdx.x;
    const int rt = tid >> 4, ct = tid & 15;
    const int n0 = blockIdx.x * TROWS;
    for (int i = tid; i < TROWS * (DIM / 4); i += BLK) {
        int row = i >> 5, c4 = i & 31;
        *(float4*)&At[row * LDA + c4 * 4] = *(const float4*)&agg[(size_t)(n0 + row) * DIM + c4 * 4];
    }
    float acc[4][8];
    init_acc_bias(acc, b_out, ct);
    gemm_tile<DIM>(At, LDA, W_out, Bc, acc, rt, ct, tid);
    __syncthreads();
#pragma unroll
    for (int i = 0; i < 4; ++i) {
        float* tp = &At[(rt * 4 + i) * LDA + ct * 8];
        *(float4*)tp = make_float4(ssp_f(acc[i][0]), ssp_f(acc[i][1]),
                                   ssp_f(acc[i][2]), ssp_f(acc[i][3]));
        *(float4*)(tp + 4) = make_float4(ssp_f(acc[i][4]), ssp_f(acc[i][5]),
                                         ssp_f(acc[i][6]), ssp_f(acc[i][7]));
    }
    init_acc_bias(acc, b_lin, ct);
    gemm_tile<DIM>(At, LDA, W_lin, Bc, acc, rt, ct, tid);
#pragma unroll
    for (int i = 0; i < 4; ++i) {
        float* op = &out[(size_t)(n0 + rt * 4 + i) * DIM + ct * 8];
        *(float4*)op = make_float4(acc[i][0], acc[i][1], acc[i][2], acc[i][3]);
        *(float4*)(op + 4) = make_float4(acc[i][4], acc[i][5], acc[i][6], acc[i][7]);
    }
}

__global__ __launch_bounds__(BLK) void edge_kernel_atomic(const float* __restrict__ f_ij,
                                                          const float* __restrict__ r_ij,
                                                          const int* __restrict__ ind_i,
                                                          const int* __restrict__ ind_j,
                                                          const float* __restrict__ W_f1,
                                                          const float* __restrict__ b_f1,
                                                          const float* __restrict__ W_f2,
                                                          const float* __restrict__ b_f2,
                                                          const float* __restrict__ h,
                                                          float* __restrict__ agg) {
    __shared__ float t1[TROWS * LDA];
    __shared__ float Bc[32 * DIM];
    const int tid = threadIdx.x;
    const int rt = tid >> 4, ct = tid & 15;
    const int e0 = blockIdx.x * TROWS;
    const float* frow[4];
#pragma unroll
    for (int i = 0; i < 4; ++i) frow[i] = f_ij + (size_t)(e0 + rt * 4 + i) * NB;
    float acc[4][8];
    init_acc_bias(acc, b_f1, ct);
    stage_chunk(W_f1, 0, 32, Bc, tid);
    __syncthreads();
    gemm1_direct<16>(frow, 0, Bc, acc, ct);
    __syncthreads();
    stage_chunk(W_f1, 32, 18, Bc, tid);
    __syncthreads();
    gemm1_direct<9>(frow, 16, Bc, acc, ct);
#pragma unroll
    for (int i = 0; i < 4; ++i) {
        float* tp = &t1[(rt * 4 + i) * LDA + ct * 8];
        *(float4*)tp = make_float4(ssp_f(acc[i][0]), ssp_f(acc[i][1]),
                                   ssp_f(acc[i][2]), ssp_f(acc[i][3]));
        *(float4*)(tp + 4) = make_float4(ssp_f(acc[i][4]), ssp_f(acc[i][5]),
                                         ssp_f(acc[i][6]), ssp_f(acc[i][7]));
    }
    init_acc_bias(acc, b_f2, ct);
    gemm_tile<DIM>(t1, LDA, W_f2, Bc, acc, rt, ct, tid);
#pragma unroll
    for (int i = 0; i < 4; ++i) {
        int e = e0 + rt * 4 + i;
        float r = r_ij[e];
        float C = (r < 5.0f) ? 0.5f * (cosf(r * PI_OVER_CUT) + 1.0f) : 0.0f;
        int nj = ind_j[e];
        int ni = ind_i[e];
        const float* hp = &h[(size_t)nj * DIM + ct * 8];
        float4 h0 = *(const float4*)hp;
        float4 h1 = *(const float4*)(hp + 4);
        float* ap = &agg[(size_t)ni * DIM + ct * 8];
        atomicAdd(ap + 0, h0.x * acc[i][0] * C);
        atomicAdd(ap + 1, h0.y * acc[i][1] * C);
        atomicAdd(ap + 2, h0.z * acc[i][2] * C);
        atomicAdd(ap + 3, h0.w * acc[i][3] * C);
        atomicAdd(ap + 4, h1.x * acc[i][4] * C);
        atomicAdd(ap + 5, h1.y * acc[i][5] * C);
        atomicAdd(ap + 6, h1.z * acc[i][6] * C);
        atomicAdd(ap + 7, h1.w * acc[i][7] * C);
    }
}

extern "C" void kernel_launch(void* const* d_in, const int* in_sizes, int n_in,
                              void* d_out, int out_size, void* d_ws, size_t ws_size,
                              hipStream_t stream) {
    const float* x      = (const float*)d_in[0];
    const float* r_ij   = (const float*)d_in[1];
    const float* f_ij   = (const float*)d_in[2];
    const int*   ind_i  = (const int*)d_in[3];
    const int*   ind_j  = (const int*)d_in[4];
    const float* W_in2f = (const float*)d_in[5];
    const float* W_f1   = (const float*)d_in[6];
    const float* b_f1   = (const float*)d_in[7];
    const float* W_f2   = (const float*)d_in[8];
    const float* b_f2   = (const float*)d_in[9];
    const float* W_out  = (const float*)d_in[10];
    const float* b_out  = (const float*)d_in[11];
    const float* W_lin  = (const float*)d_in[12];
    const float* b_lin  = (const float*)d_in[13];
    float* out = (float*)d_out;

    char* ws = (char*)d_ws;
    size_t off = 0;
    auto alloc = [&](size_t bytes) {
        char* p = ws + off;
        off = (off + bytes + 511) & ~(size_t)511;
        return p;
    };
    unsigned short* Wsplit = (unsigned short*)alloc(WSPLIT_USHORTS * sizeof(unsigned short));
    float* h      = (float*)alloc((size_t)N_NODES_C * DIM * sizeof(float));
    float* agg    = (float*)alloc((size_t)N_NODES_C * DIM * sizeof(float));
    float* msg    = (float*)alloc((size_t)N_EDGES_C * DIM * sizeof(float));
    int*   eids   = (int*)alloc((size_t)N_EDGES_C * sizeof(int));
    int*   cnt    = (int*)alloc((size_t)N_NODES_C * sizeof(int));
    int*   startA = (int*)alloc((size_t)N_NODES_C * sizeof(int));
    int*   cursor = (int*)alloc((size_t)N_NODES_C * sizeof(int));
    int*   bsum   = (int*)alloc((size_t)NSCAN_BLK * sizeof(int));
    const bool have_ws = (off <= ws_size);

    if (have_ws) {
        split5_kernel<<<(18 * 4096 + BLK - 1) / BLK, BLK, 0, stream>>>(
            W_in2f, W_f1, W_f2, W_out, W_lin, Wsplit);

        node_in2f_mfma<<<N_NODES_C / TROWS, BLK, 0, stream>>>(x, Wsplit, h);

        hipMemsetAsync(cnt, 0, (size_t)N_NODES_C * sizeof(int), stream);
        hist_kernel<<<(N_EDGES_C + BLK - 1) / BLK, BLK, 0, stream>>>(ind_i, cnt);
        scan1_kernel<<<NSCAN_BLK, BLK, 0, stream>>>(cnt, startA, bsum);
        scan2_kernel<<<1, BLK, 0, stream>>>(bsum);
        scan3_kernel<<<NSCAN_BLK, BLK, 0, stream>>>(startA, cursor, bsum);
        place_kernel<<<(N_EDGES_C + BLK - 1) / BLK, BLK, 0, stream>>>(ind_i, cursor, eids);

        edge_kernel_mfma<<<N_EDGES_C / TROWS, BLK, 0, stream>>>(
            f_ij, r_ij, ind_j, Wsplit, b_f1, b_f2, h, msg);
        gather_kernel<<<(N_NODES_C + 3) / 4, BLK, 0, stream>>>(msg, eids, startA, cnt, agg);

        node_out_mfma<<<N_NODES_C / TROWS, BLK, 0, stream>>>(agg, Wsplit, b_out, b_lin, out);
    } else {
        // minimal-workspace vector fallback (h + agg only)
        float* h2   = (float*)d_ws;
        float* agg2 = h2 + (size_t)N_NODES_C * DIM;
        node_in2f_fb<<<N_NODES_C / TROWS, BLK, 0, stream>>>(x, W_in2f, h2);
        hipMemsetAsync(agg2, 0, (size_t)N_NODES_C * DIM * sizeof(float), stream);
        edge_kernel_atomic<<<N_EDGES_C / TROWS, BLK, 0, stream>>>(
            f_ij, r_ij, ind_i, ind_j, W_f1, b_f1, W_f2, b_f2, h2, agg2);
        node_out_fb<<<N_NODES_C / TROWS, BLK, 0, stream>>>(agg2, W_out, b_out, W_lin, b_lin, out);
    }
}

// Round 8
// 529.875 us; speedup vs baseline: 1.9837x; 1.0032x over previous
//
#include <hip/hip_runtime.h>

#define N_NODES_C 40000
#define N_EDGES_C 640000
#define DIM 128
#define NB 50
#define LDA 132       // f32 transpose-buffer leading dim (528B rows: 16B-aligned)
#define BLK 256
#define TROWS 64
#define LOG2_C 0.6931471805599453f
#define PI_OVER_CUT 0.6283185307179586f  // pi/5
#define NSCAN_BLK 157  // ceil(40000/256)

typedef __attribute__((ext_vector_type(8))) short s8v;   // 8 bf16 = A/B frag of 16x16x32
typedef __attribute__((ext_vector_type(4))) float f4v;   // C/D frag

#define MFMA_BF16 __builtin_amdgcn_mfma_f32_16x16x32_bf16

// Wsplit segment offsets (ushort units). Layout per weight: [nc][128 col][40] with
// k in [0,32) at col*40+k (40-stride for bank spread; slots 32..39 unused).
#define SEG_IN2F_H 0
#define SEG_IN2F_L 20480
#define SEG_F1_H   40960
#define SEG_F1_L   51200
#define SEG_F2_H   61440
#define SEG_F2_L   81920
#define SEG_OUT_H  102400
#define SEG_OUT_L  122880
#define SEG_LIN_H  143360
#define SEG_LIN_L  163840
#define WSPLIT_USHORTS 184320

__device__ __forceinline__ unsigned short f2bf(float x) {
    unsigned int u = __float_as_uint(x);
    u += 0x7fffu + ((u >> 16) & 1u);
    return (unsigned short)(u >> 16);
}
__device__ __forceinline__ float bf2f(unsigned short h) {
    return __uint_as_float(((unsigned int)h) << 16);
}
__device__ __forceinline__ float ssp_f(float t) {
    return fmaxf(t, 0.0f) + log1pf(expf(-fabsf(t))) - LOG2_C;
}
__device__ __forceinline__ void split8(const float* av, s8v& Ah, s8v& Al) {
#pragma unroll
    for (int j = 0; j < 8; ++j) {
        unsigned short hb = f2bf(av[j]);
        Ah[j] = (short)hb;
        Al[j] = (short)f2bf(av[j] - bf2f(hb));
    }
}
// 8 output tiles x 3-term split MFMA; B-frags straight from pre-split global (L2).
__device__ __forceinline__ void mfma8(const unsigned short* __restrict__ bh,
                                      const unsigned short* __restrict__ bl,
                                      const s8v& Ah, const s8v& Al, f4v acc[8]) {
#pragma unroll
    for (int t = 0; t < 8; ++t) {
        s8v Bh = *(const s8v*)(bh + t * 640);
        s8v Bl = *(const s8v*)(bl + t * 640);
        acc[t] = MFMA_BF16(Ah, Bl, acc[t], 0, 0, 0);
        acc[t] = MFMA_BF16(Al, Bh, acc[t], 0, 0, 0);
        acc[t] = MFMA_BF16(Ah, Bh, acc[t], 0, 0, 0);
    }
}

// ---------------- weight pre-split (runs once per launch, 288 blocks) ----------------
__global__ __launch_bounds__(BLK) void split5_kernel(const float* __restrict__ Wa,
                                                     const float* __restrict__ Wb,
                                                     const float* __restrict__ Wc,
                                                     const float* __restrict__ Wd,
                                                     const float* __restrict__ We,
                                                     unsigned short* __restrict__ Ws) {
    int i = blockIdx.x * BLK + threadIdx.x;
    if (i >= 18 * 4096) return;
    int chunk = i >> 12, r = i & 4095, k = r & 31, col = r >> 5;
    const float* W; int Kr, ck, hb, lb;
    if (chunk < 4)       { W = Wa; Kr = 128; ck = chunk;      hb = SEG_IN2F_H; lb = SEG_IN2F_L; }
    else if (chunk < 6)  { W = Wb; Kr = 50;  ck = chunk - 4;  hb = SEG_F1_H;   lb = SEG_F1_L; }
    else if (chunk < 10) { W = Wc; Kr = 128; ck = chunk - 6;  hb = SEG_F2_H;   lb = SEG_F2_L; }
    else if (chunk < 14) { W = Wd; Kr = 128; ck = chunk - 10; hb = SEG_OUT_H;  lb = SEG_OUT_L; }
    else                 { W = We; Kr = 128; ck = chunk - 14; hb = SEG_LIN_H;  lb = SEG_LIN_L; }
    int krow = ck * 32 + k;
    float v = (krow < Kr) ? W[(size_t)krow * DIM + col] : 0.f;
    unsigned short h16 = f2bf(v);
    int o = ck * 5120 + col * 40 + k;
    Ws[hb + o] = h16;
    Ws[lb + o] = f2bf(v - bf2f(h16));
}

// ---------------- h = x @ W_in2f  (MFMA, no LDS) ----------------
__global__ __launch_bounds__(BLK, 4) void node_in2f_mfma(const float* __restrict__ x,
                                                         const unsigned short* __restrict__ Ws,
                                                         float* __restrict__ h) {
    const int tid = threadIdx.x;
    const int w = tid >> 6, l = tid & 63, lr = l & 15, lk = l >> 4;
    const int n0 = blockIdx.x * TROWS;
    const int rowA = 16 * w + lr;
    const float* xr = x + (size_t)(n0 + rowA) * DIM;

    f4v acc[8];
#pragma unroll
    for (int t = 0; t < 8; ++t) acc[t] = (f4v){0.f, 0.f, 0.f, 0.f};
#pragma unroll
    for (int kc = 0; kc < 4; ++kc) {
        const float* ap = xr + kc * 32 + lk * 8;
        float4 a0 = *(const float4*)ap, a1 = *(const float4*)(ap + 4);
        float av[8] = {a0.x, a0.y, a0.z, a0.w, a1.x, a1.y, a1.z, a1.w};
        s8v Ah, Al; split8(av, Ah, Al);
        const int bo = kc * 5120 + lr * 40 + lk * 8;
        mfma8(Ws + SEG_IN2F_H + bo, Ws + SEG_IN2F_L + bo, Ah, Al, acc);
    }
    // direct store: lane holds (row 16w+lk*4+r, col t*16+lr) -> quarter-wave 64B coalesced
#pragma unroll
    for (int t = 0; t < 8; ++t)
#pragma unroll
        for (int r = 0; r < 4; ++r)
            h[(size_t)(n0 + 16 * w + lk * 4 + r) * DIM + t * 16 + lr] = acc[t][r];
}

// ---------------- CSR build ----------------
__global__ __launch_bounds__(BLK) void hist_kernel(const int* __restrict__ ind_i,
                                                   int* __restrict__ cnt) {
    int e = blockIdx.x * BLK + threadIdx.x;
    if (e < N_EDGES_C) atomicAdd(&cnt[ind_i[e]], 1);
}

__global__ __launch_bounds__(BLK) void scan1_kernel(const int* __restrict__ cnt,
                                                    int* __restrict__ excl,
                                                    int* __restrict__ bsum) {
    __shared__ int s[BLK];
    const int tid = threadIdx.x;
    const int idx = blockIdx.x * BLK + tid;
    int v = (idx < N_NODES_C) ? cnt[idx] : 0;
    s[tid] = v;
    __syncthreads();
    for (int off = 1; off < BLK; off <<= 1) {
        int t = (tid >= off) ? s[tid - off] : 0;
        __syncthreads();
        s[tid] += t;
        __syncthreads();
    }
    if (idx < N_NODES_C) excl[idx] = s[tid] - v;
    if (tid == BLK - 1) bsum[blockIdx.x] = s[tid];
}

__global__ __launch_bounds__(BLK) void scan2_kernel(int* __restrict__ bsum) {
    __shared__ int s[BLK];
    const int tid = threadIdx.x;
    int v = (tid < NSCAN_BLK) ? bsum[tid] : 0;
    s[tid] = v;
    __syncthreads();
    for (int off = 1; off < BLK; off <<= 1) {
        int t = (tid >= off) ? s[tid - off] : 0;
        __syncthreads();
        s[tid] += t;
        __syncthreads();
    }
    if (tid < NSCAN_BLK) bsum[tid] = s[tid] - v;  // exclusive
}

__global__ __launch_bounds__(BLK) void scan3_kernel(int* __restrict__ start,
                                                    int* __restrict__ cursor,
                                                    const int* __restrict__ bsum) {
    const int idx = blockIdx.x * BLK + threadIdx.x;
    if (idx < N_NODES_C) {
        int v = start[idx] + bsum[blockIdx.x];
        start[idx] = v;
        cursor[idx] = v;
    }
}

__global__ __launch_bounds__(BLK) void place_kernel(const int* __restrict__ ind_i,
                                                    int* __restrict__ cursor,
                                                    int* __restrict__ eids) {
    int e = blockIdx.x * BLK + threadIdx.x;
    if (e < N_EDGES_C) {
        int slot = atomicAdd(&cursor[ind_i[e]], 1);
        eids[slot] = e;
    }
}

// ---------------- Edge kernel: full MFMA (GEMM1 K=50->64 + GEMM2), 3 barriers ----------------
__global__ __launch_bounds__(BLK, 4) void edge_kernel_mfma(const float* __restrict__ f_ij,
                                                           const float* __restrict__ r_ij,
                                                           const int* __restrict__ ind_j,
                                                           const unsigned short* __restrict__ Ws,
                                                           const float* __restrict__ b_f1,
                                                           const float* __restrict__ b_f2,
                                                           const float* __restrict__ h,
                                                           float* __restrict__ msg) {
    __shared__ float tf[TROWS * LDA];   // 33792B: C1 transpose, then C2/epilogue
    const int tid = threadIdx.x;
    const int w = tid >> 6, l = tid & 63, lr = l & 15, lk = l >> 4;
    const int rt = tid >> 4, ct = tid & 15;
    const int e0 = blockIdx.x * TROWS;  // 640000 % 64 == 0
    const int rowA = 16 * w + lr;

    // ---- GEMM1: t_pre = f @ W1 + b1; A built in-reg from global f_ij (float2, 8B-aligned)
    f4v acc[8];
#pragma unroll
    for (int t = 0; t < 8; ++t) { float bv = b_f1[t * 16 + lr]; acc[t] = (f4v){bv, bv, bv, bv}; }
    const float* fr = f_ij + (size_t)(e0 + rowA) * NB;
#pragma unroll
    for (int kc = 0; kc < 2; ++kc) {
        int kb = kc * 32 + lk * 8;
        float av[8];
#pragma unroll
        for (int ii = 0; ii < 4; ++ii) {
            int k = kb + ii * 2;                      // pairs never straddle 50 (even)
            float2 v = (k < NB) ? *(const float2*)(fr + k) : make_float2(0.f, 0.f);
            av[ii * 2] = v.x; av[ii * 2 + 1] = v.y;
        }
        s8v Ah, Al; split8(av, Ah, Al);
        const int bo = kc * 5120 + lr * 40 + lk * 8;
        mfma8(Ws + SEG_F1_H + bo, Ws + SEG_F1_L + bo, Ah, Al, acc);
    }
    // C1 layout: (row 16w+lk*4+r, col t*16+lr); apply ssp while transposing into tf
#pragma unroll
    for (int t = 0; t < 8; ++t)
#pragma unroll
        for (int r = 0; r < 4; ++r)
            tf[(16 * w + lk * 4 + r) * LDA + t * 16 + lr] = ssp_f(acc[t][r]);
    __syncthreads();

    // ---- GEMM2: msg_pre = t1 @ W2 + b2; A re-read row-major from tf + in-reg split
#pragma unroll
    for (int t = 0; t < 8; ++t) { float bv = b_f2[t * 16 + lr]; acc[t] = (f4v){bv, bv, bv, bv}; }
#pragma unroll
    for (int kc = 0; kc < 4; ++kc) {
        const float* ap = &tf[rowA * LDA + kc * 32 + lk * 8];
        float4 a0 = *(const float4*)ap, a1 = *(const float4*)(ap + 4);
        float av[8] = {a0.x, a0.y, a0.z, a0.w, a1.x, a1.y, a1.z, a1.w};
        s8v Ah, Al; split8(av, Ah, Al);
        const int bo = kc * 5120 + lr * 40 + lk * 8;
        mfma8(Ws + SEG_F2_H + bo, Ws + SEG_F2_L + bo, Ah, Al, acc);
    }
    __syncthreads();   // all tf reads done before overwrite
#pragma unroll
    for (int t = 0; t < 8; ++t)
#pragma unroll
        for (int r = 0; r < 4; ++r)
            tf[(16 * w + lk * 4 + r) * LDA + t * 16 + lr] = acc[t][r];
    __syncthreads();

    // ---- epilogue: cutoff, gather h[ind_j], write msg row (vectorized row-major)
#pragma unroll
    for (int i = 0; i < 4; ++i) {
        int e = e0 + rt * 4 + i;
        float rr = r_ij[e];
        float C = (rr < 5.0f) ? 0.5f * (cosf(rr * PI_OVER_CUT) + 1.0f) : 0.0f;
        int nj = ind_j[e];
        const float* hp = &h[(size_t)nj * DIM + ct * 8];
        float4 h0 = *(const float4*)hp, h1 = *(const float4*)(hp + 4);
        const float* ep = &tf[(rt * 4 + i) * LDA + ct * 8];
        float4 a0 = *(const float4*)ep, a1 = *(const float4*)(ep + 4);
        float* mp = &msg[(size_t)e * DIM + ct * 8];
        *(float4*)mp = make_float4(h0.x * a0.x * C, h0.y * a0.y * C,
                                   h0.z * a0.z * C, h0.w * a0.w * C);
        *(float4*)(mp + 4) = make_float4(h1.x * a1.x * C, h1.y * a1.y * C,
                                         h1.z * a1.z * C, h1.w * a1.w * C);
    }
}

// ---------------- Gather: agg[n] = sum over CSR edges of msg ----------------
__global__ __launch_bounds__(BLK) void gather_kernel(const float* __restrict__ msg,
                                                     const int* __restrict__ eids,
                                                     const int* __restrict__ start,
                                                     const int* __restrict__ cnt,
                                                     float* __restrict__ agg) {
    const int wave = threadIdx.x >> 6;
    const int lane = threadIdx.x & 63;
    const int node = blockIdx.x * 4 + wave;
    if (node >= N_NODES_C) return;
    const int s = start[node];
    const int d = cnt[node];
    float ax = 0.f, ay = 0.f;
    int k = 0;
    for (; k + 1 < d; k += 2) {
        int ea = eids[s + k], eb = eids[s + k + 1];
        float2 va = *(const float2*)&msg[(size_t)ea * DIM + lane * 2];
        float2 vb = *(const float2*)&msg[(size_t)eb * DIM + lane * 2];
        ax += va.x + vb.x;
        ay += va.y + vb.y;
    }
    if (k < d) {
        int ea = eids[s + k];
        float2 va = *(const float2*)&msg[(size_t)ea * DIM + lane * 2];
        ax += va.x;
        ay += va.y;
    }
    *(float2*)&agg[(size_t)node * DIM + lane * 2] = make_float2(ax, ay);
}

// ---------------- out = ssp(agg@W_out + b_out) @ W_lin + b_lin  (MFMA) ----------------
__global__ __launch_bounds__(BLK, 4) void node_out_mfma(const float* __restrict__ agg,
                                                        const unsigned short* __restrict__ Ws,
                                                        const float* __restrict__ b_out,
                                                        const float* __restrict__ b_lin,
                                                        float* __restrict__ out) {
    __shared__ float tf[TROWS * LDA];
    const int tid = threadIdx.x;
    const int w = tid >> 6, l = tid & 63, lr = l & 15, lk = l >> 4;
    const int n0 = blockIdx.x * TROWS;
    const int rowA = 16 * w + lr;
    const float* ar = agg + (size_t)(n0 + rowA) * DIM;

    f4v acc[8];
#pragma unroll
    for (int t = 0; t < 8; ++t) { float bv = b_out[t * 16 + lr]; acc[t] = (f4v){bv, bv, bv, bv}; }
#pragma unroll
    for (int kc = 0; kc < 4; ++kc) {
        const float* ap = ar + kc * 32 + lk * 8;
        float4 a0 = *(const float4*)ap, a1 = *(const float4*)(ap + 4);
        float av[8] = {a0.x, a0.y, a0.z, a0.w, a1.x, a1.y, a1.z, a1.w};
        s8v Ah, Al; split8(av, Ah, Al);
        const int bo = kc * 5120 + lr * 40 + lk * 8;
        mfma8(Ws + SEG_OUT_H + bo, Ws + SEG_OUT_L + bo, Ah, Al, acc);
    }
    // v = ssp(C1) -> tf transpose
#pragma unroll
    for (int t = 0; t < 8; ++t)
#pragma unroll
        for (int r = 0; r < 4; ++r)
            tf[(16 * w + lk * 4 + r) * LDA + t * 16 + lr] = ssp_f(acc[t][r]);
    __syncthreads();

#pragma unroll
    for (int t = 0; t < 8; ++t) { float bv = b_lin[t * 16 + lr]; acc[t] = (f4v){bv, bv, bv, bv}; }
#pragma unroll
    for (int kc = 0; kc < 4; ++kc) {
        const float* ap = &tf[rowA * LDA + kc * 32 + lk * 8];
        float4 a0 = *(const float4*)ap, a1 = *(const float4*)(ap + 4);
        float av[8] = {a0.x, a0.y, a0.z, a0.w, a1.x, a1.y, a1.z, a1.w};
        s8v Ah, Al; split8(av, Ah, Al);
        const int bo = kc * 5120 + lr * 40 + lk * 8;
        mfma8(Ws + SEG_LIN_H + bo, Ws + SEG_LIN_L + bo, Ah, Al, acc);
    }
    // direct store of C2
#pragma unroll
    for (int t = 0; t < 8; ++t)
#pragma unroll
        for (int r = 0; r < 4; ++r)
            out[(size_t)(n0 + 16 * w + lk * 4 + r) * DIM + t * 16 + lr] = acc[t][r];
}

// ================= vector fallback path (only if workspace too small) =================
__device__ __forceinline__ void stage_chunk(const float* __restrict__ B, int k0, int rows,
                                            float* __restrict__ Bc, int tid) {
    const int n4 = rows * (DIM / 4);
    const float4* Bg = (const float4*)B + (size_t)k0 * (DIM / 4);
    float4* Bc4 = (float4*)Bc;
    for (int i = tid; i < n4; i += BLK) Bc4[i] = Bg[i];
}

__device__ __forceinline__ void init_acc_bias(float acc[4][8], const float* __restrict__ b, int ct) {
    float4 bb0 = *(const float4*)&b[ct * 8];
    float4 bb1 = *(const float4*)&b[ct * 8 + 4];
#pragma unroll
    for (int i = 0; i < 4; ++i) {
        acc[i][0] = bb0.x; acc[i][1] = bb0.y; acc[i][2] = bb0.z; acc[i][3] = bb0.w;
        acc[i][4] = bb1.x; acc[i][5] = bb1.y; acc[i][6] = bb1.z; acc[i][7] = bb1.w;
    }
}

template <int KPAD>
__device__ __forceinline__ void gemm_tile(const float* __restrict__ A_lds, int lda,
                                          const float* __restrict__ Bglob,
                                          float* __restrict__ Bc,
                                          float acc[4][8], int rt, int ct, int tid) {
    for (int k0 = 0; k0 < KPAD; k0 += 32) {
        __syncthreads();
        stage_chunk(Bglob, k0, 32, Bc, tid);
        __syncthreads();
#pragma unroll 2
        for (int k4 = 0; k4 < 8; ++k4) {
            float4 av[4];
#pragma unroll
            for (int i = 0; i < 4; ++i)
                av[i] = *(const float4*)&A_lds[(rt * 4 + i) * lda + k0 + k4 * 4];
#pragma unroll
            for (int kk = 0; kk < 4; ++kk) {
                const float* bp = &Bc[(k4 * 4 + kk) * DIM + ct * 8];
                float4 b0 = *(const float4*)bp;
                float4 b1 = *(const float4*)(bp + 4);
#pragma unroll
                for (int i = 0; i < 4; ++i) {
                    float a = ((const float*)&av[i])[kk];
                    acc[i][0] = fmaf(a, b0.x, acc[i][0]);
                    acc[i][1] = fmaf(a, b0.y, acc[i][1]);
                    acc[i][2] = fmaf(a, b0.z, acc[i][2]);
                    acc[i][3] = fmaf(a, b0.w, acc[i][3]);
                    acc[i][4] = fmaf(a, b1.x, acc[i][4]);
                    acc[i][5] = fmaf(a, b1.y, acc[i][5]);
                    acc[i][6] = fmaf(a, b1.z, acc[i][6]);
                    acc[i][7] = fmaf(a, b1.w, acc[i][7]);
                }
            }
        }
    }
}

template <int NK2>
__device__ __forceinline__ void gemm1_direct(const float* const (&frow)[4], int k2base,
                                             const float* __restrict__ Bc,
                                             float acc[4][8], int ct) {
#pragma unroll 4
    for (int k2 = 0; k2 < NK2; ++k2) {
        float2 a2[4];
#pragma unroll
        for (int i = 0; i < 4; ++i)
            a2[i] = *(const float2*)(frow[i] + (k2base + k2) * 2);
#pragma unroll
        for (int kk = 0; kk < 2; ++kk) {
            const float* bp = &Bc[(k2 * 2 + kk) * DIM + ct * 8];
            float4 b0 = *(const float4*)bp;
            float4 b1 = *(const float4*)(bp + 4);
#pragma unroll
            for (int i = 0; i < 4; ++i) {
                float a = kk ? a2[i].y : a2[i].x;
                acc[i][0] = fmaf(a, b0.x, acc[i][0]);
                acc[i][1] = fmaf(a, b0.y, acc[i][1]);
                acc[i][2] = fmaf(a, b0.z, acc[i][2]);
                acc[i][3] = fmaf(a, b0.w, acc[i][3]);
                acc[i][4] = fmaf(a, b1.x, acc[i][4]);
                acc[i][5] = fmaf(a, b1.y, acc[i][5]);
                acc[i][6] = fmaf(a, b1.z, acc[i][6]);
                acc[i][7] = fmaf(a, b1.w, acc[i][7]);
            }
        }
    }
}

__global__ __launch_bounds__(BLK) void node_in2f_fb(const float* __restrict__ x,
                                                    const float* __restrict__ W,
                                                    float* __restrict__ h) {
    __shared__ float At[TROWS * LDA];
    __shared__ float Bc[32 * DIM];
    const int tid = threadIdx.x;
    const int rt = tid >> 4, ct = tid & 15;
    const int n0 = blockIdx.x * TROWS;
    for (int i = tid; i < TROWS * (DIM / 4); i += BLK) {
        int row = i >> 5, c4 = i & 31;
        *(float4*)&At[row * LDA + c4 * 4] = *(const float4*)&x[(size_t)(n0 + row) * DIM + c4 * 4];
    }
    float acc[4][8];
#pragma unroll
    for (int i = 0; i < 4; ++i)
#pragma unroll
        for (int j = 0; j < 8; ++j) acc[i][j] = 0.f;
    gemm_tile<DIM>(At, LDA, W, Bc, acc, rt, ct, tid);
#pragma unroll
    for (int i = 0; i < 4; ++i) {
        float* hp = &h[(size_t)(n0 + rt * 4 + i) * DIM + ct * 8];
        *(float4*)hp = make_float4(acc[i][0], acc[i][1], acc[i][2], acc[i][3]);
        *(float4*)(hp + 4) = make_float4(acc[i][4], acc[i][5], acc[i][6], acc[i][7]);
    }
}

__global__ __launch_bounds__(BLK) void node_out_fb(const float* __restrict__ agg,
                                                   const float* __restrict__ W_out,
                                                   const float* __restrict__ b_out,
                                                   const float* __restrict__ W_lin,
                                                   const float* __restrict__ b_lin,
                                                   float* __restrict__ out) {
    __shared__ float At[TROWS * LDA];
    __shared__ float Bc[32 * DIM];
    const int tid = threadIdx.x;
    const int rt = tid >> 4, ct = tid & 15;
    const int n0 = blockIdx.x * TROWS;
    for (int i = tid; i < TROWS * (DIM / 4); i += BLK) {
        int row = i >> 5, c4 = i & 31;
        *(float4*)&At[row * LDA + c4 * 4] = *(const float4*)&agg[(size_t)(n0 + row) * DIM + c4 * 4];
    }
    float acc[4][8];
    init_acc_bias(acc, b_out, ct);
    gemm_tile<DIM>(At, LDA, W_out, Bc, acc, rt, ct, tid);
    __syncthreads();
#pragma unroll
    for (int i = 0; i < 4; ++i) {
        float* tp = &At[(rt * 4 + i) * LDA + ct * 8];
        *(float4*)tp = make_float4(ssp_f(acc[i][0]), ssp_f(acc[i][1]),
                                   ssp_f(acc[i][2]), ssp_f(acc[i][3]));
        *(float4*)(tp + 4) = make_float4(ssp_f(acc[i][4]), ssp_f(acc[i][5]),
                                         ssp_f(acc[i][6]), ssp_f(acc[i][7]));
    }
    init_acc_bias(acc, b_lin, ct);
    gemm_tile<DIM>(At, LDA, W_lin, Bc, acc, rt, ct, tid);
#pragma unroll
    for (int i = 0; i < 4; ++i) {
        float* op = &out[(size_t)(n0 + rt * 4 + i) * DIM + ct * 8];
        *(float4*)op = make_float4(acc[i][0], acc[i][1], acc[i][2], acc[i][3]);
        *(float4*)(op + 4) = make_float4(acc[i][4], acc[i][5], acc[i][6], acc[i][7]);
    }
}

__global__ __launch_bounds__(BLK) void edge_kernel_atomic(const float* __restrict__ f_ij,
                                                          const float* __restrict__ r_ij,
                                                          const int* __restrict__ ind_i,
                                                          const int* __restrict__ ind_j,
                                                          const float* __restrict__ W_f1,
                                                          const float* __restrict__ b_f1,
                                                          const float* __restrict__ W_f2,
                                                          const float* __restrict__ b_f2,
                                                          const float* __restrict__ h,
                                                          float* __restrict__ agg) {
    __shared__ float t1[TROWS * LDA];
    __shared__ float Bc[32 * DIM];
    const int tid = threadIdx.x;
    const int rt = tid >> 4, ct = tid & 15;
    const int e0 = blockIdx.x * TROWS;
    const float* frow[4];
#pragma unroll
    for (int i = 0; i < 4; ++i) frow[i] = f_ij + (size_t)(e0 + rt * 4 + i) * NB;
    float acc[4][8];
    init_acc_bias(acc, b_f1, ct);
    stage_chunk(W_f1, 0, 32, Bc, tid);
    __syncthreads();
    gemm1_direct<16>(frow, 0, Bc, acc, ct);
    __syncthreads();
    stage_chunk(W_f1, 32, 18, Bc, tid);
    __syncthreads();
    gemm1_direct<9>(frow, 16, Bc, acc, ct);
#pragma unroll
    for (int i = 0; i < 4; ++i) {
        float* tp = &t1[(rt * 4 + i) * LDA + ct * 8];
        *(float4*)tp = make_float4(ssp_f(acc[i][0]), ssp_f(acc[i][1]),
                                   ssp_f(acc[i][2]), ssp_f(acc[i][3]));
        *(float4*)(tp + 4) = make_float4(ssp_f(acc[i][4]), ssp_f(acc[i][5]),
                                         ssp_f(acc[i][6]), ssp_f(acc[i][7]));
    }
    init_acc_bias(acc, b_f2, ct);
    gemm_tile<DIM>(t1, LDA, W_f2, Bc, acc, rt, ct, tid);
#pragma unroll
    for (int i = 0; i < 4; ++i) {
        int e = e0 + rt * 4 + i;
        float r = r_ij[e];
        float C = (r < 5.0f) ? 0.5f * (cosf(r * PI_OVER_CUT) + 1.0f) : 0.0f;
        int nj = ind_j[e];
        int ni = ind_i[e];
        const float* hp = &h[(size_t)nj * DIM + ct * 8];
        float4 h0 = *(const float4*)hp;
        float4 h1 = *(const float4*)(hp + 4);
        float* ap = &agg[(size_t)ni * DIM + ct * 8];
        atomicAdd(ap + 0, h0.x * acc[i][0] * C);
        atomicAdd(ap + 1, h0.y * acc[i][1] * C);
        atomicAdd(ap + 2, h0.z * acc[i][2] * C);
        atomicAdd(ap + 3, h0.w * acc[i][3] * C);
        atomicAdd(ap + 4, h1.x * acc[i][4] * C);
        atomicAdd(ap + 5, h1.y * acc[i][5] * C);
        atomicAdd(ap + 6, h1.z * acc[i][6] * C);
        atomicAdd(ap + 7, h1.w * acc[i][7] * C);
    }
}

extern "C" void kernel_launch(void* const* d_in, const int* in_sizes, int n_in,
                              void* d_out, int out_size, void* d_ws, size_t ws_size,
                              hipStream_t stream) {
    const float* x      = (const float*)d_in[0];
    const float* r_ij   = (const float*)d_in[1];
    const float* f_ij   = (const float*)d_in[2];
    const int*   ind_i  = (const int*)d_in[3];
    const int*   ind_j  = (const int*)d_in[4];
    const float* W_in2f = (const float*)d_in[5];
    const float* W_f1   = (const float*)d_in[6];
    const float* b_f1   = (const float*)d_in[7];
    const float* W_f2   = (const float*)d_in[8];
    const float* b_f2   = (const float*)d_in[9];
    const float* W_out  = (const float*)d_in[10];
    const float* b_out  = (const float*)d_in[11];
    const float* W_lin  = (const float*)d_in[12];
    const float* b_lin  = (const float*)d_in[13];
    float* out = (float*)d_out;

    char* ws = (char*)d_ws;
    size_t off = 0;
    auto alloc = [&](size_t bytes) {
        char* p = ws + off;
        off = (off + bytes + 511) & ~(size_t)511;
        return p;
    };
    unsigned short* Wsplit = (unsigned short*)alloc(WSPLIT_USHORTS * sizeof(unsigned short));
    float* h      = (float*)alloc((size_t)N_NODES_C * DIM * sizeof(float));
    float* agg    = (float*)alloc((size_t)N_NODES_C * DIM * sizeof(float));
    float* msg    = (float*)alloc((size_t)N_EDGES_C * DIM * sizeof(float));
    int*   eids   = (int*)alloc((size_t)N_EDGES_C * sizeof(int));
    int*   cnt    = (int*)alloc((size_t)N_NODES_C * sizeof(int));
    int*   startA = (int*)alloc((size_t)N_NODES_C * sizeof(int));
    int*   cursor = (int*)alloc((size_t)N_NODES_C * sizeof(int));
    int*   bsum   = (int*)alloc((size_t)NSCAN_BLK * sizeof(int));
    const bool have_ws = (off <= ws_size);

    if (have_ws) {
        split5_kernel<<<(18 * 4096 + BLK - 1) / BLK, BLK, 0, stream>>>(
            W_in2f, W_f1, W_f2, W_out, W_lin, Wsplit);

        node_in2f_mfma<<<N_NODES_C / TROWS, BLK, 0, stream>>>(x, Wsplit, h);

        hipMemsetAsync(cnt, 0, (size_t)N_NODES_C * sizeof(int), stream);
        hist_kernel<<<(N_EDGES_C + BLK - 1) / BLK, BLK, 0, stream>>>(ind_i, cnt);
        scan1_kernel<<<NSCAN_BLK, BLK, 0, stream>>>(cnt, startA, bsum);
        scan2_kernel<<<1, BLK, 0, stream>>>(bsum);
        scan3_kernel<<<NSCAN_BLK, BLK, 0, stream>>>(startA, cursor, bsum);
        place_kernel<<<(N_EDGES_C + BLK - 1) / BLK, BLK, 0, stream>>>(ind_i, cursor, eids);

        edge_kernel_mfma<<<N_EDGES_C / TROWS, BLK, 0, stream>>>(
            f_ij, r_ij, ind_j, Wsplit, b_f1, b_f2, h, msg);
        gather_kernel<<<(N_NODES_C + 3) / 4, BLK, 0, stream>>>(msg, eids, startA, cnt, agg);

        node_out_mfma<<<N_NODES_C / TROWS, BLK, 0, stream>>>(agg, Wsplit, b_out, b_lin, out);
    } else {
        // minimal-workspace vector fallback (h + agg only)
        float* h2   = (float*)d_ws;
        float* agg2 = h2 + (size_t)N_NODES_C * DIM;
        node_in2f_fb<<<N_NODES_C / TROWS, BLK, 0, stream>>>(x, W_in2f, h2);
        hipMemsetAsync(agg2, 0, (size_t)N_NODES_C * DIM * sizeof(float), stream);
        edge_kernel_atomic<<<N_EDGES_C / TROWS, BLK, 0, stream>>>(
            f_ij, r_ij, ind_i, ind_j, W_f1, b_f1, W_f2, b_f2, h2, agg2);
        node_out_fb<<<N_NODES_C / TROWS, BLK, 0, stream>>>(agg2, W_out, b_out, W_lin, b_lin, out);
    }
}

// Round 9
// 435.315 us; speedup vs baseline: 2.4146x; 1.2172x over previous
//
#include <hip/hip_runtime.h>

#define N_NODES_C 40000
#define N_EDGES_C 640000
#define DIM 128
#define NB 50
#define LDA 132       // f32 transpose-buffer leading dim (528B rows: 16B-aligned)
#define BLK 256
#define TROWS 64
#define LOG2_C 0.6931471805599453f
#define PI_OVER_CUT 0.6283185307179586f  // pi/5
#define NSCAN_BLK 157  // ceil(40000/256)

typedef __attribute__((ext_vector_type(8))) short s8v;   // 8 bf16 = A/B frag of 16x16x32
typedef __attribute__((ext_vector_type(4))) float f4v;   // C/D frag

#define MFMA_BF16 __builtin_amdgcn_mfma_f32_16x16x32_bf16

// Wsplit segment offsets (ushort units). Layout per weight: [nc][128 col][40] with
// k in [0,32) at col*40+k.
#define SEG_IN2F_H 0
#define SEG_IN2F_L 20480
#define SEG_F1_H   40960
#define SEG_F1_L   51200
#define SEG_F2_H   61440
#define SEG_F2_L   81920
#define SEG_OUT_H  102400
#define SEG_OUT_L  122880
#define SEG_LIN_H  143360
#define SEG_LIN_L  163840
#define WSPLIT_USHORTS 184320

__device__ __forceinline__ unsigned short f2bf(float x) {   // RNE (pre-split kernel only)
    unsigned int u = __float_as_uint(x);
    u += 0x7fffu + ((u >> 16) & 1u);
    return (unsigned short)(u >> 16);
}
__device__ __forceinline__ float bf2f(unsigned short h) {
    return __uint_as_float(((unsigned int)h) << 16);
}
// fast ssp: max(t,0) + log(1+exp(-|t|)) - log2, native exp/log (v_exp/v_log)
__device__ __forceinline__ float ssp_f(float t) {
    float e = __expf(-fabsf(t));
    return fmaxf(t, 0.0f) + __logf(1.0f + e) - LOG2_C;
}
// truncation split of 8 f32 -> bf16 hi/lo frags; residual x-hi is exact (same exponent)
__device__ __forceinline__ void split8t(const float* av, s8v& Ah, s8v& Al) {
#pragma unroll
    for (int j = 0; j < 8; j += 2) {
        unsigned int u0 = __float_as_uint(av[j]);
        unsigned int u1 = __float_as_uint(av[j + 1]);
        float h0 = __uint_as_float(u0 & 0xffff0000u);
        float h1 = __uint_as_float(u1 & 0xffff0000u);
        unsigned int r0 = __float_as_uint(av[j] - h0);
        unsigned int r1 = __float_as_uint(av[j + 1] - h1);
        ((unsigned int*)&Ah)[j >> 1] = __builtin_amdgcn_perm(u1, u0, 0x07060302);
        ((unsigned int*)&Al)[j >> 1] = __builtin_amdgcn_perm(r1, r0, 0x07060302);
    }
}
// 8 output tiles x 3-term split MFMA; B-frag loads batched 8-wide (issue-early, T14)
__device__ __forceinline__ void mfma8(const unsigned short* __restrict__ bh,
                                      const unsigned short* __restrict__ bl,
                                      const s8v& Ah, const s8v& Al, f4v acc[8]) {
    s8v B[8];
#pragma unroll
    for (int t = 0; t < 8; ++t) B[t] = *(const s8v*)(bl + t * 640);
#pragma unroll
    for (int t = 0; t < 8; ++t) acc[t] = MFMA_BF16(Ah, B[t], acc[t], 0, 0, 0);
#pragma unroll
    for (int t = 0; t < 8; ++t) B[t] = *(const s8v*)(bh + t * 640);
#pragma unroll
    for (int t = 0; t < 8; ++t) {
        acc[t] = MFMA_BF16(Al, B[t], acc[t], 0, 0, 0);
        acc[t] = MFMA_BF16(Ah, B[t], acc[t], 0, 0, 0);
    }
}

// ---------------- weight pre-split (runs once per launch) ----------------
__global__ __launch_bounds__(BLK) void split5_kernel(const float* __restrict__ Wa,
                                                     const float* __restrict__ Wb,
                                                     const float* __restrict__ Wc,
                                                     const float* __restrict__ Wd,
                                                     const float* __restrict__ We,
                                                     unsigned short* __restrict__ Ws) {
    int i = blockIdx.x * BLK + threadIdx.x;
    if (i >= 18 * 4096) return;
    int chunk = i >> 12, r = i & 4095, k = r & 31, col = r >> 5;
    const float* W; int Kr, ck, hb, lb;
    if (chunk < 4)       { W = Wa; Kr = 128; ck = chunk;      hb = SEG_IN2F_H; lb = SEG_IN2F_L; }
    else if (chunk < 6)  { W = Wb; Kr = 50;  ck = chunk - 4;  hb = SEG_F1_H;   lb = SEG_F1_L; }
    else if (chunk < 10) { W = Wc; Kr = 128; ck = chunk - 6;  hb = SEG_F2_H;   lb = SEG_F2_L; }
    else if (chunk < 14) { W = Wd; Kr = 128; ck = chunk - 10; hb = SEG_OUT_H;  lb = SEG_OUT_L; }
    else                 { W = We; Kr = 128; ck = chunk - 14; hb = SEG_LIN_H;  lb = SEG_LIN_L; }
    int krow = ck * 32 + k;
    float v = (krow < Kr) ? W[(size_t)krow * DIM + col] : 0.f;
    unsigned short h16 = f2bf(v);
    int o = ck * 5120 + col * 40 + k;
    Ws[hb + o] = h16;
    Ws[lb + o] = f2bf(v - bf2f(h16));
}

// ---------------- h = x @ W_in2f  (MFMA, no LDS) ----------------
__global__ __launch_bounds__(BLK, 4) void node_in2f_mfma(const float* __restrict__ x,
                                                         const unsigned short* __restrict__ Ws,
                                                         float* __restrict__ h) {
    const int tid = threadIdx.x;
    const int w = tid >> 6, l = tid & 63, lr = l & 15, lk = l >> 4;
    const int n0 = blockIdx.x * TROWS;
    const int rowA = 16 * w + lr;
    const float* xr = x + (size_t)(n0 + rowA) * DIM;

    f4v acc[8];
#pragma unroll
    for (int t = 0; t < 8; ++t) acc[t] = (f4v){0.f, 0.f, 0.f, 0.f};
#pragma unroll
    for (int kc = 0; kc < 4; ++kc) {
        const float* ap = xr + kc * 32 + lk * 8;
        float4 a0 = *(const float4*)ap, a1 = *(const float4*)(ap + 4);
        float av[8] = {a0.x, a0.y, a0.z, a0.w, a1.x, a1.y, a1.z, a1.w};
        s8v Ah, Al; split8t(av, Ah, Al);
        const int bo = kc * 5120 + lr * 40 + lk * 8;
        mfma8(Ws + SEG_IN2F_H + bo, Ws + SEG_IN2F_L + bo, Ah, Al, acc);
    }
#pragma unroll
    for (int t = 0; t < 8; ++t)
#pragma unroll
        for (int r = 0; r < 4; ++r)
            h[(size_t)(n0 + 16 * w + lk * 4 + r) * DIM + t * 16 + lr] = acc[t][r];
}

// ---------------- CSR build ----------------
__global__ __launch_bounds__(BLK) void hist_kernel(const int* __restrict__ ind_i,
                                                   int* __restrict__ cnt) {
    int e = blockIdx.x * BLK + threadIdx.x;
    if (e < N_EDGES_C) atomicAdd(&cnt[ind_i[e]], 1);
}

__global__ __launch_bounds__(BLK) void scan1_kernel(const int* __restrict__ cnt,
                                                    int* __restrict__ excl,
                                                    int* __restrict__ bsum) {
    __shared__ int s[BLK];
    const int tid = threadIdx.x;
    const int idx = blockIdx.x * BLK + tid;
    int v = (idx < N_NODES_C) ? cnt[idx] : 0;
    s[tid] = v;
    __syncthreads();
    for (int off = 1; off < BLK; off <<= 1) {
        int t = (tid >= off) ? s[tid - off] : 0;
        __syncthreads();
        s[tid] += t;
        __syncthreads();
    }
    if (idx < N_NODES_C) excl[idx] = s[tid] - v;
    if (tid == BLK - 1) bsum[blockIdx.x] = s[tid];
}

__global__ __launch_bounds__(BLK) void scan2_kernel(int* __restrict__ bsum) {
    __shared__ int s[BLK];
    const int tid = threadIdx.x;
    int v = (tid < NSCAN_BLK) ? bsum[tid] : 0;
    s[tid] = v;
    __syncthreads();
    for (int off = 1; off < BLK; off <<= 1) {
        int t = (tid >= off) ? s[tid - off] : 0;
        __syncthreads();
        s[tid] += t;
        __syncthreads();
    }
    if (tid < NSCAN_BLK) bsum[tid] = s[tid] - v;  // exclusive
}

__global__ __launch_bounds__(BLK) void scan3_kernel(int* __restrict__ start,
                                                    int* __restrict__ cursor,
                                                    const int* __restrict__ bsum) {
    const int idx = blockIdx.x * BLK + threadIdx.x;
    if (idx < N_NODES_C) {
        int v = start[idx] + bsum[blockIdx.x];
        start[idx] = v;
        cursor[idx] = v;
    }
}

__global__ __launch_bounds__(BLK) void place_kernel(const int* __restrict__ ind_i,
                                                    int* __restrict__ cursor,
                                                    int* __restrict__ eids) {
    int e = blockIdx.x * BLK + threadIdx.x;
    if (e < N_EDGES_C) {
        int slot = atomicAdd(&cursor[ind_i[e]], 1);
        eids[slot] = e;
    }
}

// ---------------- Edge kernel: full MFMA; t1 stored pre-split in LDS ----------------
// LDS (34816B): t1h[64][136] ushort + t1l[64][136] ushort; alias tf f32[64][132] post-GEMM2.
__global__ __launch_bounds__(BLK, 4) void edge_kernel_mfma(const float* __restrict__ f_ij,
                                                           const float* __restrict__ r_ij,
                                                           const int* __restrict__ ind_j,
                                                           const unsigned short* __restrict__ Ws,
                                                           const float* __restrict__ b_f1,
                                                           const float* __restrict__ b_f2,
                                                           const float* __restrict__ h,
                                                           float* __restrict__ msg) {
    __shared__ __align__(16) char smem[34816];
    unsigned short* t1h = (unsigned short*)smem;          // [64][136]
    unsigned short* t1l = t1h + 64 * 136;
    float* tf = (float*)smem;                             // [64][132] alias (post-GEMM2)

    const int tid = threadIdx.x;
    const int w = tid >> 6, l = tid & 63, lr = l & 15, lk = l >> 4;
    const int rt = tid >> 4, ct = tid & 15;
    const int e0 = blockIdx.x * TROWS;  // 640000 % 64 == 0
    const int rowA = 16 * w + lr;

    // ---- GEMM1: t_pre = f @ W1 + b1; A in-reg from global f_ij (float2, 8B-aligned)
    f4v acc[8];
#pragma unroll
    for (int t = 0; t < 8; ++t) { float bv = b_f1[t * 16 + lr]; acc[t] = (f4v){bv, bv, bv, bv}; }
    const float* fr = f_ij + (size_t)(e0 + rowA) * NB;
#pragma unroll
    for (int kc = 0; kc < 2; ++kc) {
        int kb = kc * 32 + lk * 8;
        float av[8];
#pragma unroll
        for (int ii = 0; ii < 4; ++ii) {
            int k = kb + ii * 2;                      // pairs never straddle 50 (even)
            float2 v = (k < NB) ? *(const float2*)(fr + k) : make_float2(0.f, 0.f);
            av[ii * 2] = v.x; av[ii * 2 + 1] = v.y;
        }
        s8v Ah, Al; split8t(av, Ah, Al);
        const int bo = kc * 5120 + lr * 40 + lk * 8;
        mfma8(Ws + SEG_F1_H + bo, Ws + SEG_F1_L + bo, Ah, Al, acc);
    }
    // C1 (row 16w+lk*4+r, col t*16+lr): ssp + truncation-split directly into t1h/t1l
#pragma unroll
    for (int t = 0; t < 8; ++t)
#pragma unroll
        for (int r = 0; r < 4; ++r) {
            float v = ssp_f(acc[t][r]);
            unsigned int u = __float_as_uint(v);
            float hf = __uint_as_float(u & 0xffff0000u);
            int idx = (16 * w + lk * 4 + r) * 136 + t * 16 + lr;
            t1h[idx] = (unsigned short)(u >> 16);
            t1l[idx] = (unsigned short)(__float_as_uint(v - hf) >> 16);
        }
    __syncthreads();

    // ---- GEMM2: msg_pre = t1 @ W2 + b2; A-frags read pre-split from LDS (b128)
#pragma unroll
    for (int t = 0; t < 8; ++t) { float bv = b_f2[t * 16 + lr]; acc[t] = (f4v){bv, bv, bv, bv}; }
#pragma unroll
    for (int kc = 0; kc < 4; ++kc) {
        s8v Ah = *(const s8v*)&t1h[rowA * 136 + kc * 32 + lk * 8];
        s8v Al = *(const s8v*)&t1l[rowA * 136 + kc * 32 + lk * 8];
        const int bo = kc * 5120 + lr * 40 + lk * 8;
        mfma8(Ws + SEG_F2_H + bo, Ws + SEG_F2_L + bo, Ah, Al, acc);
    }
    __syncthreads();   // all t1 reads done before tf overwrite
#pragma unroll
    for (int t = 0; t < 8; ++t)
#pragma unroll
        for (int r = 0; r < 4; ++r)
            tf[(16 * w + lk * 4 + r) * LDA + t * 16 + lr] = acc[t][r];
    __syncthreads();

    // ---- epilogue: cutoff, gather h[ind_j], write msg row (vectorized row-major)
#pragma unroll
    for (int i = 0; i < 4; ++i) {
        int e = e0 + rt * 4 + i;
        float rr = r_ij[e];
        float C = (rr < 5.0f) ? (0.5f * __cosf(rr * PI_OVER_CUT) + 0.5f) : 0.0f;
        int nj = ind_j[e];
        const float* hp = &h[(size_t)nj * DIM + ct * 8];
        float4 h0 = *(const float4*)hp, h1 = *(const float4*)(hp + 4);
        const float* ep = &tf[(rt * 4 + i) * LDA + ct * 8];
        float4 a0 = *(const float4*)ep, a1 = *(const float4*)(ep + 4);
        float* mp = &msg[(size_t)e * DIM + ct * 8];
        *(float4*)mp = make_float4(h0.x * a0.x * C, h0.y * a0.y * C,
                                   h0.z * a0.z * C, h0.w * a0.w * C);
        *(float4*)(mp + 4) = make_float4(h1.x * a1.x * C, h1.y * a1.y * C,
                                         h1.z * a1.z * C, h1.w * a1.w * C);
    }
}

// ---------------- Gather: agg[n] = sum over CSR edges of msg ----------------
__global__ __launch_bounds__(BLK) void gather_kernel(const float* __restrict__ msg,
                                                     const int* __restrict__ eids,
                                                     const int* __restrict__ start,
                                                     const int* __restrict__ cnt,
                                                     float* __restrict__ agg) {
    const int wave = threadIdx.x >> 6;
    const int lane = threadIdx.x & 63;
    const int node = blockIdx.x * 4 + wave;
    if (node >= N_NODES_C) return;
    const int s = start[node];
    const int d = cnt[node];
    float ax = 0.f, ay = 0.f;
    int k = 0;
    for (; k + 1 < d; k += 2) {
        int ea = eids[s + k], eb = eids[s + k + 1];
        float2 va = *(const float2*)&msg[(size_t)ea * DIM + lane * 2];
        float2 vb = *(const float2*)&msg[(size_t)eb * DIM + lane * 2];
        ax += va.x + vb.x;
        ay += va.y + vb.y;
    }
    if (k < d) {
        int ea = eids[s + k];
        float2 va = *(const float2*)&msg[(size_t)ea * DIM + lane * 2];
        ax += va.x;
        ay += va.y;
    }
    *(float2*)&agg[(size_t)node * DIM + lane * 2] = make_float2(ax, ay);
}

// ---------------- out = ssp(agg@W_out + b_out) @ W_lin + b_lin  (MFMA) ----------------
__global__ __launch_bounds__(BLK, 4) void node_out_mfma(const float* __restrict__ agg,
                                                        const unsigned short* __restrict__ Ws,
                                                        const float* __restrict__ b_out,
                                                        const float* __restrict__ b_lin,
                                                        float* __restrict__ out) {
    __shared__ __align__(16) char smem[34816];
    unsigned short* t1h = (unsigned short*)smem;
    unsigned short* t1l = t1h + 64 * 136;

    const int tid = threadIdx.x;
    const int w = tid >> 6, l = tid & 63, lr = l & 15, lk = l >> 4;
    const int n0 = blockIdx.x * TROWS;
    const int rowA = 16 * w + lr;
    const float* ar = agg + (size_t)(n0 + rowA) * DIM;

    f4v acc[8];
#pragma unroll
    for (int t = 0; t < 8; ++t) { float bv = b_out[t * 16 + lr]; acc[t] = (f4v){bv, bv, bv, bv}; }
#pragma unroll
    for (int kc = 0; kc < 4; ++kc) {
        const float* ap = ar + kc * 32 + lk * 8;
        float4 a0 = *(const float4*)ap, a1 = *(const float4*)(ap + 4);
        float av[8] = {a0.x, a0.y, a0.z, a0.w, a1.x, a1.y, a1.z, a1.w};
        s8v Ah, Al; split8t(av, Ah, Al);
        const int bo = kc * 5120 + lr * 40 + lk * 8;
        mfma8(Ws + SEG_OUT_H + bo, Ws + SEG_OUT_L + bo, Ah, Al, acc);
    }
    // v = ssp(C1) split into LDS
#pragma unroll
    for (int t = 0; t < 8; ++t)
#pragma unroll
        for (int r = 0; r < 4; ++r) {
            float v = ssp_f(acc[t][r]);
            unsigned int u = __float_as_uint(v);
            float hf = __uint_as_float(u & 0xffff0000u);
            int idx = (16 * w + lk * 4 + r) * 136 + t * 16 + lr;
            t1h[idx] = (unsigned short)(u >> 16);
            t1l[idx] = (unsigned short)(__float_as_uint(v - hf) >> 16);
        }
    __syncthreads();

#pragma unroll
    for (int t = 0; t < 8; ++t) { float bv = b_lin[t * 16 + lr]; acc[t] = (f4v){bv, bv, bv, bv}; }
#pragma unroll
    for (int kc = 0; kc < 4; ++kc) {
        s8v Ah = *(const s8v*)&t1h[rowA * 136 + kc * 32 + lk * 8];
        s8v Al = *(const s8v*)&t1l[rowA * 136 + kc * 32 + lk * 8];
        const int bo = kc * 5120 + lr * 40 + lk * 8;
        mfma8(Ws + SEG_LIN_H + bo, Ws + SEG_LIN_L + bo, Ah, Al, acc);
    }
#pragma unroll
    for (int t = 0; t < 8; ++t)
#pragma unroll
        for (int r = 0; r < 4; ++r)
            out[(size_t)(n0 + 16 * w + lk * 4 + r) * DIM + t * 16 + lr] = acc[t][r];
}

// ================= vector fallback path (only if workspace too small) =================
__device__ __forceinline__ void stage_chunk(const float* __restrict__ B, int k0, int rows,
                                            float* __restrict__ Bc, int tid) {
    const int n4 = rows * (DIM / 4);
    const float4* Bg = (const float4*)B + (size_t)k0 * (DIM / 4);
    float4* Bc4 = (float4*)Bc;
    for (int i = tid; i < n4; i += BLK) Bc4[i] = Bg[i];
}

__device__ __forceinline__ void init_acc_bias(float acc[4][8], const float* __restrict__ b, int ct) {
    float4 bb0 = *(const float4*)&b[ct * 8];
    float4 bb1 = *(const float4*)&b[ct * 8 + 4];
#pragma unroll
    for (int i = 0; i < 4; ++i) {
        acc[i][0] = bb0.x; acc[i][1] = bb0.y; acc[i][2] = bb0.z; acc[i][3] = bb0.w;
        acc[i][4] = bb1.x; acc[i][5] = bb1.y; acc[i][6] = bb1.z; acc[i][7] = bb1.w;
    }
}

template <int KPAD>
__device__ __forceinline__ void gemm_tile(const float* __restrict__ A_lds, int lda,
                                          const float* __restrict__ Bglob,
                                          float* __restrict__ Bc,
                                          float acc[4][8], int rt, int ct, int tid) {
    for (int k0 = 0; k0 < KPAD; k0 += 32) {
        __syncthreads();
        stage_chunk(Bglob, k0, 32, Bc, tid);
        __syncthreads();
#pragma unroll 2
        for (int k4 = 0; k4 < 8; ++k4) {
            float4 av[4];
#pragma unroll
            for (int i = 0; i < 4; ++i)
                av[i] = *(const float4*)&A_lds[(rt * 4 + i) * lda + k0 + k4 * 4];
#pragma unroll
            for (int kk = 0; kk < 4; ++kk) {
                const float* bp = &Bc[(k4 * 4 + kk) * DIM + ct * 8];
                float4 b0 = *(const float4*)bp;
                float4 b1 = *(const float4*)(bp + 4);
#pragma unroll
                for (int i = 0; i < 4; ++i) {
                    float a = ((const float*)&av[i])[kk];
                    acc[i][0] = fmaf(a, b0.x, acc[i][0]);
                    acc[i][1] = fmaf(a, b0.y, acc[i][1]);
                    acc[i][2] = fmaf(a, b0.z, acc[i][2]);
                    acc[i][3] = fmaf(a, b0.w, acc[i][3]);
                    acc[i][4] = fmaf(a, b1.x, acc[i][4]);
                    acc[i][5] = fmaf(a, b1.y, acc[i][5]);
                    acc[i][6] = fmaf(a, b1.z, acc[i][6]);
                    acc[i][7] = fmaf(a, b1.w, acc[i][7]);
                }
            }
        }
    }
}

template <int NK2>
__device__ __forceinline__ void gemm1_direct(const float* const (&frow)[4], int k2base,
                                             const float* __restrict__ Bc,
                                             float acc[4][8], int ct) {
#pragma unroll 4
    for (int k2 = 0; k2 < NK2; ++k2) {
        float2 a2[4];
#pragma unroll
        for (int i = 0; i < 4; ++i)
            a2[i] = *(const float2*)(frow[i] + (k2base + k2) * 2);
#pragma unroll
        for (int kk = 0; kk < 2; ++kk) {
            const float* bp = &Bc[(k2 * 2 + kk) * DIM + ct * 8];
            float4 b0 = *(const float4*)bp;
            float4 b1 = *(const float4*)(bp + 4);
#pragma unroll
            for (int i = 0; i < 4; ++i) {
                float a = kk ? a2[i].y : a2[i].x;
                acc[i][0] = fmaf(a, b0.x, acc[i][0]);
                acc[i][1] = fmaf(a, b0.y, acc[i][1]);
                acc[i][2] = fmaf(a, b0.z, acc[i][2]);
                acc[i][3] = fmaf(a, b0.w, acc[i][3]);
                acc[i][4] = fmaf(a, b1.x, acc[i][4]);
                acc[i][5] = fmaf(a, b1.y, acc[i][5]);
                acc[i][6] = fmaf(a, b1.z, acc[i][6]);
                acc[i][7] = fmaf(a, b1.w, acc[i][7]);
            }
        }
    }
}

__global__ __launch_bounds__(BLK) void node_in2f_fb(const float* __restrict__ x,
                                                    const float* __restrict__ W,
                                                    float* __restrict__ h) {
    __shared__ float At[TROWS * LDA];
    __shared__ float Bc[32 * DIM];
    const int tid = threadIdx.x;
    const int rt = tid >> 4, ct = tid & 15;
    const int n0 = blockIdx.x * TROWS;
    for (int i = tid; i < TROWS * (DIM / 4); i += BLK) {
        int row = i >> 5, c4 = i & 31;
        *(float4*)&At[row * LDA + c4 * 4] = *(const float4*)&x[(size_t)(n0 + row) * DIM + c4 * 4];
    }
    float acc[4][8];
#pragma unroll
    for (int i = 0; i < 4; ++i)
#pragma unroll
        for (int j = 0; j < 8; ++j) acc[i][j] = 0.f;
    gemm_tile<DIM>(At, LDA, W, Bc, acc, rt, ct, tid);
#pragma unroll
    for (int i = 0; i < 4; ++i) {
        float* hp = &h[(size_t)(n0 + rt * 4 + i) * DIM + ct * 8];
        *(float4*)hp = make_float4(acc[i][0], acc[i][1], acc[i][2], acc[i][3]);
        *(float4*)(hp + 4) = make_float4(acc[i][4], acc[i][5], acc[i][6], acc[i][7]);
    }
}

__global__ __launch_bounds__(BLK) void node_out_fb(const float* __restrict__ agg,
                                                   const float* __restrict__ W_out,
                                                   const float* __restrict__ b_out,
                                                   const float* __restrict__ W_lin,
                                                   const float* __restrict__ b_lin,
                                                   float* __restrict__ out) {
    __shared__ float At[TROWS * LDA];
    __shared__ float Bc[32 * DIM];
    const int tid = threadIdx.x;
    const int rt = tid >> 4, ct = tid & 15;
    const int n0 = blockIdx.x * TROWS;
    for (int i = tid; i < TROWS * (DIM / 4); i += BLK) {
        int row = i >> 5, c4 = i & 31;
        *(float4*)&At[row * LDA + c4 * 4] = *(const float4*)&agg[(size_t)(n0 + row) * DIM + c4 * 4];
    }
    float acc[4][8];
    init_acc_bias(acc, b_out, ct);
    gemm_tile<DIM>(At, LDA, W_out, Bc, acc, rt, ct, tid);
    __syncthreads();
#pragma unroll
    for (int i = 0; i < 4; ++i) {
        float* tp = &At[(rt * 4 + i) * LDA + ct * 8];
        *(float4*)tp = make_float4(ssp_f(acc[i][0]), ssp_f(acc[i][1]),
                                   ssp_f(acc[i][2]), ssp_f(acc[i][3]));
        *(float4*)(tp + 4) = make_float4(ssp_f(acc[i][4]), ssp_f(acc[i][5]),
                                         ssp_f(acc[i][6]), ssp_f(acc[i][7]));
    }
    init_acc_bias(acc, b_lin, ct);
    gemm_tile<DIM>(At, LDA, W_lin, Bc, acc, rt, ct, tid);
#pragma unroll
    for (int i = 0; i < 4; ++i) {
        float* op = &out[(size_t)(n0 + rt * 4 + i) * DIM + ct * 8];
        *(float4*)op = make_float4(acc[i][0], acc[i][1], acc[i][2], acc[i][3]);
        *(float4*)(op + 4) = make_float4(acc[i][4], acc[i][5], acc[i][6], acc[i][7]);
    }
}

__global__ __launch_bounds__(BLK) void edge_kernel_atomic(const float* __restrict__ f_ij,
                                                          const float* __restrict__ r_ij,
                                                          const int* __restrict__ ind_i,
                                                          const int* __restrict__ ind_j,
                                                          const float* __restrict__ W_f1,
                                                          const float* __restrict__ b_f1,
                                                          const float* __restrict__ W_f2,
                                                          const float* __restrict__ b_f2,
                                                          const float* __restrict__ h,
                                                          float* __restrict__ agg) {
    __shared__ float t1[TROWS * LDA];
    __shared__ float Bc[32 * DIM];
    const int tid = threadIdx.x;
    const int rt = tid >> 4, ct = tid & 15;
    const int e0 = blockIdx.x * TROWS;
    const float* frow[4];
#pragma unroll
    for (int i = 0; i < 4; ++i) frow[i] = f_ij + (size_t)(e0 + rt * 4 + i) * NB;
    float acc[4][8];
    init_acc_bias(acc, b_f1, ct);
    stage_chunk(W_f1, 0, 32, Bc, tid);
    __syncthreads();
    gemm1_direct<16>(frow, 0, Bc, acc, ct);
    __syncthreads();
    stage_chunk(W_f1, 32, 18, Bc, tid);
    __syncthreads();
    gemm1_direct<9>(frow, 16, Bc, acc, ct);
#pragma unroll
    for (int i = 0; i < 4; ++i) {
        float* tp = &t1[(rt * 4 + i) * LDA + ct * 8];
        *(float4*)tp = make_float4(ssp_f(acc[i][0]), ssp_f(acc[i][1]),
                                   ssp_f(acc[i][2]), ssp_f(acc[i][3]));
        *(float4*)(tp + 4) = make_float4(ssp_f(acc[i][4]), ssp_f(acc[i][5]),
                                         ssp_f(acc[i][6]), ssp_f(acc[i][7]));
    }
    init_acc_bias(acc, b_f2, ct);
    gemm_tile<DIM>(t1, LDA, W_f2, Bc, acc, rt, ct, tid);
#pragma unroll
    for (int i = 0; i < 4; ++i) {
        int e = e0 + rt * 4 + i;
        float r = r_ij[e];
        float C = (r < 5.0f) ? 0.5f * (cosf(r * PI_OVER_CUT) + 1.0f) : 0.0f;
        int nj = ind_j[e];
        int ni = ind_i[e];
        const float* hp = &h[(size_t)nj * DIM + ct * 8];
        float4 h0 = *(const float4*)hp;
        float4 h1 = *(const float4*)(hp + 4);
        float* ap = &agg[(size_t)ni * DIM + ct * 8];
        atomicAdd(ap + 0, h0.x * acc[i][0] * C);
        atomicAdd(ap + 1, h0.y * acc[i][1] * C);
        atomicAdd(ap + 2, h0.z * acc[i][2] * C);
        atomicAdd(ap + 3, h0.w * acc[i][3] * C);
        atomicAdd(ap + 4, h1.x * acc[i][4] * C);
        atomicAdd(ap + 5, h1.y * acc[i][5] * C);
        atomicAdd(ap + 6, h1.z * acc[i][6] * C);
        atomicAdd(ap + 7, h1.w * acc[i][7] * C);
    }
}

extern "C" void kernel_launch(void* const* d_in, const int* in_sizes, int n_in,
                              void* d_out, int out_size, void* d_ws, size_t ws_size,
                              hipStream_t stream) {
    const float* x      = (const float*)d_in[0];
    const float* r_ij   = (const float*)d_in[1];
    const float* f_ij   = (const float*)d_in[2];
    const int*   ind_i  = (const int*)d_in[3];
    const int*   ind_j  = (const int*)d_in[4];
    const float* W_in2f = (const float*)d_in[5];
    const float* W_f1   = (const float*)d_in[6];
    const float* b_f1   = (const float*)d_in[7];
    const float* W_f2   = (const float*)d_in[8];
    const float* b_f2   = (const float*)d_in[9];
    const float* W_out  = (const float*)d_in[10];
    const float* b_out  = (const float*)d_in[11];
    const float* W_lin  = (const float*)d_in[12];
    const float* b_lin  = (const float*)d_in[13];
    float* out = (float*)d_out;

    char* ws = (char*)d_ws;
    size_t off = 0;
    auto alloc = [&](size_t bytes) {
        char* p = ws + off;
        off = (off + bytes + 511) & ~(size_t)511;
        return p;
    };
    unsigned short* Wsplit = (unsigned short*)alloc(WSPLIT_USHORTS * sizeof(unsigned short));
    float* h      = (float*)alloc((size_t)N_NODES_C * DIM * sizeof(float));
    float* agg    = (float*)alloc((size_t)N_NODES_C * DIM * sizeof(float));
    float* msg    = (float*)alloc((size_t)N_EDGES_C * DIM * sizeof(float));
    int*   eids   = (int*)alloc((size_t)N_EDGES_C * sizeof(int));
    int*   cnt    = (int*)alloc((size_t)N_NODES_C * sizeof(int));
    int*   startA = (int*)alloc((size_t)N_NODES_C * sizeof(int));
    int*   cursor = (int*)alloc((size_t)N_NODES_C * sizeof(int));
    int*   bsum   = (int*)alloc((size_t)NSCAN_BLK * sizeof(int));
    const bool have_ws = (off <= ws_size);

    if (have_ws) {
        split5_kernel<<<(18 * 4096 + BLK - 1) / BLK, BLK, 0, stream>>>(
            W_in2f, W_f1, W_f2, W_out, W_lin, Wsplit);

        node_in2f_mfma<<<N_NODES_C / TROWS, BLK, 0, stream>>>(x, Wsplit, h);

        hipMemsetAsync(cnt, 0, (size_t)N_NODES_C * sizeof(int), stream);
        hist_kernel<<<(N_EDGES_C + BLK - 1) / BLK, BLK, 0, stream>>>(ind_i, cnt);
        scan1_kernel<<<NSCAN_BLK, BLK, 0, stream>>>(cnt, startA, bsum);
        scan2_kernel<<<1, BLK, 0, stream>>>(bsum);
        scan3_kernel<<<NSCAN_BLK, BLK, 0, stream>>>(startA, cursor, bsum);
        place_kernel<<<(N_EDGES_C + BLK - 1) / BLK, BLK, 0, stream>>>(ind_i, cursor, eids);

        edge_kernel_mfma<<<N_EDGES_C / TROWS, BLK, 0, stream>>>(
            f_ij, r_ij, ind_j, Wsplit, b_f1, b_f2, h, msg);
        gather_kernel<<<(N_NODES_C + 3) / 4, BLK, 0, stream>>>(msg, eids, startA, cnt, agg);

        node_out_mfma<<<N_NODES_C / TROWS, BLK, 0, stream>>>(agg, Wsplit, b_out, b_lin, out);
    } else {
        // minimal-workspace vector fallback (h + agg only)
        float* h2   = (float*)d_ws;
        float* agg2 = h2 + (size_t)N_NODES_C * DIM;
        node_in2f_fb<<<N_NODES_C / TROWS, BLK, 0, stream>>>(x, W_in2f, h2);
        hipMemsetAsync(agg2, 0, (size_t)N_NODES_C * DIM * sizeof(float), stream);
        edge_kernel_atomic<<<N_EDGES_C / TROWS, BLK, 0, stream>>>(
            f_ij, r_ij, ind_i, ind_j, W_f1, b_f1, W_f2, b_f2, h2, agg2);
        node_out_fb<<<N_NODES_C / TROWS, BLK, 0, stream>>>(agg2, W_out, b_out, W_lin, b_lin, out);
    }
}